// Round 18
// baseline (338.345 us; speedup 1.0000x reference)
//
#include <hip/hip_runtime.h>
#include <hip/hip_bf16.h>

#define D_MODEL 1024
#define N_HEADS 16
#define DH 64
#define D_FF   4096
#define SEQ    1024
#define BATCH  4
#define TOK    (BATCH*SEQ)
#define EPS    1e-5f
#define SCALE  0.125f           // 1/sqrt(64)
#define QSCL   0.18033688f      // SCALE * log2(e): QK^T lands in log2 domain

typedef unsigned short USHORT;
typedef __attribute__((ext_vector_type(8))) short short8v;
typedef __attribute__((ext_vector_type(4))) float f32x4;

__device__ __forceinline__ USHORT f2bf(float f) {
    unsigned int u; __builtin_memcpy(&u, &f, 4);
    u += 0x7fffu + ((u >> 16) & 1u);          // RNE
    return (USHORT)(u >> 16);
}
// 2-op round-half-up pack (P in (0,256] and O: error == RNE magnitude)
__device__ __forceinline__ USHORT f2bf_fast(float f) {
    unsigned int u; __builtin_memcpy(&u, &f, 4);
    return (USHORT)((u + 0x8000u) >> 16);
}
// HW pack: 2 floats -> u32 of 2 bf16 (RNE, v_cvt_pk path); lo -> bits [15:0]
__device__ __forceinline__ unsigned pk2bf(float lo, float hi) {
    __hip_bfloat162 h = __float22bfloat162_rn(make_float2(lo, hi));
    unsigned u; __builtin_memcpy(&u, &h, 4);
    return u;
}
__device__ __forceinline__ float bf2f(USHORT s) {
    unsigned int u = ((unsigned int)s) << 16;
    float f; __builtin_memcpy(&f, &u, 4);
    return f;
}
__device__ __forceinline__ float max3f(float a, float b, float c) {
    return fmaxf(fmaxf(a, b), c);             // fuses to v_max3_f32
}

// row-stride-64 swizzled read: unit ^= row&7
__device__ __forceinline__ short8v ld_frag(const USHORT* lds, int row, int c8) {
    return *reinterpret_cast<const short8v*>(
        &lds[row * 64 + (((c8) ^ (row & 7)) << 3)]);
}
// row-stride-128 swizzled read (attn V/P tiles): unit ^= row&15
__device__ __forceinline__ short8v ld128(const USHORT* lds, int row, int cu) {
    return *reinterpret_cast<const short8v*>(
        &lds[row * 128 + (((cu) ^ (row & 15)) << 3)]);
}

#define GLDS(gsrc, ldst) \
    __builtin_amdgcn_global_load_lds( \
        (const __attribute__((address_space(1))) void*)(gsrc), \
        (__attribute__((address_space(3))) void*)(ldst), 16, 0, 0)

#define WAITVM(n) asm volatile("s_waitcnt vmcnt(" #n ")" ::: "memory")

// ---------------------------------------------------------------------------
// bf16 MFMA GEMM, 256x256 tile, BK=64, 512 threads = 8 waves (2M x 4N).
// 2-buffer counted-vmcnt pipeline. Epilogues: normal or fused-QKV routing.
// (R18: Vt pack uses pk2bf / v_cvt_pk_bf16_f32)
// ---------------------------------------------------------------------------
__global__ __launch_bounds__(512) void gemm_k256_kernel(
    const USHORT* __restrict__ A, const USHORT* __restrict__ Bt,
    float* __restrict__ Cf, USHORT* __restrict__ Cb, USHORT* __restrict__ Ck,
    USHORT* __restrict__ VtOut,
    int M, int N, int K, const float* __restrict__ bias, int relu, int qkv)
{
    __shared__ USHORT As[2][256 * 64];
    __shared__ USHORT Bs[2][256 * 64];

    const int tid = threadIdx.x;
    const int l   = tid & 63;
    const int w   = tid >> 6;              // 0..7
    const int wr  = w >> 2, wc = w & 3;    // 2 x 4 wave grid
    const int lr  = l & 15, lg = l >> 4;

    const int gx  = gridDim.x;
    const int nwg = gx * gridDim.y;
    const int lin = blockIdx.y * gx + blockIdx.x;
    const int swz = (lin & 7) * (nwg >> 3) + (lin >> 3);
    const int m0  = (swz / gx) * 256, n0 = (swz % gx) * 256;

    const USHORT* aS[4]; const USHORT* bS[4]; int dOf[4];
#pragma unroll
    for (int p = 0; p < 4; ++p) {
        const int q = p * 512 + tid;
        const int row = q >> 3, cu = q & 7;
        const int cs = ((cu ^ (row & 7)) << 3);
        aS[p] = A  + (size_t)(m0 + row) * K + cs;
        bS[p] = Bt + (size_t)(n0 + row) * K + cs;
        dOf[p] = (p * 512 + w * 64) * 8;
    }

    auto stage = [&](int buf, int k0) {
#pragma unroll
        for (int p = 0; p < 4; ++p) {
            GLDS(aS[p] + k0, &As[buf][dOf[p]]);
            GLDS(bS[p] + k0, &Bs[buf][dOf[p]]);
        }
    };

    f32x4 acc[8][4];
#pragma unroll
    for (int i = 0; i < 8; ++i)
#pragma unroll
        for (int j = 0; j < 4; ++j) acc[i][j] = (f32x4){0.f, 0.f, 0.f, 0.f};

    const int nk = K >> 6;
    stage(0, 0);

    for (int t = 0; t < nk; ++t) {
        const int cur = t & 1;
        if (t + 1 < nk) {
            stage(cur ^ 1, (t + 1) << 6);
            WAITVM(8);
        } else {
            WAITVM(0);
        }
        __builtin_amdgcn_s_barrier();

#pragma unroll
        for (int ks = 0; ks < 2; ++ks) {
            short8v bfr[4];
#pragma unroll
            for (int ni = 0; ni < 4; ++ni)
                bfr[ni] = ld_frag(Bs[cur], wc * 64 + ni * 16 + lr, ks * 4 + lg);
            __builtin_amdgcn_s_setprio(1);
#pragma unroll
            for (int mi = 0; mi < 8; ++mi) {
                short8v af = ld_frag(As[cur], wr * 128 + mi * 16 + lr, ks * 4 + lg);
#pragma unroll
                for (int ni = 0; ni < 4; ++ni)
                    acc[mi][ni] = __builtin_amdgcn_mfma_f32_16x16x32_bf16(
                        af, bfr[ni], acc[mi][ni], 0, 0, 0);
            }
            __builtin_amdgcn_s_setprio(0);
        }
        __builtin_amdgcn_s_barrier();
    }

    // epilogue: C/D layout col = lane&15, row = (lane>>4)*4 + reg
    if (qkv) {
#pragma unroll
        for (int mi = 0; mi < 8; ++mi) {
            const int row = m0 + wr * 128 + mi * 16 + (l >> 4) * 4;
#pragma unroll
            for (int ni = 0; ni < 4; ++ni) {
                const int col = n0 + wc * 64 + ni * 16 + lr;
                if (col < 2048) {
                    USHORT* dst = (col < 1024) ? Cb : Ck;
                    const float scl = (col < 1024) ? QSCL : 1.f;  // log2-e domain
                    const int c = col & 1023;
#pragma unroll
                    for (int j = 0; j < 4; ++j)
                        dst[(size_t)(row + j) * D_MODEL + c] =
                            f2bf(acc[mi][ni][j] * scl);
                } else {
                    const int c = col - 2048;
                    const int bb = row >> 10, jr = row & 1023;
                    const int hh = c >> 6, dd = c & 63;
                    uint2 pk = make_uint2(
                        pk2bf(acc[mi][ni][0], acc[mi][ni][1]),
                        pk2bf(acc[mi][ni][2], acc[mi][ni][3]));
                    *reinterpret_cast<uint2*>(
                        &VtOut[((size_t)(bb * 16 + hh) * 64 + dd) * 1024 + jr]) = pk;
                }
            }
        }
    } else {
#pragma unroll
        for (int mi = 0; mi < 8; ++mi) {
            const int row = m0 + wr * 128 + mi * 16 + (l >> 4) * 4;
#pragma unroll
            for (int ni = 0; ni < 4; ++ni) {
                const int col = n0 + wc * 64 + ni * 16 + lr;
                const float bv = bias ? bias[col] : 0.f;
#pragma unroll
                for (int j = 0; j < 4; ++j) {
                    float v = acc[mi][ni][j] + bv;
                    if (relu) v = fmaxf(v, 0.f);
                    const size_t idx = (size_t)(row + j) * N + col;
                    if (Cf) Cf[idx] = v;
                    if (Cb) Cb[idx] = f2bf(v);
                }
            }
        }
    }
}

// ---------------------------------------------------------------------------
// Split-K bf16 GEMM for the N=1024 shapes: 128x128 tile, BK=64, 2-buffer
// counted-vmcnt, 8 waves. Split-K=2, bf16 partials. (unchanged from R15)
// ---------------------------------------------------------------------------
__global__ __launch_bounds__(512) void gemm_k128c_kernel(
    const USHORT* __restrict__ A, const USHORT* __restrict__ Bt,
    USHORT* __restrict__ Pa, USHORT* __restrict__ Pb,
    int M, int N, int K)
{
    __shared__ USHORT As[2][128 * 64];
    __shared__ USHORT Bs[2][128 * 64];

    const int tid = threadIdx.x;
    const int l   = tid & 63;
    const int w   = tid >> 6;
    const int wr  = w >> 2, wc = w & 3;
    const int lr  = l & 15, lg = l >> 4;

    const int gx  = gridDim.x;
    const int nwg = gx * gridDim.y;
    const int lin = blockIdx.y * gx + blockIdx.x;
    const int swz = (lin & 7) * (nwg >> 3) + (lin >> 3);
    const int my  = swz / gx;
    const int mt  = M >> 7;
    const int part = my / mt;
    const int m0  = (my % mt) << 7;
    const int n0  = (swz % gx) * 128;
    const int koff = part * (K >> 1);
    USHORT* dst = part ? Pb : Pa;

    const USHORT* aS[2]; const USHORT* bS[2]; int dOf[2];
#pragma unroll
    for (int p = 0; p < 2; ++p) {
        const int q = p * 512 + tid;
        const int row = q >> 3, cu = q & 7;
        const int cs = ((cu ^ (row & 7)) << 3);
        aS[p] = A  + (size_t)(m0 + row) * K + cs;
        bS[p] = Bt + (size_t)(n0 + row) * K + cs;
        dOf[p] = (p * 512 + w * 64) * 8;
    }

    auto stage = [&](int buf, int k0) {
#pragma unroll
        for (int p = 0; p < 2; ++p) {
            GLDS(aS[p] + k0, &As[buf][dOf[p]]);
            GLDS(bS[p] + k0, &Bs[buf][dOf[p]]);
        }
    };

    f32x4 acc[4][2];
#pragma unroll
    for (int i = 0; i < 4; ++i)
#pragma unroll
        for (int j = 0; j < 2; ++j) acc[i][j] = (f32x4){0.f, 0.f, 0.f, 0.f};

    const int nk = K >> 7;
    stage(0, koff);

    for (int t = 0; t < nk; ++t) {
        const int cur = t & 1;
        if (t + 1 < nk) {
            stage(cur ^ 1, koff + ((t + 1) << 6));
            WAITVM(4);
        } else {
            WAITVM(0);
        }
        __builtin_amdgcn_s_barrier();

#pragma unroll
        for (int ks = 0; ks < 2; ++ks) {
            short8v bfr[2];
#pragma unroll
            for (int ni = 0; ni < 2; ++ni)
                bfr[ni] = ld_frag(Bs[cur], wc * 32 + ni * 16 + lr, ks * 4 + lg);
            __builtin_amdgcn_s_setprio(1);
#pragma unroll
            for (int mi = 0; mi < 4; ++mi) {
                short8v af = ld_frag(As[cur], wr * 64 + mi * 16 + lr, ks * 4 + lg);
#pragma unroll
                for (int ni = 0; ni < 2; ++ni)
                    acc[mi][ni] = __builtin_amdgcn_mfma_f32_16x16x32_bf16(
                        af, bfr[ni], acc[mi][ni], 0, 0, 0);
            }
            __builtin_amdgcn_s_setprio(0);
        }
        __builtin_amdgcn_s_barrier();
    }

#pragma unroll
    for (int mi = 0; mi < 4; ++mi) {
        const int row = m0 + wr * 64 + mi * 16 + (l >> 4) * 4;
#pragma unroll
        for (int ni = 0; ni < 2; ++ni) {
            const int col = n0 + wc * 32 + ni * 16 + lr;
#pragma unroll
            for (int j = 0; j < 4; ++j)
                dst[(size_t)(row + j) * N + col] = f2bf(acc[mi][ni][j]);
        }
    }
}

// ---------------------------------------------------------------------------
// Weight convert+transpose kernels (unchanged).
// ---------------------------------------------------------------------------
struct TcvtB4 {
    const float* s0; const float* s1; const float* s2; const float* s3;
    USHORT* d0; USHORT* d1; USHORT* d2; USHORT* d3;
};

__device__ __forceinline__ void tcvt_body(
    const float* __restrict__ W, USHORT* __restrict__ Wt, int K, int N)
{
    __shared__ USHORT L[64][65];
    const int tid = threadIdx.x;
    const int tx = tid & 15, ty = tid >> 4;
    const int n0 = blockIdx.x * 64, k0 = blockIdx.y * 64;
#pragma unroll
    for (int r = 0; r < 4; ++r) {
        int kr = ty + 16 * r;
        float4 v = *reinterpret_cast<const float4*>(
            &W[(size_t)(k0 + kr) * N + n0 + tx * 4]);
        L[tx * 4 + 0][kr] = f2bf(v.x);
        L[tx * 4 + 1][kr] = f2bf(v.y);
        L[tx * 4 + 2][kr] = f2bf(v.z);
        L[tx * 4 + 3][kr] = f2bf(v.w);
    }
    __syncthreads();
#pragma unroll
    for (int r = 0; r < 4; ++r) {
        int nr = ty + 16 * r;
        ushort4 o = make_ushort4(L[nr][tx * 4 + 0], L[nr][tx * 4 + 1],
                                 L[nr][tx * 4 + 2], L[nr][tx * 4 + 3]);
        *reinterpret_cast<ushort4*>(&Wt[(size_t)(n0 + nr) * K + k0 + tx * 4]) = o;
    }
}

__global__ __launch_bounds__(256) void tcvt_kernel(
    const float* __restrict__ W, USHORT* __restrict__ Wt, int K, int N)
{
    tcvt_body(W, Wt, K, N);
}

__global__ __launch_bounds__(256) void tcvt4_kernel(TcvtB4 p, int K, int N)
{
    const int z = blockIdx.z;
    const float* W = (z == 0) ? p.s0 : (z == 1) ? p.s1 : (z == 2) ? p.s2 : p.s3;
    USHORT*    Wt = (z == 0) ? p.d0 : (z == 1) ? p.d1 : (z == 2) ? p.d2 : p.d3;
    tcvt_body(W, Wt, K, N);
}

__global__ __launch_bounds__(256) void f2b_kernel(
    const float* __restrict__ in, USHORT* __restrict__ out, int n4)
{
    int i = blockIdx.x * 256 + threadIdx.x;
    if (i < n4) {
        float4 v = reinterpret_cast<const float4*>(in)[i];
        reinterpret_cast<ushort4*>(out)[i] =
            make_ushort4(f2bf(v.x), f2bf(v.y), f2bf(v.z), f2bf(v.w));
    }
}

// ---------------------------------------------------------------------------
// MFMA flash attention (R16 structure: swapped QK^T, per-lane softmax state).
// R18: P pack via pk2bf (__float22bfloat162_rn -> v_cvt_pk, 1 instr per pair
// vs 5-op manual bit-twiddle).
// ---------------------------------------------------------------------------
__global__ __launch_bounds__(256) void attn_mfma_kernel(
    const USHORT* __restrict__ Q, const USHORT* __restrict__ K,
    const USHORT* __restrict__ Vt, USHORT* __restrict__ O, int causal)
{
    __shared__ USHORT smem[40960];                 // 80 KB

    const int tid = threadIdx.x;
    const int l  = tid & 63;
    const int w  = tid >> 6;
    const int lr = l & 15;
    const int lg = l >> 4;

    const int lin = blockIdx.y * 16 + blockIdx.x;   // nwg = 1024
    const int swz = (lin & 7) * 128 + (lin >> 3);
    const int qt = swz & 15;
    const int bh = swz >> 4;
    const int h = bh & 15, b = bh >> 4;
    const int q0 = qt * 64;

    const USHORT* gq  = Q  + (size_t)(b * SEQ + q0) * D_MODEL + h * DH;
    const USHORT* gk0 = K  + (size_t)b * SEQ * D_MODEL + h * DH;
    const USHORT* gv0 = Vt + (size_t)bh * DH * SEQ;

    auto stageK = [&](int buf, int kt) {
        USHORT* dst = smem + buf * 8192;
        const size_t base = (size_t)kt * 128 * 1024;
#pragma unroll
        for (int p = 0; p < 4; ++p) {
            const int q = p * 256 + tid;
            const int row = q >> 3, cu = q & 7;
            GLDS(gk0 + base + (size_t)row * 1024 + ((cu ^ (row & 7)) << 3),
                 dst + (p * 256 + w * 64) * 8);
        }
    };
    auto stageV = [&](int buf, int kt) {
        USHORT* dst = smem + 16384 + buf * 8192;
        const int j0 = kt * 128;
#pragma unroll
        for (int p = 0; p < 4; ++p) {
            const int q = p * 256 + tid;
            const int row = q >> 4, cu = q & 15;
            GLDS(gv0 + (size_t)row * 1024 + j0 + ((cu ^ (row & 15)) << 3),
                 dst + (p * 256 + w * 64) * 8);
        }
    };

#pragma unroll
    for (int p = 0; p < 2; ++p) {
        const int q = p * 256 + tid;
        const int row = q >> 3, cu = q & 7;
        GLDS(gq + (size_t)row * 1024 + ((cu ^ (row & 7)) << 3),
             smem + 32768 + (p * 256 + w * 64) * 8);
    }
    stageK(0, 0);
    stageV(0, 0);

    f32x4 oacc[4];
    float m_ = -1e30f, l_ = 0.f;   // per-lane state for q_own = w*16 + lr
#pragma unroll
    for (int d = 0; d < 4; ++d) oacc[d] = (f32x4){0.f, 0.f, 0.f, 0.f};

    // P write offsets: row = lr, j = jb*16 + lg*4 .. +3 (one b64 per jb)
    int paddr[8];
#pragma unroll
    for (int jb = 0; jb < 8; ++jb) {
        const int cu = jb * 2 + (lg >> 1);
        paddr[jb] = lr * 128 + ((cu ^ lr) << 3) + (lg & 1) * 4;
    }

    __syncthreads();
    short8v qa0 = ld_frag(smem + 32768, w * 16 + lr, lg);
    short8v qa1 = ld_frag(smem + 32768, w * 16 + lr, 4 + lg);
    __syncthreads();
    USHORT* PsW = smem + 32768 + w * 2048;

    const int ntile = causal ? (qt >> 1) + 1 : (SEQ / 128);
    for (int kt = 0; kt < ntile; ++kt) {
        const int cur = kt & 1;
        if (kt + 1 < ntile) {
            stageK(cur ^ 1, kt + 1);
            stageV(cur ^ 1, kt + 1);
        }
        const int j0 = kt * 128;
        const USHORT* KsC = smem + cur * 8192;
        const USHORT* VsC = smem + 16384 + cur * 8192;

        // S^T = mfma(K, Q): lane holds S[q = w*16+lr][j = jb*16 + lg*4 + r]
        f32x4 sa[8];
        __builtin_amdgcn_s_setprio(1);
#pragma unroll
        for (int jb = 0; jb < 8; ++jb) {
            sa[jb] = (f32x4){0.f, 0.f, 0.f, 0.f};
            sa[jb] = __builtin_amdgcn_mfma_f32_16x16x32_bf16(
                ld_frag(KsC, jb * 16 + lr, lg), qa0, sa[jb], 0, 0, 0);
            sa[jb] = __builtin_amdgcn_mfma_f32_16x16x32_bf16(
                ld_frag(KsC, jb * 16 + lr, 4 + lg), qa1, sa[jb], 0, 0, 0);
        }
        __builtin_amdgcn_s_setprio(0);

        if (causal && kt == ntile - 1) {
#pragma unroll
            for (int jb = 0; jb < 8; ++jb)
#pragma unroll
                for (int r = 0; r < 4; ++r)
                    if ((j0 + jb * 16 + lg * 4 + r) > (q0 + w * 16 + lr))
                        sa[jb][r] = -1e30f;
        }

        // per-lane tile max over 32 values + cross-lg reduce (2 shfls)
        float tm = max3f(
            max3f(max3f(sa[0][0], sa[0][1], sa[0][2]),
                  max3f(sa[0][3], sa[1][0], sa[1][1]),
                  max3f(sa[1][2], sa[1][3], sa[2][0])),
            max3f(max3f(sa[2][1], sa[2][2], sa[2][3]),
                  max3f(sa[3][0], sa[3][1], sa[3][2]),
                  max3f(sa[3][3], sa[4][0], sa[4][1])),
            max3f(max3f(max3f(sa[4][2], sa[4][3], sa[5][0]),
                        max3f(sa[5][1], sa[5][2], sa[5][3]),
                        max3f(sa[6][0], sa[6][1], sa[6][2])),
                  max3f(sa[6][3], sa[7][0], sa[7][1]),
                  fmaxf(sa[7][2], sa[7][3])));
        tm = fmaxf(tm, __shfl_xor(tm, 16));
        tm = fmaxf(tm, __shfl_xor(tm, 32));

        // defer-max rescale (wave-gated; broadcast sc from owner lanes)
        if (__ballot(tm > m_ + 8.f)) {
            const float mn = (tm > m_ + 8.f) ? tm : m_;
            const float sc = exp2f(m_ - mn);
            l_ *= sc;
            m_ = mn;
#pragma unroll
            for (int r = 0; r < 4; ++r) {
                const float scr = __shfl(sc, (l & 48) | (lg * 4 + r));
#pragma unroll
                for (int d = 0; d < 4; ++d) oacc[d][r] *= scr;
            }
        }

        // exp (log2 domain) + lane-partial sum + HW pack + b64 P-writes
#pragma unroll
        for (int jb = 0; jb < 8; ++jb) {
            const float p0 = exp2f(sa[jb][0] - m_);
            const float p1 = exp2f(sa[jb][1] - m_);
            const float p2 = exp2f(sa[jb][2] - m_);
            const float p3 = exp2f(sa[jb][3] - m_);
            l_ += (p0 + p1) + (p2 + p3);
            *reinterpret_cast<uint2*>(&PsW[paddr[jb]]) =
                make_uint2(pk2bf(p0, p1), pk2bf(p2, p3));
        }

        // PV: oacc[d] += P(16q x 32j) * V(32j x 16d)
        __builtin_amdgcn_s_setprio(1);
#pragma unroll
        for (int ks = 0; ks < 4; ++ks) {
            short8v pa = ld128(PsW, lr, ks * 4 + lg);
#pragma unroll
            for (int d = 0; d < 4; ++d)
                oacc[d] = __builtin_amdgcn_mfma_f32_16x16x32_bf16(
                    pa, ld128(VsC, d * 16 + lr, ks * 4 + lg), oacc[d], 0, 0, 0);
        }
        __builtin_amdgcn_s_setprio(0);
        __syncthreads();   // drains prefetch + guards K/V/P buffer reuse
    }

    // epilogue: cross-lg l sum, then per-output-row inv via owner-lane shfl
    float lv = l_;
    lv += __shfl_xor(lv, 16);
    lv += __shfl_xor(lv, 32);
    const float inv_own = 1.f / lv;

    USHORT* go = O + (size_t)(b * SEQ + q0 + w * 16) * D_MODEL + h * DH;
#pragma unroll
    for (int r = 0; r < 4; ++r) {
        const float inv = __shfl(inv_own, (l & 48) | (lg * 4 + r));
        const int qrow = lg * 4 + r;
#pragma unroll
        for (int d = 0; d < 4; ++d)
            go[(size_t)qrow * D_MODEL + d * 16 + lr] = f2bf_fast(oacc[d][r] * inv);
    }
}

// ---------------------------------------------------------------------------
// out = res + LayerNorm(x)*g + b, where x = xb (+ xb2) (+ biasx). (unchanged)
// ---------------------------------------------------------------------------
__global__ __launch_bounds__(256) void ln_res_kernel(
    const USHORT* __restrict__ xb, const USHORT* __restrict__ xb2,
    const float* __restrict__ biasx,
    const float* __restrict__ resf, const USHORT* __restrict__ resb,
    const float* __restrict__ g, const float* __restrict__ bta,
    float* __restrict__ outf, USHORT* __restrict__ outb)
{
    __shared__ float red[256];
    __shared__ float s_mu, s_rstd;

    const int row = blockIdx.x;
    const int tid = threadIdx.x;
    ushort4 xv = reinterpret_cast<const ushort4*>(xb + (size_t)row * D_MODEL)[tid];
    float vx = bf2f(xv.x), vy = bf2f(xv.y), vz = bf2f(xv.z), vw = bf2f(xv.w);
    if (xb2) {
        ushort4 x2 = reinterpret_cast<const ushort4*>(
            xb2 + (size_t)row * D_MODEL)[tid];
        vx += bf2f(x2.x); vy += bf2f(x2.y); vz += bf2f(x2.z); vw += bf2f(x2.w);
    }
    if (biasx) {
        float4 bx = reinterpret_cast<const float4*>(biasx)[tid];
        vx += bx.x; vy += bx.y; vz += bx.z; vw += bx.w;
    }

    red[tid] = vx + vy + vz + vw;
    __syncthreads();
    for (int s = 128; s > 0; s >>= 1) {
        if (tid < s) red[tid] += red[tid + s];
        __syncthreads();
    }
    if (tid == 0) s_mu = red[0] * (1.f / D_MODEL);
    __syncthreads();
    const float mu = s_mu;

    float dx = vx - mu, dy = vy - mu, dz = vz - mu, dw = vw - mu;
    red[tid] = dx * dx + dy * dy + dz * dz + dw * dw;
    __syncthreads();
    for (int s = 128; s > 0; s >>= 1) {
        if (tid < s) red[tid] += red[tid + s];
        __syncthreads();
    }
    if (tid == 0) s_rstd = rsqrtf(red[0] * (1.f / D_MODEL) + EPS);
    __syncthreads();
    const float rstd = s_rstd;

    float4 rv;
    if (resf) {
        rv = reinterpret_cast<const float4*>(resf + (size_t)row * D_MODEL)[tid];
    } else if (resb) {
        ushort4 rb = reinterpret_cast<const ushort4*>(
            resb + (size_t)row * D_MODEL)[tid];
        rv = make_float4(bf2f(rb.x), bf2f(rb.y), bf2f(rb.z), bf2f(rb.w));
    } else {
        rv = make_float4(vx, vy, vz, vw);          // res = x (norm_attn2 wiring)
    }
    float4 gv = reinterpret_cast<const float4*>(g)[tid];
    float4 bv = reinterpret_cast<const float4*>(bta)[tid];

    float4 o;
    o.x = rv.x + dx * rstd * gv.x + bv.x;
    o.y = rv.y + dy * rstd * gv.y + bv.y;
    o.z = rv.z + dz * rstd * gv.z + bv.z;
    o.w = rv.w + dw * rstd * gv.w + bv.w;
    reinterpret_cast<float4*>(outf + (size_t)row * D_MODEL)[tid] = o;
    if (outb)
        reinterpret_cast<ushort4*>(outb + (size_t)row * D_MODEL)[tid] =
            make_ushort4(f2bf(o.x), f2bf(o.y), f2bf(o.z), f2bf(o.w));
}

// ---------------------------------------------------------------------------
extern "C" void kernel_launch(void* const* d_in, const int* in_sizes, int n_in,
                              void* d_out, int out_size, void* d_ws, size_t ws_size,
                              hipStream_t stream)
{
    const float* X    = (const float*)d_in[0];
    const float* Wq1  = (const float*)d_in[1];
    const float* Wk1  = (const float*)d_in[2];
    const float* Wv1  = (const float*)d_in[3];
    const float* Wo1  = (const float*)d_in[4];
    const float* Wq2  = (const float*)d_in[5];
    const float* Wk2  = (const float*)d_in[6];
    const float* Wv2  = (const float*)d_in[7];
    const float* Wo2  = (const float*)d_in[8];
    const float* ln_g = (const float*)d_in[9];
    const float* ln_b = (const float*)d_in[10];
    const float* W1   = (const float*)d_in[11];
    const float* b1   = (const float*)d_in[12];
    const float* W2   = (const float*)d_in[13];
    const float* b2   = (const float*)d_in[14];

    const size_t MI = 1024 * 1024;
    USHORT* ws16 = (USHORT*)d_ws;
    USHORT* Wqkv1t = ws16;                 // [0,3Mi); also scr0 after MHA1
    USHORT* scr0   = ws16;
    USHORT* Wo1t   = ws16 + 3 * MI;
    USHORT* Wqkv2t = ws16 + 4 * MI;
    USHORT* Wo2t   = ws16 + 7 * MI;
    USHORT* W2t    = ws16 + 8 * MI;
    USHORT* Xb     = ws16 + 12 * MI;
    USHORT* W1t    = Xb;
    USHORT* qb     = ws16 + 16 * MI;
    USHORT* kb     = ws16 + 20 * MI;
    USHORT* Vtb    = ws16 + 24 * MI;
    USHORT* t0b    = ws16 + 28 * MI;
    USHORT* hb     = qb;
    USHORT* t2b    = ws16 + 32 * MI;
    USHORT* t1b    = ws16 + 36 * MI;
    float*  t2     = (float*)(ws16 + 40 * MI);

    auto gemm256 = [&](const USHORT* A, const USHORT* Bt, float* Cf, USHORT* Cb,
                       int M, int N, int K, const float* bias, int relu) {
        gemm_k256_kernel<<<dim3(N / 256, M / 256), 512, 0, stream>>>(
            A, Bt, Cf, Cb, nullptr, nullptr, M, N, K, bias, relu, 0);
    };
    auto gemm_qkv = [&](const USHORT* A, const USHORT* Bt) {
        gemm_k256_kernel<<<dim3(3072 / 256, TOK / 256), 512, 0, stream>>>(
            A, Bt, nullptr, qb, kb, Vtb, TOK, 3072, D_MODEL, nullptr, 0, 1);
    };
    auto gemm128c = [&](const USHORT* A, const USHORT* Bt, USHORT* Pa, USHORT* Pb,
                        int M, int N, int K) {
        gemm_k128c_kernel<<<dim3(N / 128, (M / 128) * 2), 512, 0, stream>>>(
            A, Bt, Pa, Pb, M, N, K);
    };

    dim3 agrid(SEQ / 64, BATCH * N_HEADS);

    // ---- prologue: all square weights + W2 + X -> bf16 ----
    {
        TcvtB4 p1{Wq1, Wk1, Wv1, Wo1,
                  Wqkv1t, Wqkv1t + 1 * MI, Wqkv1t + 2 * MI, Wo1t};
        tcvt4_kernel<<<dim3(16, 16, 4), 256, 0, stream>>>(p1, D_MODEL, D_MODEL);
        TcvtB4 p2{Wq2, Wk2, Wv2, Wo2,
                  Wqkv2t, Wqkv2t + 1 * MI, Wqkv2t + 2 * MI, Wo2t};
        tcvt4_kernel<<<dim3(16, 16, 4), 256, 0, stream>>>(p2, D_MODEL, D_MODEL);
    }
    tcvt_kernel<<<dim3(D_MODEL / 64, D_FF / 64), 256, 0, stream>>>(
        W2, W2t, D_FF, D_MODEL);
    f2b_kernel<<<dim3(4096), 256, 0, stream>>>(X, Xb, TOK * D_MODEL / 4);

    // ---- MHA 1 (causal) ----
    gemm_qkv(Xb, Wqkv1t);
    attn_mfma_kernel<<<agrid, 256, 0, stream>>>(qb, kb, Vtb, t0b, 1);
    gemm128c(t0b, Wo1t, t2b, t1b, TOK, D_MODEL, D_MODEL);     // masked = t2b+t1b
    ln_res_kernel<<<dim3(TOK), 256, 0, stream>>>(t2b, t1b, nullptr, X, nullptr,
                                                 ln_g, ln_b, t2, t2b);
    tcvt_kernel<<<dim3(D_FF / 64, D_MODEL / 64), 256, 0, stream>>>(
        W1, W1t, D_MODEL, D_FF);

    // ---- MHA 2 (full) ----
    gemm_qkv(t2b, Wqkv2t);
    attn_mfma_kernel<<<agrid, 256, 0, stream>>>(qb, kb, Vtb, t0b, 0);
    gemm128c(t0b, Wo2t, scr0, t1b, TOK, D_MODEL, D_MODEL);    // attn2 = scr0+t1b
    ln_res_kernel<<<dim3(TOK), 256, 0, stream>>>(scr0, t1b, nullptr,
                                                 nullptr, nullptr,   // res = x
                                                 ln_g, ln_b, t2, t2b);

    // ---- FFN ----
    gemm256(t2b, W1t, nullptr, hb, TOK, D_FF, D_MODEL, b1, 1);
    gemm128c(hb, W2t, t2b, t1b, TOK, D_MODEL, D_FF);          // ff = t2b+t1b+b2
    ln_res_kernel<<<dim3(TOK), 256, 0, stream>>>(t2b, t1b, b2, t2, nullptr,
                                                 ln_g, ln_b, (float*)d_out, nullptr);
}

// Round 19
// 335.113 us; speedup vs baseline: 1.0096x; 1.0096x over previous
//
#include <hip/hip_runtime.h>
#include <hip/hip_bf16.h>

#define D_MODEL 1024
#define N_HEADS 16
#define DH 64
#define D_FF   4096
#define SEQ    1024
#define BATCH  4
#define TOK    (BATCH*SEQ)
#define EPS    1e-5f
#define SCALE  0.125f           // 1/sqrt(64)
#define QSCL   0.18033688f      // SCALE * log2(e): QK^T lands in log2 domain

typedef unsigned short USHORT;
typedef __attribute__((ext_vector_type(8))) short short8v;
typedef __attribute__((ext_vector_type(4))) float f32x4;

__device__ __forceinline__ USHORT f2bf(float f) {
    unsigned int u; __builtin_memcpy(&u, &f, 4);
    u += 0x7fffu + ((u >> 16) & 1u);          // RNE
    return (USHORT)(u >> 16);
}
// 2-op round-half-up pack (P in (0,256] and O: error == RNE magnitude)
__device__ __forceinline__ USHORT f2bf_fast(float f) {
    unsigned int u; __builtin_memcpy(&u, &f, 4);
    return (USHORT)((u + 0x8000u) >> 16);
}
// HW pack: 2 floats -> u32 of 2 bf16 (RNE, v_cvt_pk path); lo -> bits [15:0]
__device__ __forceinline__ unsigned pk2bf(float lo, float hi) {
    __hip_bfloat162 h = __float22bfloat162_rn(make_float2(lo, hi));
    unsigned u; __builtin_memcpy(&u, &h, 4);
    return u;
}
__device__ __forceinline__ float bf2f(USHORT s) {
    unsigned int u = ((unsigned int)s) << 16;
    float f; __builtin_memcpy(&f, &u, 4);
    return f;
}
__device__ __forceinline__ float max3f(float a, float b, float c) {
    return fmaxf(fmaxf(a, b), c);             // fuses to v_max3_f32
}

// row-stride-64 swizzled read: unit ^= row&7
__device__ __forceinline__ short8v ld_frag(const USHORT* lds, int row, int c8) {
    return *reinterpret_cast<const short8v*>(
        &lds[row * 64 + (((c8) ^ (row & 7)) << 3)]);
}

#define GLDS(gsrc, ldst) \
    __builtin_amdgcn_global_load_lds( \
        (const __attribute__((address_space(1))) void*)(gsrc), \
        (__attribute__((address_space(3))) void*)(ldst), 16, 0, 0)

#define WAITVM(n) asm volatile("s_waitcnt vmcnt(" #n ")" ::: "memory")

// ---------------------------------------------------------------------------
// bf16 MFMA GEMM, 256x256 tile, BK=64, 512 threads = 8 waves (2M x 4N).
// 2-buffer counted-vmcnt pipeline. Epilogues: normal or fused-QKV routing.
// (unchanged from R18)
// ---------------------------------------------------------------------------
__global__ __launch_bounds__(512) void gemm_k256_kernel(
    const USHORT* __restrict__ A, const USHORT* __restrict__ Bt,
    float* __restrict__ Cf, USHORT* __restrict__ Cb, USHORT* __restrict__ Ck,
    USHORT* __restrict__ VtOut,
    int M, int N, int K, const float* __restrict__ bias, int relu, int qkv)
{
    __shared__ USHORT As[2][256 * 64];
    __shared__ USHORT Bs[2][256 * 64];

    const int tid = threadIdx.x;
    const int l   = tid & 63;
    const int w   = tid >> 6;              // 0..7
    const int wr  = w >> 2, wc = w & 3;    // 2 x 4 wave grid
    const int lr  = l & 15, lg = l >> 4;

    const int gx  = gridDim.x;
    const int nwg = gx * gridDim.y;
    const int lin = blockIdx.y * gx + blockIdx.x;
    const int swz = (lin & 7) * (nwg >> 3) + (lin >> 3);
    const int m0  = (swz / gx) * 256, n0 = (swz % gx) * 256;

    const USHORT* aS[4]; const USHORT* bS[4]; int dOf[4];
#pragma unroll
    for (int p = 0; p < 4; ++p) {
        const int q = p * 512 + tid;
        const int row = q >> 3, cu = q & 7;
        const int cs = ((cu ^ (row & 7)) << 3);
        aS[p] = A  + (size_t)(m0 + row) * K + cs;
        bS[p] = Bt + (size_t)(n0 + row) * K + cs;
        dOf[p] = (p * 512 + w * 64) * 8;
    }

    auto stage = [&](int buf, int k0) {
#pragma unroll
        for (int p = 0; p < 4; ++p) {
            GLDS(aS[p] + k0, &As[buf][dOf[p]]);
            GLDS(bS[p] + k0, &Bs[buf][dOf[p]]);
        }
    };

    f32x4 acc[8][4];
#pragma unroll
    for (int i = 0; i < 8; ++i)
#pragma unroll
        for (int j = 0; j < 4; ++j) acc[i][j] = (f32x4){0.f, 0.f, 0.f, 0.f};

    const int nk = K >> 6;
    stage(0, 0);

    for (int t = 0; t < nk; ++t) {
        const int cur = t & 1;
        if (t + 1 < nk) {
            stage(cur ^ 1, (t + 1) << 6);
            WAITVM(8);
        } else {
            WAITVM(0);
        }
        __builtin_amdgcn_s_barrier();

#pragma unroll
        for (int ks = 0; ks < 2; ++ks) {
            short8v bfr[4];
#pragma unroll
            for (int ni = 0; ni < 4; ++ni)
                bfr[ni] = ld_frag(Bs[cur], wc * 64 + ni * 16 + lr, ks * 4 + lg);
            __builtin_amdgcn_s_setprio(1);
#pragma unroll
            for (int mi = 0; mi < 8; ++mi) {
                short8v af = ld_frag(As[cur], wr * 128 + mi * 16 + lr, ks * 4 + lg);
#pragma unroll
                for (int ni = 0; ni < 4; ++ni)
                    acc[mi][ni] = __builtin_amdgcn_mfma_f32_16x16x32_bf16(
                        af, bfr[ni], acc[mi][ni], 0, 0, 0);
            }
            __builtin_amdgcn_s_setprio(0);
        }
        __builtin_amdgcn_s_barrier();
    }

    // epilogue: C/D layout col = lane&15, row = (lane>>4)*4 + reg
    if (qkv) {
#pragma unroll
        for (int mi = 0; mi < 8; ++mi) {
            const int row = m0 + wr * 128 + mi * 16 + (l >> 4) * 4;
#pragma unroll
            for (int ni = 0; ni < 4; ++ni) {
                const int col = n0 + wc * 64 + ni * 16 + lr;
                if (col < 2048) {
                    USHORT* dst = (col < 1024) ? Cb : Ck;
                    const float scl = (col < 1024) ? QSCL : 1.f;  // log2-e domain
                    const int c = col & 1023;
#pragma unroll
                    for (int j = 0; j < 4; ++j)
                        dst[(size_t)(row + j) * D_MODEL + c] =
                            f2bf(acc[mi][ni][j] * scl);
                } else {
                    const int c = col - 2048;
                    const int bb = row >> 10, jr = row & 1023;
                    const int hh = c >> 6, dd = c & 63;
                    uint2 pk = make_uint2(
                        pk2bf(acc[mi][ni][0], acc[mi][ni][1]),
                        pk2bf(acc[mi][ni][2], acc[mi][ni][3]));
                    *reinterpret_cast<uint2*>(
                        &VtOut[((size_t)(bb * 16 + hh) * 64 + dd) * 1024 + jr]) = pk;
                }
            }
        }
    } else {
#pragma unroll
        for (int mi = 0; mi < 8; ++mi) {
            const int row = m0 + wr * 128 + mi * 16 + (l >> 4) * 4;
#pragma unroll
            for (int ni = 0; ni < 4; ++ni) {
                const int col = n0 + wc * 64 + ni * 16 + lr;
                const float bv = bias ? bias[col] : 0.f;
#pragma unroll
                for (int j = 0; j < 4; ++j) {
                    float v = acc[mi][ni][j] + bv;
                    if (relu) v = fmaxf(v, 0.f);
                    const size_t idx = (size_t)(row + j) * N + col;
                    if (Cf) Cf[idx] = v;
                    if (Cb) Cb[idx] = f2bf(v);
                }
            }
        }
    }
}

// ---------------------------------------------------------------------------
// Split-K bf16 GEMM for the N=1024 shapes: 128x128 tile, BK=64, 2-buffer
// counted-vmcnt, 8 waves. Split-K=2, bf16 partials. (unchanged from R15)
// ---------------------------------------------------------------------------
__global__ __launch_bounds__(512) void gemm_k128c_kernel(
    const USHORT* __restrict__ A, const USHORT* __restrict__ Bt,
    USHORT* __restrict__ Pa, USHORT* __restrict__ Pb,
    int M, int N, int K)
{
    __shared__ USHORT As[2][128 * 64];
    __shared__ USHORT Bs[2][128 * 64];

    const int tid = threadIdx.x;
    const int l   = tid & 63;
    const int w   = tid >> 6;
    const int wr  = w >> 2, wc = w & 3;
    const int lr  = l & 15, lg = l >> 4;

    const int gx  = gridDim.x;
    const int nwg = gx * gridDim.y;
    const int lin = blockIdx.y * gx + blockIdx.x;
    const int swz = (lin & 7) * (nwg >> 3) + (lin >> 3);
    const int my  = swz / gx;
    const int mt  = M >> 7;
    const int part = my / mt;
    const int m0  = (my % mt) << 7;
    const int n0  = (swz % gx) * 128;
    const int koff = part * (K >> 1);
    USHORT* dst = part ? Pb : Pa;

    const USHORT* aS[2]; const USHORT* bS[2]; int dOf[2];
#pragma unroll
    for (int p = 0; p < 2; ++p) {
        const int q = p * 512 + tid;
        const int row = q >> 3, cu = q & 7;
        const int cs = ((cu ^ (row & 7)) << 3);
        aS[p] = A  + (size_t)(m0 + row) * K + cs;
        bS[p] = Bt + (size_t)(n0 + row) * K + cs;
        dOf[p] = (p * 512 + w * 64) * 8;
    }

    auto stage = [&](int buf, int k0) {
#pragma unroll
        for (int p = 0; p < 2; ++p) {
            GLDS(aS[p] + k0, &As[buf][dOf[p]]);
            GLDS(bS[p] + k0, &Bs[buf][dOf[p]]);
        }
    };

    f32x4 acc[4][2];
#pragma unroll
    for (int i = 0; i < 4; ++i)
#pragma unroll
        for (int j = 0; j < 2; ++j) acc[i][j] = (f32x4){0.f, 0.f, 0.f, 0.f};

    const int nk = K >> 7;
    stage(0, koff);

    for (int t = 0; t < nk; ++t) {
        const int cur = t & 1;
        if (t + 1 < nk) {
            stage(cur ^ 1, koff + ((t + 1) << 6));
            WAITVM(4);
        } else {
            WAITVM(0);
        }
        __builtin_amdgcn_s_barrier();

#pragma unroll
        for (int ks = 0; ks < 2; ++ks) {
            short8v bfr[2];
#pragma unroll
            for (int ni = 0; ni < 2; ++ni)
                bfr[ni] = ld_frag(Bs[cur], wc * 32 + ni * 16 + lr, ks * 4 + lg);
            __builtin_amdgcn_s_setprio(1);
#pragma unroll
            for (int mi = 0; mi < 4; ++mi) {
                short8v af = ld_frag(As[cur], wr * 64 + mi * 16 + lr, ks * 4 + lg);
#pragma unroll
                for (int ni = 0; ni < 2; ++ni)
                    acc[mi][ni] = __builtin_amdgcn_mfma_f32_16x16x32_bf16(
                        af, bfr[ni], acc[mi][ni], 0, 0, 0);
            }
            __builtin_amdgcn_s_setprio(0);
        }
        __builtin_amdgcn_s_barrier();
    }

#pragma unroll
    for (int mi = 0; mi < 4; ++mi) {
        const int row = m0 + wr * 64 + mi * 16 + (l >> 4) * 4;
#pragma unroll
        for (int ni = 0; ni < 2; ++ni) {
            const int col = n0 + wc * 32 + ni * 16 + lr;
#pragma unroll
            for (int j = 0; j < 4; ++j)
                dst[(size_t)(row + j) * N + col] = f2bf(acc[mi][ni][j]);
        }
    }
}

// ---------------------------------------------------------------------------
// Weight convert+transpose kernels (unchanged).
// ---------------------------------------------------------------------------
struct TcvtB4 {
    const float* s0; const float* s1; const float* s2; const float* s3;
    USHORT* d0; USHORT* d1; USHORT* d2; USHORT* d3;
};

__device__ __forceinline__ void tcvt_body(
    const float* __restrict__ W, USHORT* __restrict__ Wt, int K, int N)
{
    __shared__ USHORT L[64][65];
    const int tid = threadIdx.x;
    const int tx = tid & 15, ty = tid >> 4;
    const int n0 = blockIdx.x * 64, k0 = blockIdx.y * 64;
#pragma unroll
    for (int r = 0; r < 4; ++r) {
        int kr = ty + 16 * r;
        float4 v = *reinterpret_cast<const float4*>(
            &W[(size_t)(k0 + kr) * N + n0 + tx * 4]);
        L[tx * 4 + 0][kr] = f2bf(v.x);
        L[tx * 4 + 1][kr] = f2bf(v.y);
        L[tx * 4 + 2][kr] = f2bf(v.z);
        L[tx * 4 + 3][kr] = f2bf(v.w);
    }
    __syncthreads();
#pragma unroll
    for (int r = 0; r < 4; ++r) {
        int nr = ty + 16 * r;
        ushort4 o = make_ushort4(L[nr][tx * 4 + 0], L[nr][tx * 4 + 1],
                                 L[nr][tx * 4 + 2], L[nr][tx * 4 + 3]);
        *reinterpret_cast<ushort4*>(&Wt[(size_t)(n0 + nr) * K + k0 + tx * 4]) = o;
    }
}

__global__ __launch_bounds__(256) void tcvt_kernel(
    const float* __restrict__ W, USHORT* __restrict__ Wt, int K, int N)
{
    tcvt_body(W, Wt, K, N);
}

__global__ __launch_bounds__(256) void tcvt4_kernel(TcvtB4 p, int K, int N)
{
    const int z = blockIdx.z;
    const float* W = (z == 0) ? p.s0 : (z == 1) ? p.s1 : (z == 2) ? p.s2 : p.s3;
    USHORT*    Wt = (z == 0) ? p.d0 : (z == 1) ? p.d1 : (z == 2) ? p.d2 : p.d3;
    tcvt_body(W, Wt, K, N);
}

__global__ __launch_bounds__(256) void f2b_kernel(
    const float* __restrict__ in, USHORT* __restrict__ out, int n4)
{
    int i = blockIdx.x * 256 + threadIdx.x;
    if (i < n4) {
        float4 v = reinterpret_cast<const float4*>(in)[i];
        reinterpret_cast<ushort4*>(out)[i] =
            make_ushort4(f2bf(v.x), f2bf(v.y), f2bf(v.z), f2bf(v.w));
    }
}

// ---------------------------------------------------------------------------
// MFMA flash attention, R19: QBLK=128, KVBLK=64. Block = (b,h, 128 q-rows),
// 4 waves; wave owns TWO 16-row q-subtiles (q = w*32 + s*16 + lr) sharing
// every K/V fragment read (ds_reads/work 36->20 per 32 MFMA) and halving
// staging. LDS = 48 KB (K dbuf 16 + V dbuf 16 + union(Q 16, P 16)) ->
// 3 blocks/CU; grid 512 blocks fully co-resident.
// Swapped QK^T (mfma(K,Q)), per-lane softmax state per qsub, log2 domain,
// defer-max, lane-partial l, HW cvt_pk P pack, one b64 P-write per (s,jb).
// LDS map (ushort offsets): K buf0 @0, buf1 @4096; V buf0 @8192, buf1 @12288;
// QP @16384 (Q [128][64] until consumed; then P per-wave 32x64 @ +w*2048).
// ---------------------------------------------------------------------------
__global__ __launch_bounds__(256) void attn_mfma_kernel(
    const USHORT* __restrict__ Q, const USHORT* __restrict__ K,
    const USHORT* __restrict__ Vt, USHORT* __restrict__ O, int causal)
{
    __shared__ USHORT smem[24576];                 // 48 KB

    const int tid = threadIdx.x;
    const int l  = tid & 63;
    const int w  = tid >> 6;
    const int lr = l & 15;
    const int lg = l >> 4;

    const int lin = blockIdx.y * 8 + blockIdx.x;    // nwg = 512
    const int swz = (lin & 7) * 64 + (lin >> 3);
    const int qt = swz & 7;
    const int bh = swz >> 3;
    const int h = bh & 15, b = bh >> 4;
    const int q0 = qt * 128;

    const USHORT* gq  = Q  + (size_t)(b * SEQ + q0) * D_MODEL + h * DH;
    const USHORT* gk0 = K  + (size_t)b * SEQ * D_MODEL + h * DH;
    const USHORT* gv0 = Vt + (size_t)bh * DH * SEQ;

    auto stageK = [&](int buf, int kt) {           // 64x64, row&7 swizzle
        USHORT* dst = smem + buf * 4096;
        const size_t base = (size_t)kt * 64 * 1024;
#pragma unroll
        for (int p = 0; p < 2; ++p) {
            const int q = p * 256 + tid;
            const int row = q >> 3, cu = q & 7;
            GLDS(gk0 + base + (size_t)row * 1024 + ((cu ^ (row & 7)) << 3),
                 dst + (p * 256 + w * 64) * 8);
        }
    };
    auto stageV = [&](int buf, int kt) {           // 64 d x 64 j, row&7 swizzle
        USHORT* dst = smem + 8192 + buf * 4096;
        const int j0 = kt * 64;
#pragma unroll
        for (int p = 0; p < 2; ++p) {
            const int q = p * 256 + tid;
            const int row = q >> 3, cu = q & 7;
            GLDS(gv0 + (size_t)row * 1024 + j0 + ((cu ^ (row & 7)) << 3),
                 dst + (p * 256 + w * 64) * 8);
        }
    };

    // stage Q (128x64, row&7 swizzle) + first K/V tile
#pragma unroll
    for (int p = 0; p < 4; ++p) {
        const int q = p * 256 + tid;
        const int row = q >> 3, cu = q & 7;
        GLDS(gq + (size_t)row * 1024 + ((cu ^ (row & 7)) << 3),
             smem + 16384 + (p * 256 + w * 64) * 8);
    }
    stageK(0, 0);
    stageV(0, 0);

    f32x4 oacc[2][4];
    float m_[2], l_[2];            // per-lane state for q = w*32 + s*16 + lr
#pragma unroll
    for (int s = 0; s < 2; ++s) {
        m_[s] = -1e30f; l_[s] = 0.f;
#pragma unroll
        for (int d = 0; d < 4; ++d) oacc[s][d] = (f32x4){0.f, 0.f, 0.f, 0.f};
    }

    // P write offsets: row = s*16+lr, j = jb*16 + lg*4 .. +3 (one b64 each)
    int paddr[2][4];
#pragma unroll
    for (int s = 0; s < 2; ++s) {
        const int row = s * 16 + lr;
#pragma unroll
        for (int jb = 0; jb < 4; ++jb) {
            const int cu = jb * 2 + (lg >> 1);
            paddr[s][jb] = row * 64 + ((cu ^ (row & 7)) << 3) + (lg & 1) * 4;
        }
    }

    __syncthreads();                               // Q + tile 0 staged
    short8v qa[2][2];
#pragma unroll
    for (int s = 0; s < 2; ++s) {
        qa[s][0] = ld_frag(smem + 16384, w * 32 + s * 16 + lr, lg);
        qa[s][1] = ld_frag(smem + 16384, w * 32 + s * 16 + lr, 4 + lg);
    }
    __syncthreads();                               // Q consumed -> P may reuse
    USHORT* PsW = smem + 16384 + w * 2048;         // per-wave P [32 q][64 j]

    const int ntile = causal ? (qt * 2 + 2) : (SEQ / 64);
    for (int kt = 0; kt < ntile; ++kt) {
        const int cur = kt & 1;
        if (kt + 1 < ntile) {                      // prefetch next K/V tile
            stageK(cur ^ 1, kt + 1);
            stageV(cur ^ 1, kt + 1);
        }
        const int j0 = kt * 64;
        const USHORT* KsC = smem + cur * 4096;
        const USHORT* VsC = smem + 8192 + cur * 4096;

        // S^T = mfma(K, Q); K frags shared across both q-subtiles
        f32x4 sa[2][4];
        __builtin_amdgcn_s_setprio(1);
#pragma unroll
        for (int jb = 0; jb < 4; ++jb) {
            short8v kf0 = ld_frag(KsC, jb * 16 + lr, lg);
            short8v kf1 = ld_frag(KsC, jb * 16 + lr, 4 + lg);
#pragma unroll
            for (int s = 0; s < 2; ++s) {
                sa[s][jb] = (f32x4){0.f, 0.f, 0.f, 0.f};
                sa[s][jb] = __builtin_amdgcn_mfma_f32_16x16x32_bf16(
                    kf0, qa[s][0], sa[s][jb], 0, 0, 0);
                sa[s][jb] = __builtin_amdgcn_mfma_f32_16x16x32_bf16(
                    kf1, qa[s][1], sa[s][jb], 0, 0, 0);
            }
        }
        __builtin_amdgcn_s_setprio(0);

        // causal mask: only the last two tiles can cross the diagonal
        if (causal && kt >= ntile - 2) {
#pragma unroll
            for (int s = 0; s < 2; ++s) {
                const int qrow = q0 + w * 32 + s * 16 + lr;
#pragma unroll
                for (int jb = 0; jb < 4; ++jb)
#pragma unroll
                    for (int r = 0; r < 4; ++r)
                        if ((j0 + jb * 16 + lg * 4 + r) > qrow)
                            sa[s][jb][r] = -1e30f;
            }
        }

        // per-lane tile max over 16 values per qsub + 2 shfl each
        float tm[2];
#pragma unroll
        for (int s = 0; s < 2; ++s) {
            float t1 = max3f(sa[s][0][0], sa[s][0][1], sa[s][0][2]);
            float t2 = max3f(sa[s][0][3], sa[s][1][0], sa[s][1][1]);
            float t3 = max3f(sa[s][1][2], sa[s][1][3], sa[s][2][0]);
            float t4 = max3f(sa[s][2][1], sa[s][2][2], sa[s][2][3]);
            float t5 = max3f(sa[s][3][0], sa[s][3][1], sa[s][3][2]);
            float tv = fmaxf(max3f(max3f(t1, t2, t3), t4, t5), sa[s][3][3]);
            tv = fmaxf(tv, __shfl_xor(tv, 16));
            tv = fmaxf(tv, __shfl_xor(tv, 32));
            tm[s] = tv;
        }

        // defer-max rescale (wave-gated; broadcast sc from owner lanes)
        const bool anyf = (tm[0] > m_[0] + 8.f) | (tm[1] > m_[1] + 8.f);
        if (__ballot(anyf)) {
            float sc[2];
#pragma unroll
            for (int s = 0; s < 2; ++s) {
                const float mn = (tm[s] > m_[s] + 8.f) ? tm[s] : m_[s];
                sc[s] = exp2f(m_[s] - mn);
                l_[s] *= sc[s];
                m_[s] = mn;
            }
#pragma unroll
            for (int s = 0; s < 2; ++s)
#pragma unroll
                for (int r = 0; r < 4; ++r) {
                    const float scr = __shfl(sc[s], (l & 48) | (lg * 4 + r));
#pragma unroll
                    for (int d = 0; d < 4; ++d) oacc[s][d][r] *= scr;
                }
        }

        // exp (log2 domain) + lane-partial sum + HW pack + b64 P-writes
#pragma unroll
        for (int s = 0; s < 2; ++s)
#pragma unroll
            for (int jb = 0; jb < 4; ++jb) {
                const float p0 = exp2f(sa[s][jb][0] - m_[s]);
                const float p1 = exp2f(sa[s][jb][1] - m_[s]);
                const float p2 = exp2f(sa[s][jb][2] - m_[s]);
                const float p3 = exp2f(sa[s][jb][3] - m_[s]);
                l_[s] += (p0 + p1) + (p2 + p3);
                *reinterpret_cast<uint2*>(&PsW[paddr[s][jb]]) =
                    make_uint2(pk2bf(p0, p1), pk2bf(p2, p3));
            }

        // PV: V frags shared across both q-subtiles
        __builtin_amdgcn_s_setprio(1);
#pragma unroll
        for (int ks = 0; ks < 2; ++ks) {
            short8v pa[2];
#pragma unroll
            for (int s = 0; s < 2; ++s)
                pa[s] = ld_frag(PsW, s * 16 + lr, ks * 4 + lg);
#pragma unroll
            for (int d = 0; d < 4; ++d) {
                short8v vf = ld_frag(VsC, d * 16 + lr, ks * 4 + lg);
#pragma unroll
                for (int s = 0; s < 2; ++s)
                    oacc[s][d] = __builtin_amdgcn_mfma_f32_16x16x32_bf16(
                        pa[s], vf, oacc[s][d], 0, 0, 0);
            }
        }
        __builtin_amdgcn_s_setprio(0);
        __syncthreads();   // drains prefetch + guards K/V/P buffer reuse
    }

    // epilogue: cross-lg l sum per qsub, inv via owner-lane shfl
    USHORT* go = O + (size_t)(b * SEQ + q0 + w * 32) * D_MODEL + h * DH;
#pragma unroll
    for (int s = 0; s < 2; ++s) {
        float lv = l_[s];
        lv += __shfl_xor(lv, 16);
        lv += __shfl_xor(lv, 32);
        const float inv_own = 1.f / lv;
#pragma unroll
        for (int r = 0; r < 4; ++r) {
            const float inv = __shfl(inv_own, (l & 48) | (lg * 4 + r));
            const int qrow = s * 16 + lg * 4 + r;
#pragma unroll
            for (int d = 0; d < 4; ++d)
                go[(size_t)qrow * D_MODEL + d * 16 + lr] =
                    f2bf_fast(oacc[s][d][r] * inv);
        }
    }
}

// ---------------------------------------------------------------------------
// out = res + LayerNorm(x)*g + b, where x = xb (+ xb2) (+ biasx). (unchanged)
// ---------------------------------------------------------------------------
__global__ __launch_bounds__(256) void ln_res_kernel(
    const USHORT* __restrict__ xb, const USHORT* __restrict__ xb2,
    const float* __restrict__ biasx,
    const float* __restrict__ resf, const USHORT* __restrict__ resb,
    const float* __restrict__ g, const float* __restrict__ bta,
    float* __restrict__ outf, USHORT* __restrict__ outb)
{
    __shared__ float red[256];
    __shared__ float s_mu, s_rstd;

    const int row = blockIdx.x;
    const int tid = threadIdx.x;
    ushort4 xv = reinterpret_cast<const ushort4*>(xb + (size_t)row * D_MODEL)[tid];
    float vx = bf2f(xv.x), vy = bf2f(xv.y), vz = bf2f(xv.z), vw = bf2f(xv.w);
    if (xb2) {
        ushort4 x2 = reinterpret_cast<const ushort4*>(
            xb2 + (size_t)row * D_MODEL)[tid];
        vx += bf2f(x2.x); vy += bf2f(x2.y); vz += bf2f(x2.z); vw += bf2f(x2.w);
    }
    if (biasx) {
        float4 bx = reinterpret_cast<const float4*>(biasx)[tid];
        vx += bx.x; vy += bx.y; vz += bx.z; vw += bx.w;
    }

    red[tid] = vx + vy + vz + vw;
    __syncthreads();
    for (int s = 128; s > 0; s >>= 1) {
        if (tid < s) red[tid] += red[tid + s];
        __syncthreads();
    }
    if (tid == 0) s_mu = red[0] * (1.f / D_MODEL);
    __syncthreads();
    const float mu = s_mu;

    float dx = vx - mu, dy = vy - mu, dz = vz - mu, dw = vw - mu;
    red[tid] = dx * dx + dy * dy + dz * dz + dw * dw;
    __syncthreads();
    for (int s = 128; s > 0; s >>= 1) {
        if (tid < s) red[tid] += red[tid + s];
        __syncthreads();
    }
    if (tid == 0) s_rstd = rsqrtf(red[0] * (1.f / D_MODEL) + EPS);
    __syncthreads();
    const float rstd = s_rstd;

    float4 rv;
    if (resf) {
        rv = reinterpret_cast<const float4*>(resf + (size_t)row * D_MODEL)[tid];
    } else if (resb) {
        ushort4 rb = reinterpret_cast<const ushort4*>(
            resb + (size_t)row * D_MODEL)[tid];
        rv = make_float4(bf2f(rb.x), bf2f(rb.y), bf2f(rb.z), bf2f(rb.w));
    } else {
        rv = make_float4(vx, vy, vz, vw);          // res = x (norm_attn2 wiring)
    }
    float4 gv = reinterpret_cast<const float4*>(g)[tid];
    float4 bv = reinterpret_cast<const float4*>(bta)[tid];

    float4 o;
    o.x = rv.x + dx * rstd * gv.x + bv.x;
    o.y = rv.y + dy * rstd * gv.y + bv.y;
    o.z = rv.z + dz * rstd * gv.z + bv.z;
    o.w = rv.w + dw * rstd * gv.w + bv.w;
    reinterpret_cast<float4*>(outf + (size_t)row * D_MODEL)[tid] = o;
    if (outb)
        reinterpret_cast<ushort4*>(outb + (size_t)row * D_MODEL)[tid] =
            make_ushort4(f2bf(o.x), f2bf(o.y), f2bf(o.z), f2bf(o.w));
}

// ---------------------------------------------------------------------------
extern "C" void kernel_launch(void* const* d_in, const int* in_sizes, int n_in,
                              void* d_out, int out_size, void* d_ws, size_t ws_size,
                              hipStream_t stream)
{
    const float* X    = (const float*)d_in[0];
    const float* Wq1  = (const float*)d_in[1];
    const float* Wk1  = (const float*)d_in[2];
    const float* Wv1  = (const float*)d_in[3];
    const float* Wo1  = (const float*)d_in[4];
    const float* Wq2  = (const float*)d_in[5];
    const float* Wk2  = (const float*)d_in[6];
    const float* Wv2  = (const float*)d_in[7];
    const float* Wo2  = (const float*)d_in[8];
    const float* ln_g = (const float*)d_in[9];
    const float* ln_b = (const float*)d_in[10];
    const float* W1   = (const float*)d_in[11];
    const float* b1   = (const float*)d_in[12];
    const float* W2   = (const float*)d_in[13];
    const float* b2   = (const float*)d_in[14];

    const size_t MI = 1024 * 1024;
    USHORT* ws16 = (USHORT*)d_ws;
    USHORT* Wqkv1t = ws16;                 // [0,3Mi); also scr0 after MHA1
    USHORT* scr0   = ws16;
    USHORT* Wo1t   = ws16 + 3 * MI;
    USHORT* Wqkv2t = ws16 + 4 * MI;
    USHORT* Wo2t   = ws16 + 7 * MI;
    USHORT* W2t    = ws16 + 8 * MI;
    USHORT* Xb     = ws16 + 12 * MI;
    USHORT* W1t    = Xb;
    USHORT* qb     = ws16 + 16 * MI;
    USHORT* kb     = ws16 + 20 * MI;
    USHORT* Vtb    = ws16 + 24 * MI;
    USHORT* t0b    = ws16 + 28 * MI;
    USHORT* hb     = qb;
    USHORT* t2b    = ws16 + 32 * MI;
    USHORT* t1b    = ws16 + 36 * MI;
    float*  t2     = (float*)(ws16 + 40 * MI);

    auto gemm256 = [&](const USHORT* A, const USHORT* Bt, float* Cf, USHORT* Cb,
                       int M, int N, int K, const float* bias, int relu) {
        gemm_k256_kernel<<<dim3(N / 256, M / 256), 512, 0, stream>>>(
            A, Bt, Cf, Cb, nullptr, nullptr, M, N, K, bias, relu, 0);
    };
    auto gemm_qkv = [&](const USHORT* A, const USHORT* Bt) {
        gemm_k256_kernel<<<dim3(3072 / 256, TOK / 256), 512, 0, stream>>>(
            A, Bt, nullptr, qb, kb, Vtb, TOK, 3072, D_MODEL, nullptr, 0, 1);
    };
    auto gemm128c = [&](const USHORT* A, const USHORT* Bt, USHORT* Pa, USHORT* Pb,
                        int M, int N, int K) {
        gemm_k128c_kernel<<<dim3(N / 128, (M / 128) * 2), 512, 0, stream>>>(
            A, Bt, Pa, Pb, M, N, K);
    };

    dim3 agrid(SEQ / 128, BATCH * N_HEADS);

    // ---- prologue: all square weights + W2 + X -> bf16 ----
    {
        TcvtB4 p1{Wq1, Wk1, Wv1, Wo1,
                  Wqkv1t, Wqkv1t + 1 * MI, Wqkv1t + 2 * MI, Wo1t};
        tcvt4_kernel<<<dim3(16, 16, 4), 256, 0, stream>>>(p1, D_MODEL, D_MODEL);
        TcvtB4 p2{Wq2, Wk2, Wv2, Wo2,
                  Wqkv2t, Wqkv2t + 1 * MI, Wqkv2t + 2 * MI, Wo2t};
        tcvt4_kernel<<<dim3(16, 16, 4), 256, 0, stream>>>(p2, D_MODEL, D_MODEL);
    }
    tcvt_kernel<<<dim3(D_MODEL / 64, D_FF / 64), 256, 0, stream>>>(
        W2, W2t, D_FF, D_MODEL);
    f2b_kernel<<<dim3(4096), 256, 0, stream>>>(X, Xb, TOK * D_MODEL / 4);

    // ---- MHA 1 (causal) ----
    gemm_qkv(Xb, Wqkv1t);
    attn_mfma_kernel<<<agrid, 256, 0, stream>>>(qb, kb, Vtb, t0b, 1);
    gemm128c(t0b, Wo1t, t2b, t1b, TOK, D_MODEL, D_MODEL);     // masked = t2b+t1b
    ln_res_kernel<<<dim3(TOK), 256, 0, stream>>>(t2b, t1b, nullptr, X, nullptr,
                                                 ln_g, ln_b, t2, t2b);
    tcvt_kernel<<<dim3(D_FF / 64, D_MODEL / 64), 256, 0, stream>>>(
        W1, W1t, D_MODEL, D_FF);

    // ---- MHA 2 (full) ----
    gemm_qkv(t2b, Wqkv2t);
    attn_mfma_kernel<<<agrid, 256, 0, stream>>>(qb, kb, Vtb, t0b, 0);
    gemm128c(t0b, Wo2t, scr0, t1b, TOK, D_MODEL, D_MODEL);    // attn2 = scr0+t1b
    ln_res_kernel<<<dim3(TOK), 256, 0, stream>>>(scr0, t1b, nullptr,
                                                 nullptr, nullptr,   // res = x
                                                 ln_g, ln_b, t2, t2b);

    // ---- FFN ----
    gemm256(t2b, W1t, nullptr, hb, TOK, D_FF, D_MODEL, b1, 1);
    gemm128c(hb, W2t, t2b, t1b, TOK, D_MODEL, D_FF);          // ff = t2b+t1b+b2
    ln_res_kernel<<<dim3(TOK), 256, 0, stream>>>(t2b, t1b, b2, t2, nullptr,
                                                 ln_g, ln_b, (float*)d_out, nullptr);
}

// Round 20
// 329.129 us; speedup vs baseline: 1.0280x; 1.0182x over previous
//
#include <hip/hip_runtime.h>
#include <hip/hip_bf16.h>

#define D_MODEL 1024
#define N_HEADS 16
#define DH 64
#define D_FF   4096
#define SEQ    1024
#define BATCH  4
#define TOK    (BATCH*SEQ)
#define EPS    1e-5f
#define SCALE  0.125f           // 1/sqrt(64)
#define QSCL   0.18033688f      // SCALE * log2(e): QK^T lands in log2 domain

typedef unsigned short USHORT;
typedef __attribute__((ext_vector_type(8))) short short8v;
typedef __attribute__((ext_vector_type(4))) float f32x4;

__device__ __forceinline__ USHORT f2bf(float f) {
    unsigned int u; __builtin_memcpy(&u, &f, 4);
    u += 0x7fffu + ((u >> 16) & 1u);          // RNE
    return (USHORT)(u >> 16);
}
// 2-op round-half-up pack (P in (0,256] and O: error == RNE magnitude)
__device__ __forceinline__ USHORT f2bf_fast(float f) {
    unsigned int u; __builtin_memcpy(&u, &f, 4);
    return (USHORT)((u + 0x8000u) >> 16);
}
// HW pack: 2 floats -> u32 of 2 bf16 (RNE, v_cvt_pk path); lo -> bits [15:0]
__device__ __forceinline__ unsigned pk2bf(float lo, float hi) {
    __hip_bfloat162 h = __float22bfloat162_rn(make_float2(lo, hi));
    unsigned u; __builtin_memcpy(&u, &h, 4);
    return u;
}
__device__ __forceinline__ float bf2f(USHORT s) {
    unsigned int u = ((unsigned int)s) << 16;
    float f; __builtin_memcpy(&f, &u, 4);
    return f;
}
__device__ __forceinline__ float max3f(float a, float b, float c) {
    return fmaxf(fmaxf(a, b), c);             // fuses to v_max3_f32
}

// row-stride-64 swizzled read: unit ^= row&7
__device__ __forceinline__ short8v ld_frag(const USHORT* lds, int row, int c8) {
    return *reinterpret_cast<const short8v*>(
        &lds[row * 64 + (((c8) ^ (row & 7)) << 3)]);
}
// row-stride-32 swizzled read (BK=32 tiles): unit ^= (row>>1)&3  (2-way = free)
__device__ __forceinline__ short8v ld32(const USHORT* lds, int row, int c8) {
    return *reinterpret_cast<const short8v*>(
        &lds[row * 32 + (((c8) ^ ((row >> 1) & 3)) << 3)]);
}

#define GLDS(gsrc, ldst) \
    __builtin_amdgcn_global_load_lds( \
        (const __attribute__((address_space(1))) void*)(gsrc), \
        (__attribute__((address_space(3))) void*)(ldst), 16, 0, 0)

#define WAITVM(n) asm volatile("s_waitcnt vmcnt(" #n ")" ::: "memory")

// ---------------------------------------------------------------------------
// bf16 MFMA GEMM, 128M x 256N tile, BK=32, 512 threads = 8 waves (2M x 4N,
// wave = 64x64, acc[4][4]). 2-buffer counted-vmcnt pipeline (issue-early,
// WAITVM(3), never 0 mid-loop). LDS = 2 x (8KB A + 16KB B) = 48 KB -> with
// grid 512 (FFN1) / 384 (QKV), 2 blocks/CU co-resident = 4 waves/SIMD
// (restores m114 inter-block overlap that the 256^2/128KB tile lacked at
// 1 block/CU). BK=32 ld32 swizzle (2-way, free). Epilogues: normal
// (Cf fp32 / Cb bf16, +bias/relu) or fused-QKV routing (Q pre-scaled into
// log2-e domain; V transposed per-head).
// ---------------------------------------------------------------------------
__global__ __launch_bounds__(512) void gemm_k128n256_kernel(
    const USHORT* __restrict__ A, const USHORT* __restrict__ Bt,
    float* __restrict__ Cf, USHORT* __restrict__ Cb, USHORT* __restrict__ Ck,
    USHORT* __restrict__ VtOut,
    int M, int N, int K, const float* __restrict__ bias, int relu, int qkv)
{
    __shared__ USHORT As[2][128 * 32];     // [128 m][32 k], (row>>1)&3 swizzle
    __shared__ USHORT Bs[2][256 * 32];     // [256 n][32 k], (row>>1)&3 swizzle

    const int tid = threadIdx.x;
    const int l   = tid & 63;
    const int w   = tid >> 6;              // 0..7
    const int wr  = w >> 2, wc = w & 3;    // 2M x 4N wave grid
    const int lr  = l & 15, lg = l >> 4;

    const int gx  = gridDim.x;             // N/256
    const int nwg = gx * gridDim.y;
    const int lin = blockIdx.y * gx + blockIdx.x;
    const int swz = (lin & 7) * (nwg >> 3) + (lin >> 3);
    const int m0  = (swz / gx) * 128, n0 = (swz % gx) * 256;

    // A staging: 512 units (1/thread); B staging: 1024 units (2/thread).
    // LDS unit q holds global col-unit (q&3) ^ ((row>>1)&3)  [inverse swizzle]
    const int ar = tid >> 2;
    const USHORT* aS = A + (size_t)(m0 + ar) * K
                         + (((tid & 3) ^ ((ar >> 1) & 3)) << 3);
    const int adOf = (w * 64) * 8;

    const USHORT* bS[2]; int bdOf[2];
#pragma unroll
    for (int p = 0; p < 2; ++p) {
        const int q = p * 512 + tid;
        const int row = q >> 2, cu = q & 3;
        bS[p] = Bt + (size_t)(n0 + row) * K + ((cu ^ ((row >> 1) & 3)) << 3);
        bdOf[p] = (p * 512 + w * 64) * 8;
    }

    auto stage = [&](int buf, int k0) {    // 3 GLDS per thread per tile
        GLDS(aS + k0, &As[buf][adOf]);
#pragma unroll
        for (int p = 0; p < 2; ++p)
            GLDS(bS[p] + k0, &Bs[buf][bdOf[p]]);
    };

    f32x4 acc[4][4];
#pragma unroll
    for (int i = 0; i < 4; ++i)
#pragma unroll
        for (int j = 0; j < 4; ++j) acc[i][j] = (f32x4){0.f, 0.f, 0.f, 0.f};

    const int nk = K >> 5;
    stage(0, 0);

    for (int t = 0; t < nk; ++t) {
        const int cur = t & 1;
        if (t + 1 < nk) {
            stage(cur ^ 1, (t + 1) << 5);  // issue early: full MFMA phase to land
            WAITVM(3);                     // tile t complete; t+1 stays in flight
        } else {
            WAITVM(0);
        }
        __builtin_amdgcn_s_barrier();      // all waves' tile-t loads done

        short8v bfr[4];
#pragma unroll
        for (int ni = 0; ni < 4; ++ni)
            bfr[ni] = ld32(Bs[cur], wc * 64 + ni * 16 + lr, lg);
        __builtin_amdgcn_s_setprio(1);
#pragma unroll
        for (int mi = 0; mi < 4; ++mi) {
            short8v af = ld32(As[cur], wr * 64 + mi * 16 + lr, lg);
#pragma unroll
            for (int ni = 0; ni < 4; ++ni)
                acc[mi][ni] = __builtin_amdgcn_mfma_f32_16x16x32_bf16(
                    af, bfr[ni], acc[mi][ni], 0, 0, 0);
        }
        __builtin_amdgcn_s_setprio(0);
        __builtin_amdgcn_s_barrier();      // all waves done reading buf cur
    }

    // epilogue: C/D layout col = lane&15, row = (lane>>4)*4 + reg
    if (qkv) {
#pragma unroll
        for (int mi = 0; mi < 4; ++mi) {
            const int row = m0 + wr * 64 + mi * 16 + (l >> 4) * 4;
#pragma unroll
            for (int ni = 0; ni < 4; ++ni) {
                const int col = n0 + wc * 64 + ni * 16 + lr;
                if (col < 2048) {
                    USHORT* dst = (col < 1024) ? Cb : Ck;
                    const float scl = (col < 1024) ? QSCL : 1.f;  // log2-e domain
                    const int c = col & 1023;
#pragma unroll
                    for (int j = 0; j < 4; ++j)
                        dst[(size_t)(row + j) * D_MODEL + c] =
                            f2bf(acc[mi][ni][j] * scl);
                } else {
                    const int c = col - 2048;
                    const int bb = row >> 10, jr = row & 1023;
                    const int hh = c >> 6, dd = c & 63;
                    uint2 pk = make_uint2(
                        pk2bf(acc[mi][ni][0], acc[mi][ni][1]),
                        pk2bf(acc[mi][ni][2], acc[mi][ni][3]));
                    *reinterpret_cast<uint2*>(
                        &VtOut[((size_t)(bb * 16 + hh) * 64 + dd) * 1024 + jr]) = pk;
                }
            }
        }
    } else {
#pragma unroll
        for (int mi = 0; mi < 4; ++mi) {
            const int row = m0 + wr * 64 + mi * 16 + (l >> 4) * 4;
#pragma unroll
            for (int ni = 0; ni < 4; ++ni) {
                const int col = n0 + wc * 64 + ni * 16 + lr;
                const float bv = bias ? bias[col] : 0.f;
#pragma unroll
                for (int j = 0; j < 4; ++j) {
                    float v = acc[mi][ni][j] + bv;
                    if (relu) v = fmaxf(v, 0.f);
                    const size_t idx = (size_t)(row + j) * N + col;
                    if (Cf) Cf[idx] = v;
                    if (Cb) Cb[idx] = f2bf(v);
                }
            }
        }
    }
}

// ---------------------------------------------------------------------------
// Split-K bf16 GEMM for the N=1024 shapes: 128x128 tile, BK=64, 2-buffer
// counted-vmcnt, 8 waves. Split-K=2, bf16 partials. (unchanged from R15)
// ---------------------------------------------------------------------------
__global__ __launch_bounds__(512) void gemm_k128c_kernel(
    const USHORT* __restrict__ A, const USHORT* __restrict__ Bt,
    USHORT* __restrict__ Pa, USHORT* __restrict__ Pb,
    int M, int N, int K)
{
    __shared__ USHORT As[2][128 * 64];
    __shared__ USHORT Bs[2][128 * 64];

    const int tid = threadIdx.x;
    const int l   = tid & 63;
    const int w   = tid >> 6;
    const int wr  = w >> 2, wc = w & 3;
    const int lr  = l & 15, lg = l >> 4;

    const int gx  = gridDim.x;
    const int nwg = gx * gridDim.y;
    const int lin = blockIdx.y * gx + blockIdx.x;
    const int swz = (lin & 7) * (nwg >> 3) + (lin >> 3);
    const int my  = swz / gx;
    const int mt  = M >> 7;
    const int part = my / mt;
    const int m0  = (my % mt) << 7;
    const int n0  = (swz % gx) * 128;
    const int koff = part * (K >> 1);
    USHORT* dst = part ? Pb : Pa;

    const USHORT* aS[2]; const USHORT* bS[2]; int dOf[2];
#pragma unroll
    for (int p = 0; p < 2; ++p) {
        const int q = p * 512 + tid;
        const int row = q >> 3, cu = q & 7;
        const int cs = ((cu ^ (row & 7)) << 3);
        aS[p] = A  + (size_t)(m0 + row) * K + cs;
        bS[p] = Bt + (size_t)(n0 + row) * K + cs;
        dOf[p] = (p * 512 + w * 64) * 8;
    }

    auto stage = [&](int buf, int k0) {
#pragma unroll
        for (int p = 0; p < 2; ++p) {
            GLDS(aS[p] + k0, &As[buf][dOf[p]]);
            GLDS(bS[p] + k0, &Bs[buf][dOf[p]]);
        }
    };

    f32x4 acc[4][2];
#pragma unroll
    for (int i = 0; i < 4; ++i)
#pragma unroll
        for (int j = 0; j < 2; ++j) acc[i][j] = (f32x4){0.f, 0.f, 0.f, 0.f};

    const int nk = K >> 7;
    stage(0, koff);

    for (int t = 0; t < nk; ++t) {
        const int cur = t & 1;
        if (t + 1 < nk) {
            stage(cur ^ 1, koff + ((t + 1) << 6));
            WAITVM(4);
        } else {
            WAITVM(0);
        }
        __builtin_amdgcn_s_barrier();

#pragma unroll
        for (int ks = 0; ks < 2; ++ks) {
            short8v bfr[2];
#pragma unroll
            for (int ni = 0; ni < 2; ++ni)
                bfr[ni] = ld_frag(Bs[cur], wc * 32 + ni * 16 + lr, ks * 4 + lg);
            __builtin_amdgcn_s_setprio(1);
#pragma unroll
            for (int mi = 0; mi < 4; ++mi) {
                short8v af = ld_frag(As[cur], wr * 64 + mi * 16 + lr, ks * 4 + lg);
#pragma unroll
                for (int ni = 0; ni < 2; ++ni)
                    acc[mi][ni] = __builtin_amdgcn_mfma_f32_16x16x32_bf16(
                        af, bfr[ni], acc[mi][ni], 0, 0, 0);
            }
            __builtin_amdgcn_s_setprio(0);
        }
        __builtin_amdgcn_s_barrier();
    }

#pragma unroll
    for (int mi = 0; mi < 4; ++mi) {
        const int row = m0 + wr * 64 + mi * 16 + (l >> 4) * 4;
#pragma unroll
        for (int ni = 0; ni < 2; ++ni) {
            const int col = n0 + wc * 32 + ni * 16 + lr;
#pragma unroll
            for (int j = 0; j < 4; ++j)
                dst[(size_t)(row + j) * N + col] = f2bf(acc[mi][ni][j]);
        }
    }
}

// ---------------------------------------------------------------------------
// Weight convert+transpose kernels (unchanged).
// ---------------------------------------------------------------------------
struct TcvtB4 {
    const float* s0; const float* s1; const float* s2; const float* s3;
    USHORT* d0; USHORT* d1; USHORT* d2; USHORT* d3;
};

__device__ __forceinline__ void tcvt_body(
    const float* __restrict__ W, USHORT* __restrict__ Wt, int K, int N)
{
    __shared__ USHORT L[64][65];
    const int tid = threadIdx.x;
    const int tx = tid & 15, ty = tid >> 4;
    const int n0 = blockIdx.x * 64, k0 = blockIdx.y * 64;
#pragma unroll
    for (int r = 0; r < 4; ++r) {
        int kr = ty + 16 * r;
        float4 v = *reinterpret_cast<const float4*>(
            &W[(size_t)(k0 + kr) * N + n0 + tx * 4]);
        L[tx * 4 + 0][kr] = f2bf(v.x);
        L[tx * 4 + 1][kr] = f2bf(v.y);
        L[tx * 4 + 2][kr] = f2bf(v.z);
        L[tx * 4 + 3][kr] = f2bf(v.w);
    }
    __syncthreads();
#pragma unroll
    for (int r = 0; r < 4; ++r) {
        int nr = ty + 16 * r;
        ushort4 o = make_ushort4(L[nr][tx * 4 + 0], L[nr][tx * 4 + 1],
                                 L[nr][tx * 4 + 2], L[nr][tx * 4 + 3]);
        *reinterpret_cast<ushort4*>(&Wt[(size_t)(n0 + nr) * K + k0 + tx * 4]) = o;
    }
}

__global__ __launch_bounds__(256) void tcvt_kernel(
    const float* __restrict__ W, USHORT* __restrict__ Wt, int K, int N)
{
    tcvt_body(W, Wt, K, N);
}

__global__ __launch_bounds__(256) void tcvt4_kernel(TcvtB4 p, int K, int N)
{
    const int z = blockIdx.z;
    const float* W = (z == 0) ? p.s0 : (z == 1) ? p.s1 : (z == 2) ? p.s2 : p.s3;
    USHORT*    Wt = (z == 0) ? p.d0 : (z == 1) ? p.d1 : (z == 2) ? p.d2 : p.d3;
    tcvt_body(W, Wt, K, N);
}

__global__ __launch_bounds__(256) void f2b_kernel(
    const float* __restrict__ in, USHORT* __restrict__ out, int n4)
{
    int i = blockIdx.x * 256 + threadIdx.x;
    if (i < n4) {
        float4 v = reinterpret_cast<const float4*>(in)[i];
        reinterpret_cast<ushort4*>(out)[i] =
            make_ushort4(f2bf(v.x), f2bf(v.y), f2bf(v.z), f2bf(v.w));
    }
}

// ---------------------------------------------------------------------------
// MFMA flash attention (unchanged from R19): QBLK=128, KVBLK=64, 4 waves,
// wave owns two 16-row q-subtiles sharing K/V frags, 48 KB LDS, swapped QK^T,
// per-lane softmax state, log2 domain, defer-max, cvt_pk P pack.
// ---------------------------------------------------------------------------
__global__ __launch_bounds__(256) void attn_mfma_kernel(
    const USHORT* __restrict__ Q, const USHORT* __restrict__ K,
    const USHORT* __restrict__ Vt, USHORT* __restrict__ O, int causal)
{
    __shared__ USHORT smem[24576];                 // 48 KB

    const int tid = threadIdx.x;
    const int l  = tid & 63;
    const int w  = tid >> 6;
    const int lr = l & 15;
    const int lg = l >> 4;

    const int lin = blockIdx.y * 8 + blockIdx.x;    // nwg = 512
    const int swz = (lin & 7) * 64 + (lin >> 3);
    const int qt = swz & 7;
    const int bh = swz >> 3;
    const int h = bh & 15, b = bh >> 4;
    const int q0 = qt * 128;

    const USHORT* gq  = Q  + (size_t)(b * SEQ + q0) * D_MODEL + h * DH;
    const USHORT* gk0 = K  + (size_t)b * SEQ * D_MODEL + h * DH;
    const USHORT* gv0 = Vt + (size_t)bh * DH * SEQ;

    auto stageK = [&](int buf, int kt) {           // 64x64, row&7 swizzle
        USHORT* dst = smem + buf * 4096;
        const size_t base = (size_t)kt * 64 * 1024;
#pragma unroll
        for (int p = 0; p < 2; ++p) {
            const int q = p * 256 + tid;
            const int row = q >> 3, cu = q & 7;
            GLDS(gk0 + base + (size_t)row * 1024 + ((cu ^ (row & 7)) << 3),
                 dst + (p * 256 + w * 64) * 8);
        }
    };
    auto stageV = [&](int buf, int kt) {           // 64 d x 64 j, row&7 swizzle
        USHORT* dst = smem + 8192 + buf * 4096;
        const int j0 = kt * 64;
#pragma unroll
        for (int p = 0; p < 2; ++p) {
            const int q = p * 256 + tid;
            const int row = q >> 3, cu = q & 7;
            GLDS(gv0 + (size_t)row * 1024 + j0 + ((cu ^ (row & 7)) << 3),
                 dst + (p * 256 + w * 64) * 8);
        }
    };

    // stage Q (128x64, row&7 swizzle) + first K/V tile
#pragma unroll
    for (int p = 0; p < 4; ++p) {
        const int q = p * 256 + tid;
        const int row = q >> 3, cu = q & 7;
        GLDS(gq + (size_t)row * 1024 + ((cu ^ (row & 7)) << 3),
             smem + 16384 + (p * 256 + w * 64) * 8);
    }
    stageK(0, 0);
    stageV(0, 0);

    f32x4 oacc[2][4];
    float m_[2], l_[2];            // per-lane state for q = w*32 + s*16 + lr
#pragma unroll
    for (int s = 0; s < 2; ++s) {
        m_[s] = -1e30f; l_[s] = 0.f;
#pragma unroll
        for (int d = 0; d < 4; ++d) oacc[s][d] = (f32x4){0.f, 0.f, 0.f, 0.f};
    }

    // P write offsets: row = s*16+lr, j = jb*16 + lg*4 .. +3 (one b64 each)
    int paddr[2][4];
#pragma unroll
    for (int s = 0; s < 2; ++s) {
        const int row = s * 16 + lr;
#pragma unroll
        for (int jb = 0; jb < 4; ++jb) {
            const int cu = jb * 2 + (lg >> 1);
            paddr[s][jb] = row * 64 + ((cu ^ (row & 7)) << 3) + (lg & 1) * 4;
        }
    }

    __syncthreads();                               // Q + tile 0 staged
    short8v qa[2][2];
#pragma unroll
    for (int s = 0; s < 2; ++s) {
        qa[s][0] = ld_frag(smem + 16384, w * 32 + s * 16 + lr, lg);
        qa[s][1] = ld_frag(smem + 16384, w * 32 + s * 16 + lr, 4 + lg);
    }
    __syncthreads();                               // Q consumed -> P may reuse
    USHORT* PsW = smem + 16384 + w * 2048;         // per-wave P [32 q][64 j]

    const int ntile = causal ? (qt * 2 + 2) : (SEQ / 64);
    for (int kt = 0; kt < ntile; ++kt) {
        const int cur = kt & 1;
        if (kt + 1 < ntile) {                      // prefetch next K/V tile
            stageK(cur ^ 1, kt + 1);
            stageV(cur ^ 1, kt + 1);
        }
        const int j0 = kt * 64;
        const USHORT* KsC = smem + cur * 4096;
        const USHORT* VsC = smem + 8192 + cur * 4096;

        // S^T = mfma(K, Q); K frags shared across both q-subtiles
        f32x4 sa[2][4];
        __builtin_amdgcn_s_setprio(1);
#pragma unroll
        for (int jb = 0; jb < 4; ++jb) {
            short8v kf0 = ld_frag(KsC, jb * 16 + lr, lg);
            short8v kf1 = ld_frag(KsC, jb * 16 + lr, 4 + lg);
#pragma unroll
            for (int s = 0; s < 2; ++s) {
                sa[s][jb] = (f32x4){0.f, 0.f, 0.f, 0.f};
                sa[s][jb] = __builtin_amdgcn_mfma_f32_16x16x32_bf16(
                    kf0, qa[s][0], sa[s][jb], 0, 0, 0);
                sa[s][jb] = __builtin_amdgcn_mfma_f32_16x16x32_bf16(
                    kf1, qa[s][1], sa[s][jb], 0, 0, 0);
            }
        }
        __builtin_amdgcn_s_setprio(0);

        // causal mask: only the last two tiles can cross the diagonal
        if (causal && kt >= ntile - 2) {
#pragma unroll
            for (int s = 0; s < 2; ++s) {
                const int qrow = q0 + w * 32 + s * 16 + lr;
#pragma unroll
                for (int jb = 0; jb < 4; ++jb)
#pragma unroll
                    for (int r = 0; r < 4; ++r)
                        if ((j0 + jb * 16 + lg * 4 + r) > qrow)
                            sa[s][jb][r] = -1e30f;
            }
        }

        // per-lane tile max over 16 values per qsub + 2 shfl each
        float tm[2];
#pragma unroll
        for (int s = 0; s < 2; ++s) {
            float t1 = max3f(sa[s][0][0], sa[s][0][1], sa[s][0][2]);
            float t2 = max3f(sa[s][0][3], sa[s][1][0], sa[s][1][1]);
            float t3 = max3f(sa[s][1][2], sa[s][1][3], sa[s][2][0]);
            float t4 = max3f(sa[s][2][1], sa[s][2][2], sa[s][2][3]);
            float t5 = max3f(sa[s][3][0], sa[s][3][1], sa[s][3][2]);
            float tv = fmaxf(max3f(max3f(t1, t2, t3), t4, t5), sa[s][3][3]);
            tv = fmaxf(tv, __shfl_xor(tv, 16));
            tv = fmaxf(tv, __shfl_xor(tv, 32));
            tm[s] = tv;
        }

        // defer-max rescale (wave-gated; broadcast sc from owner lanes)
        const bool anyf = (tm[0] > m_[0] + 8.f) | (tm[1] > m_[1] + 8.f);
        if (__ballot(anyf)) {
            float sc[2];
#pragma unroll
            for (int s = 0; s < 2; ++s) {
                const float mn = (tm[s] > m_[s] + 8.f) ? tm[s] : m_[s];
                sc[s] = exp2f(m_[s] - mn);
                l_[s] *= sc[s];
                m_[s] = mn;
            }
#pragma unroll
            for (int s = 0; s < 2; ++s)
#pragma unroll
                for (int r = 0; r < 4; ++r) {
                    const float scr = __shfl(sc[s], (l & 48) | (lg * 4 + r));
#pragma unroll
                    for (int d = 0; d < 4; ++d) oacc[s][d][r] *= scr;
                }
        }

        // exp (log2 domain) + lane-partial sum + HW pack + b64 P-writes
#pragma unroll
        for (int s = 0; s < 2; ++s)
#pragma unroll
            for (int jb = 0; jb < 4; ++jb) {
                const float p0 = exp2f(sa[s][jb][0] - m_[s]);
                const float p1 = exp2f(sa[s][jb][1] - m_[s]);
                const float p2 = exp2f(sa[s][jb][2] - m_[s]);
                const float p3 = exp2f(sa[s][jb][3] - m_[s]);
                l_[s] += (p0 + p1) + (p2 + p3);
                *reinterpret_cast<uint2*>(&PsW[paddr[s][jb]]) =
                    make_uint2(pk2bf(p0, p1), pk2bf(p2, p3));
            }

        // PV: V frags shared across both q-subtiles
        __builtin_amdgcn_s_setprio(1);
#pragma unroll
        for (int ks = 0; ks < 2; ++ks) {
            short8v pa[2];
#pragma unroll
            for (int s = 0; s < 2; ++s)
                pa[s] = ld_frag(PsW, s * 16 + lr, ks * 4 + lg);
#pragma unroll
            for (int d = 0; d < 4; ++d) {
                short8v vf = ld_frag(VsC, d * 16 + lr, ks * 4 + lg);
#pragma unroll
                for (int s = 0; s < 2; ++s)
                    oacc[s][d] = __builtin_amdgcn_mfma_f32_16x16x32_bf16(
                        pa[s], vf, oacc[s][d], 0, 0, 0);
            }
        }
        __builtin_amdgcn_s_setprio(0);
        __syncthreads();   // drains prefetch + guards K/V/P buffer reuse
    }

    // epilogue: cross-lg l sum per qsub, inv via owner-lane shfl
    USHORT* go = O + (size_t)(b * SEQ + q0 + w * 32) * D_MODEL + h * DH;
#pragma unroll
    for (int s = 0; s < 2; ++s) {
        float lv = l_[s];
        lv += __shfl_xor(lv, 16);
        lv += __shfl_xor(lv, 32);
        const float inv_own = 1.f / lv;
#pragma unroll
        for (int r = 0; r < 4; ++r) {
            const float inv = __shfl(inv_own, (l & 48) | (lg * 4 + r));
            const int qrow = s * 16 + lg * 4 + r;
#pragma unroll
            for (int d = 0; d < 4; ++d)
                go[(size_t)qrow * D_MODEL + d * 16 + lr] =
                    f2bf_fast(oacc[s][d][r] * inv);
        }
    }
}

// ---------------------------------------------------------------------------
// out = res + LayerNorm(x)*g + b, where x = xb (+ xb2) (+ biasx). (unchanged)
// ---------------------------------------------------------------------------
__global__ __launch_bounds__(256) void ln_res_kernel(
    const USHORT* __restrict__ xb, const USHORT* __restrict__ xb2,
    const float* __restrict__ biasx,
    const float* __restrict__ resf, const USHORT* __restrict__ resb,
    const float* __restrict__ g, const float* __restrict__ bta,
    float* __restrict__ outf, USHORT* __restrict__ outb)
{
    __shared__ float red[256];
    __shared__ float s_mu, s_rstd;

    const int row = blockIdx.x;
    const int tid = threadIdx.x;
    ushort4 xv = reinterpret_cast<const ushort4*>(xb + (size_t)row * D_MODEL)[tid];
    float vx = bf2f(xv.x), vy = bf2f(xv.y), vz = bf2f(xv.z), vw = bf2f(xv.w);
    if (xb2) {
        ushort4 x2 = reinterpret_cast<const ushort4*>(
            xb2 + (size_t)row * D_MODEL)[tid];
        vx += bf2f(x2.x); vy += bf2f(x2.y); vz += bf2f(x2.z); vw += bf2f(x2.w);
    }
    if (biasx) {
        float4 bx = reinterpret_cast<const float4*>(biasx)[tid];
        vx += bx.x; vy += bx.y; vz += bx.z; vw += bx.w;
    }

    red[tid] = vx + vy + vz + vw;
    __syncthreads();
    for (int s = 128; s > 0; s >>= 1) {
        if (tid < s) red[tid] += red[tid + s];
        __syncthreads();
    }
    if (tid == 0) s_mu = red[0] * (1.f / D_MODEL);
    __syncthreads();
    const float mu = s_mu;

    float dx = vx - mu, dy = vy - mu, dz = vz - mu, dw = vw - mu;
    red[tid] = dx * dx + dy * dy + dz * dz + dw * dw;
    __syncthreads();
    for (int s = 128; s > 0; s >>= 1) {
        if (tid < s) red[tid] += red[tid + s];
        __syncthreads();
    }
    if (tid == 0) s_rstd = rsqrtf(red[0] * (1.f / D_MODEL) + EPS);
    __syncthreads();
    const float rstd = s_rstd;

    float4 rv;
    if (resf) {
        rv = reinterpret_cast<const float4*>(resf + (size_t)row * D_MODEL)[tid];
    } else if (resb) {
        ushort4 rb = reinterpret_cast<const ushort4*>(
            resb + (size_t)row * D_MODEL)[tid];
        rv = make_float4(bf2f(rb.x), bf2f(rb.y), bf2f(rb.z), bf2f(rb.w));
    } else {
        rv = make_float4(vx, vy, vz, vw);          // res = x (norm_attn2 wiring)
    }
    float4 gv = reinterpret_cast<const float4*>(g)[tid];
    float4 bv = reinterpret_cast<const float4*>(bta)[tid];

    float4 o;
    o.x = rv.x + dx * rstd * gv.x + bv.x;
    o.y = rv.y + dy * rstd * gv.y + bv.y;
    o.z = rv.z + dz * rstd * gv.z + bv.z;
    o.w = rv.w + dw * rstd * gv.w + bv.w;
    reinterpret_cast<float4*>(outf + (size_t)row * D_MODEL)[tid] = o;
    if (outb)
        reinterpret_cast<ushort4*>(outb + (size_t)row * D_MODEL)[tid] =
            make_ushort4(f2bf(o.x), f2bf(o.y), f2bf(o.z), f2bf(o.w));
}

// ---------------------------------------------------------------------------
extern "C" void kernel_launch(void* const* d_in, const int* in_sizes, int n_in,
                              void* d_out, int out_size, void* d_ws, size_t ws_size,
                              hipStream_t stream)
{
    const float* X    = (const float*)d_in[0];
    const float* Wq1  = (const float*)d_in[1];
    const float* Wk1  = (const float*)d_in[2];
    const float* Wv1  = (const float*)d_in[3];
    const float* Wo1  = (const float*)d_in[4];
    const float* Wq2  = (const float*)d_in[5];
    const float* Wk2  = (const float*)d_in[6];
    const float* Wv2  = (const float*)d_in[7];
    const float* Wo2  = (const float*)d_in[8];
    const float* ln_g = (const float*)d_in[9];
    const float* ln_b = (const float*)d_in[10];
    const float* W1   = (const float*)d_in[11];
    const float* b1   = (const float*)d_in[12];
    const float* W2   = (const float*)d_in[13];
    const float* b2   = (const float*)d_in[14];

    const size_t MI = 1024 * 1024;
    USHORT* ws16 = (USHORT*)d_ws;
    USHORT* Wqkv1t = ws16;                 // [0,3Mi); also scr0 after MHA1
    USHORT* scr0   = ws16;
    USHORT* Wo1t   = ws16 + 3 * MI;
    USHORT* Wqkv2t = ws16 + 4 * MI;
    USHORT* Wo2t   = ws16 + 7 * MI;
    USHORT* W2t    = ws16 + 8 * MI;
    USHORT* Xb     = ws16 + 12 * MI;
    USHORT* W1t    = Xb;
    USHORT* qb     = ws16 + 16 * MI;
    USHORT* kb     = ws16 + 20 * MI;
    USHORT* Vtb    = ws16 + 24 * MI;
    USHORT* t0b    = ws16 + 28 * MI;
    USHORT* hb     = qb;
    USHORT* t2b    = ws16 + 32 * MI;
    USHORT* t1b    = ws16 + 36 * MI;
    float*  t2     = (float*)(ws16 + 40 * MI);

    auto gemmBig = [&](const USHORT* A, const USHORT* Bt, float* Cf, USHORT* Cb,
                       int M, int N, int K, const float* bias, int relu) {
        gemm_k128n256_kernel<<<dim3(N / 256, M / 128), 512, 0, stream>>>(
            A, Bt, Cf, Cb, nullptr, nullptr, M, N, K, bias, relu, 0);
    };
    auto gemm_qkv = [&](const USHORT* A, const USHORT* Bt) {
        gemm_k128n256_kernel<<<dim3(3072 / 256, TOK / 128), 512, 0, stream>>>(
            A, Bt, nullptr, qb, kb, Vtb, TOK, 3072, D_MODEL, nullptr, 0, 1);
    };
    auto gemm128c = [&](const USHORT* A, const USHORT* Bt, USHORT* Pa, USHORT* Pb,
                        int M, int N, int K) {
        gemm_k128c_kernel<<<dim3(N / 128, (M / 128) * 2), 512, 0, stream>>>(
            A, Bt, Pa, Pb, M, N, K);
    };

    dim3 agrid(SEQ / 128, BATCH * N_HEADS);

    // ---- prologue: all square weights + W2 + X -> bf16 ----
    {
        TcvtB4 p1{Wq1, Wk1, Wv1, Wo1,
                  Wqkv1t, Wqkv1t + 1 * MI, Wqkv1t + 2 * MI, Wo1t};
        tcvt4_kernel<<<dim3(16, 16, 4), 256, 0, stream>>>(p1, D_MODEL, D_MODEL);
        TcvtB4 p2{Wq2, Wk2, Wv2, Wo2,
                  Wqkv2t, Wqkv2t + 1 * MI, Wqkv2t + 2 * MI, Wo2t};
        tcvt4_kernel<<<dim3(16, 16, 4), 256, 0, stream>>>(p2, D_MODEL, D_MODEL);
    }
    tcvt_kernel<<<dim3(D_MODEL / 64, D_FF / 64), 256, 0, stream>>>(
        W2, W2t, D_FF, D_MODEL);
    f2b_kernel<<<dim3(4096), 256, 0, stream>>>(X, Xb, TOK * D_MODEL / 4);

    // ---- MHA 1 (causal) ----
    gemm_qkv(Xb, Wqkv1t);
    attn_mfma_kernel<<<agrid, 256, 0, stream>>>(qb, kb, Vtb, t0b, 1);
    gemm128c(t0b, Wo1t, t2b, t1b, TOK, D_MODEL, D_MODEL);     // masked = t2b+t1b
    ln_res_kernel<<<dim3(TOK), 256, 0, stream>>>(t2b, t1b, nullptr, X, nullptr,
                                                 ln_g, ln_b, t2, t2b);
    tcvt_kernel<<<dim3(D_FF / 64, D_MODEL / 64), 256, 0, stream>>>(
        W1, W1t, D_MODEL, D_FF);

    // ---- MHA 2 (full) ----
    gemm_qkv(t2b, Wqkv2t);
    attn_mfma_kernel<<<agrid, 256, 0, stream>>>(qb, kb, Vtb, t0b, 0);
    gemm128c(t0b, Wo2t, scr0, t1b, TOK, D_MODEL, D_MODEL);    // attn2 = scr0+t1b
    ln_res_kernel<<<dim3(TOK), 256, 0, stream>>>(scr0, t1b, nullptr,
                                                 nullptr, nullptr,   // res = x
                                                 ln_g, ln_b, t2, t2b);

    // ---- FFN ----
    gemmBig(t2b, W1t, nullptr, hb, TOK, D_FF, D_MODEL, b1, 1);
    gemm128c(hb, W2t, t2b, t1b, TOK, D_MODEL, D_FF);          // ff = t2b+t1b+b2
    ln_res_kernel<<<dim3(TOK), 256, 0, stream>>>(t2b, t1b, b2, t2, nullptr,
                                                 ln_g, ln_b, (float*)d_out, nullptr);
}

// Round 21
// 321.071 us; speedup vs baseline: 1.0538x; 1.0251x over previous
//
#include <hip/hip_runtime.h>
#include <hip/hip_bf16.h>

#define D_MODEL 1024
#define N_HEADS 16
#define DH 64
#define D_FF   4096
#define SEQ    1024
#define BATCH  4
#define TOK    (BATCH*SEQ)
#define EPS    1e-5f
#define SCALE  0.125f           // 1/sqrt(64)
#define QSCL   0.18033688f      // SCALE * log2(e): QK^T lands in log2 domain

typedef unsigned short USHORT;
typedef __attribute__((ext_vector_type(8))) short short8v;
typedef __attribute__((ext_vector_type(4))) float f32x4;

__device__ __forceinline__ USHORT f2bf(float f) {
    unsigned int u; __builtin_memcpy(&u, &f, 4);
    u += 0x7fffu + ((u >> 16) & 1u);          // RNE
    return (USHORT)(u >> 16);
}
// 2-op round-half-up pack (P in (0,256] and O: error == RNE magnitude)
__device__ __forceinline__ USHORT f2bf_fast(float f) {
    unsigned int u; __builtin_memcpy(&u, &f, 4);
    return (USHORT)((u + 0x8000u) >> 16);
}
// HW pack: 2 floats -> u32 of 2 bf16 (RNE, v_cvt_pk path); lo -> bits [15:0]
__device__ __forceinline__ unsigned pk2bf(float lo, float hi) {
    __hip_bfloat162 h = __float22bfloat162_rn(make_float2(lo, hi));
    unsigned u; __builtin_memcpy(&u, &h, 4);
    return u;
}
__device__ __forceinline__ float bf2f(USHORT s) {
    unsigned int u = ((unsigned int)s) << 16;
    float f; __builtin_memcpy(&f, &u, 4);
    return f;
}
__device__ __forceinline__ float max3f(float a, float b, float c) {
    return fmaxf(fmaxf(a, b), c);             // fuses to v_max3_f32
}

// row-stride-64 swizzled read: unit ^= row&7
__device__ __forceinline__ short8v ld_frag(const USHORT* lds, int row, int c8) {
    return *reinterpret_cast<const short8v*>(
        &lds[row * 64 + (((c8) ^ (row & 7)) << 3)]);
}
// row-stride-32 swizzled read (BK=32 tiles): unit ^= (row>>1)&3  (2-way = free)
__device__ __forceinline__ short8v ld32(const USHORT* lds, int row, int c8) {
    return *reinterpret_cast<const short8v*>(
        &lds[row * 32 + (((c8) ^ ((row >> 1) & 3)) << 3)]);
}

#define GLDS(gsrc, ldst) \
    __builtin_amdgcn_global_load_lds( \
        (const __attribute__((address_space(1))) void*)(gsrc), \
        (__attribute__((address_space(3))) void*)(ldst), 16, 0, 0)

#define WAITVM(n) asm volatile("s_waitcnt vmcnt(" #n ")" ::: "memory")

// ---------------------------------------------------------------------------
// bf16 MFMA GEMM, 128M x 256N tile, BK=32, 512 threads = 8 waves (2M x 4N,
// wave = 64x64, acc[4][4]).  R21: 3-buffer counted-vmcnt pipeline, ONE
// barrier per iter (R7-proven k32 schedule): stage t+2 after the barrier,
// WAITVM(3) mid-loop -> loads span ~2 MFMA phases (covers L2 latency), and
// barrier count halves vs the 2-buffer double-barrier form.
// LDS = 3 x (8KB A + 16KB B) = 72 KB -> 2 blocks/CU.
// Epilogues: normal (Cf/Cb, +bias/relu) or fused-QKV routing.
// ---------------------------------------------------------------------------
__global__ __launch_bounds__(512) void gemm_k128n256_kernel(
    const USHORT* __restrict__ A, const USHORT* __restrict__ Bt,
    float* __restrict__ Cf, USHORT* __restrict__ Cb, USHORT* __restrict__ Ck,
    USHORT* __restrict__ VtOut,
    int M, int N, int K, const float* __restrict__ bias, int relu, int qkv)
{
    __shared__ USHORT As[3][128 * 32];     // [128 m][32 k], (row>>1)&3 swizzle
    __shared__ USHORT Bs[3][256 * 32];     // [256 n][32 k], (row>>1)&3 swizzle

    const int tid = threadIdx.x;
    const int l   = tid & 63;
    const int w   = tid >> 6;              // 0..7
    const int wr  = w >> 2, wc = w & 3;    // 2M x 4N wave grid
    const int lr  = l & 15, lg = l >> 4;

    const int gx  = gridDim.x;             // N/256
    const int nwg = gx * gridDim.y;
    const int lin = blockIdx.y * gx + blockIdx.x;
    const int swz = (lin & 7) * (nwg >> 3) + (lin >> 3);
    const int m0  = (swz / gx) * 128, n0 = (swz % gx) * 256;

    const int ar = tid >> 2;
    const USHORT* aS = A + (size_t)(m0 + ar) * K
                         + (((tid & 3) ^ ((ar >> 1) & 3)) << 3);
    const int adOf = (w * 64) * 8;

    const USHORT* bS[2]; int bdOf[2];
#pragma unroll
    for (int p = 0; p < 2; ++p) {
        const int q = p * 512 + tid;
        const int row = q >> 2, cu = q & 3;
        bS[p] = Bt + (size_t)(n0 + row) * K + ((cu ^ ((row >> 1) & 3)) << 3);
        bdOf[p] = (p * 512 + w * 64) * 8;
    }

    auto stage = [&](int buf, int k0) {    // 3 GLDS per thread per tile
        GLDS(aS + k0, &As[buf][adOf]);
#pragma unroll
        for (int p = 0; p < 2; ++p)
            GLDS(bS[p] + k0, &Bs[buf][bdOf[p]]);
    };

    f32x4 acc[4][4];
#pragma unroll
    for (int i = 0; i < 4; ++i)
#pragma unroll
        for (int j = 0; j < 4; ++j) acc[i][j] = (f32x4){0.f, 0.f, 0.f, 0.f};

    const int nk = K >> 5;
    stage(0, 0);
    if (nk > 1) stage(1, 32);

    for (int t = 0; t < nk; ++t) {
        const int cur = t % 3;
        if (t + 1 < nk) { WAITVM(3); } else { WAITVM(0); }   // tile t landed
        __builtin_amdgcn_s_barrier();      // all waves done with t-1 + t ready
        if (t + 2 < nk) stage((t + 2) % 3, (t + 2) << 5);

        short8v bfr[4];
#pragma unroll
        for (int ni = 0; ni < 4; ++ni)
            bfr[ni] = ld32(Bs[cur], wc * 64 + ni * 16 + lr, lg);
        __builtin_amdgcn_s_setprio(1);
#pragma unroll
        for (int mi = 0; mi < 4; ++mi) {
            short8v af = ld32(As[cur], wr * 64 + mi * 16 + lr, lg);
#pragma unroll
            for (int ni = 0; ni < 4; ++ni)
                acc[mi][ni] = __builtin_amdgcn_mfma_f32_16x16x32_bf16(
                    af, bfr[ni], acc[mi][ni], 0, 0, 0);
        }
        __builtin_amdgcn_s_setprio(0);
    }

    // epilogue: C/D layout col = lane&15, row = (lane>>4)*4 + reg
    if (qkv) {
#pragma unroll
        for (int mi = 0; mi < 4; ++mi) {
            const int row = m0 + wr * 64 + mi * 16 + (l >> 4) * 4;
#pragma unroll
            for (int ni = 0; ni < 4; ++ni) {
                const int col = n0 + wc * 64 + ni * 16 + lr;
                if (col < 2048) {
                    USHORT* dst = (col < 1024) ? Cb : Ck;
                    const float scl = (col < 1024) ? QSCL : 1.f;  // log2-e domain
                    const int c = col & 1023;
#pragma unroll
                    for (int j = 0; j < 4; ++j)
                        dst[(size_t)(row + j) * D_MODEL + c] =
                            f2bf(acc[mi][ni][j] * scl);
                } else {
                    const int c = col - 2048;
                    const int bb = row >> 10, jr = row & 1023;
                    const int hh = c >> 6, dd = c & 63;
                    uint2 pk = make_uint2(
                        pk2bf(acc[mi][ni][0], acc[mi][ni][1]),
                        pk2bf(acc[mi][ni][2], acc[mi][ni][3]));
                    *reinterpret_cast<uint2*>(
                        &VtOut[((size_t)(bb * 16 + hh) * 64 + dd) * 1024 + jr]) = pk;
                }
            }
        }
    } else {
#pragma unroll
        for (int mi = 0; mi < 4; ++mi) {
            const int row = m0 + wr * 64 + mi * 16 + (l >> 4) * 4;
#pragma unroll
            for (int ni = 0; ni < 4; ++ni) {
                const int col = n0 + wc * 64 + ni * 16 + lr;
                const float bv = bias ? bias[col] : 0.f;
#pragma unroll
                for (int j = 0; j < 4; ++j) {
                    float v = acc[mi][ni][j] + bv;
                    if (relu) v = fmaxf(v, 0.f);
                    const size_t idx = (size_t)(row + j) * N + col;
                    if (Cf) Cf[idx] = v;
                    if (Cb) Cb[idx] = f2bf(v);
                }
            }
        }
    }
}

// ---------------------------------------------------------------------------
// Split-K bf16 GEMM for the N=1024 shapes: 128x128 tile, BK=64, 2-buffer
// counted-vmcnt, 8 waves. Split-K=2, bf16 partials. (unchanged from R15)
// ---------------------------------------------------------------------------
__global__ __launch_bounds__(512) void gemm_k128c_kernel(
    const USHORT* __restrict__ A, const USHORT* __restrict__ Bt,
    USHORT* __restrict__ Pa, USHORT* __restrict__ Pb,
    int M, int N, int K)
{
    __shared__ USHORT As[2][128 * 64];
    __shared__ USHORT Bs[2][128 * 64];

    const int tid = threadIdx.x;
    const int l   = tid & 63;
    const int w   = tid >> 6;
    const int wr  = w >> 2, wc = w & 3;
    const int lr  = l & 15, lg = l >> 4;

    const int gx  = gridDim.x;
    const int nwg = gx * gridDim.y;
    const int lin = blockIdx.y * gx + blockIdx.x;
    const int swz = (lin & 7) * (nwg >> 3) + (lin >> 3);
    const int my  = swz / gx;
    const int mt  = M >> 7;
    const int part = my / mt;
    const int m0  = (my % mt) << 7;
    const int n0  = (swz % gx) * 128;
    const int koff = part * (K >> 1);
    USHORT* dst = part ? Pb : Pa;

    const USHORT* aS[2]; const USHORT* bS[2]; int dOf[2];
#pragma unroll
    for (int p = 0; p < 2; ++p) {
        const int q = p * 512 + tid;
        const int row = q >> 3, cu = q & 7;
        const int cs = ((cu ^ (row & 7)) << 3);
        aS[p] = A  + (size_t)(m0 + row) * K + cs;
        bS[p] = Bt + (size_t)(n0 + row) * K + cs;
        dOf[p] = (p * 512 + w * 64) * 8;
    }

    auto stage = [&](int buf, int k0) {
#pragma unroll
        for (int p = 0; p < 2; ++p) {
            GLDS(aS[p] + k0, &As[buf][dOf[p]]);
            GLDS(bS[p] + k0, &Bs[buf][dOf[p]]);
        }
    };

    f32x4 acc[4][2];
#pragma unroll
    for (int i = 0; i < 4; ++i)
#pragma unroll
        for (int j = 0; j < 2; ++j) acc[i][j] = (f32x4){0.f, 0.f, 0.f, 0.f};

    const int nk = K >> 7;
    stage(0, koff);

    for (int t = 0; t < nk; ++t) {
        const int cur = t & 1;
        if (t + 1 < nk) {
            stage(cur ^ 1, koff + ((t + 1) << 6));
            WAITVM(4);
        } else {
            WAITVM(0);
        }
        __builtin_amdgcn_s_barrier();

#pragma unroll
        for (int ks = 0; ks < 2; ++ks) {
            short8v bfr[2];
#pragma unroll
            for (int ni = 0; ni < 2; ++ni)
                bfr[ni] = ld_frag(Bs[cur], wc * 32 + ni * 16 + lr, ks * 4 + lg);
            __builtin_amdgcn_s_setprio(1);
#pragma unroll
            for (int mi = 0; mi < 4; ++mi) {
                short8v af = ld_frag(As[cur], wr * 64 + mi * 16 + lr, ks * 4 + lg);
#pragma unroll
                for (int ni = 0; ni < 2; ++ni)
                    acc[mi][ni] = __builtin_amdgcn_mfma_f32_16x16x32_bf16(
                        af, bfr[ni], acc[mi][ni], 0, 0, 0);
            }
            __builtin_amdgcn_s_setprio(0);
        }
        __builtin_amdgcn_s_barrier();
    }

#pragma unroll
    for (int mi = 0; mi < 4; ++mi) {
        const int row = m0 + wr * 64 + mi * 16 + (l >> 4) * 4;
#pragma unroll
        for (int ni = 0; ni < 2; ++ni) {
            const int col = n0 + wc * 32 + ni * 16 + lr;
#pragma unroll
            for (int j = 0; j < 4; ++j)
                dst[(size_t)(row + j) * N + col] = f2bf(acc[mi][ni][j]);
        }
    }
}

// ---------------------------------------------------------------------------
// Weight convert+transpose kernels (unchanged).
// ---------------------------------------------------------------------------
struct TcvtB4 {
    const float* s0; const float* s1; const float* s2; const float* s3;
    USHORT* d0; USHORT* d1; USHORT* d2; USHORT* d3;
};

__device__ __forceinline__ void tcvt_body(
    const float* __restrict__ W, USHORT* __restrict__ Wt, int K, int N)
{
    __shared__ USHORT L[64][65];
    const int tid = threadIdx.x;
    const int tx = tid & 15, ty = tid >> 4;
    const int n0 = blockIdx.x * 64, k0 = blockIdx.y * 64;
#pragma unroll
    for (int r = 0; r < 4; ++r) {
        int kr = ty + 16 * r;
        float4 v = *reinterpret_cast<const float4*>(
            &W[(size_t)(k0 + kr) * N + n0 + tx * 4]);
        L[tx * 4 + 0][kr] = f2bf(v.x);
        L[tx * 4 + 1][kr] = f2bf(v.y);
        L[tx * 4 + 2][kr] = f2bf(v.z);
        L[tx * 4 + 3][kr] = f2bf(v.w);
    }
    __syncthreads();
#pragma unroll
    for (int r = 0; r < 4; ++r) {
        int nr = ty + 16 * r;
        ushort4 o = make_ushort4(L[nr][tx * 4 + 0], L[nr][tx * 4 + 1],
                                 L[nr][tx * 4 + 2], L[nr][tx * 4 + 3]);
        *reinterpret_cast<ushort4*>(&Wt[(size_t)(n0 + nr) * K + k0 + tx * 4]) = o;
    }
}

__global__ __launch_bounds__(256) void tcvt_kernel(
    const float* __restrict__ W, USHORT* __restrict__ Wt, int K, int N)
{
    tcvt_body(W, Wt, K, N);
}

__global__ __launch_bounds__(256) void tcvt4_kernel(TcvtB4 p, int K, int N)
{
    const int z = blockIdx.z;
    const float* W = (z == 0) ? p.s0 : (z == 1) ? p.s1 : (z == 2) ? p.s2 : p.s3;
    USHORT*    Wt = (z == 0) ? p.d0 : (z == 1) ? p.d1 : (z == 2) ? p.d2 : p.d3;
    tcvt_body(W, Wt, K, N);
}

__global__ __launch_bounds__(256) void f2b_kernel(
    const float* __restrict__ in, USHORT* __restrict__ out, int n4)
{
    int i = blockIdx.x * 256 + threadIdx.x;
    if (i < n4) {
        float4 v = reinterpret_cast<const float4*>(in)[i];
        reinterpret_cast<ushort4*>(out)[i] =
            make_ushort4(f2bf(v.x), f2bf(v.y), f2bf(v.z), f2bf(v.w));
    }
}

// ---------------------------------------------------------------------------
// MFMA flash attention (R19 structure). R21: causal qt ANTI-PAIRING — with
// grid=512 = exactly 2 blocks/CU, blocks c and c+256 land on the same CU and
// previously had IDENTICAL qt (work ~ qt+1), so worst CUs carried 2x qt=7
// while others 2x qt=0 (measured: causal time == full time). Remap
// qt ^= 7 when bit5 of swz is set (bijective per bh): stride-256 pairs now
// sum to qt=7 -> uniform per-CU work.
// ---------------------------------------------------------------------------
__global__ __launch_bounds__(256) void attn_mfma_kernel(
    const USHORT* __restrict__ Q, const USHORT* __restrict__ K,
    const USHORT* __restrict__ Vt, USHORT* __restrict__ O, int causal)
{
    __shared__ USHORT smem[24576];                 // 48 KB

    const int tid = threadIdx.x;
    const int l  = tid & 63;
    const int w  = tid >> 6;
    const int lr = l & 15;
    const int lg = l >> 4;

    const int lin = blockIdx.y * 8 + blockIdx.x;    // nwg = 512
    const int swz = (lin & 7) * 64 + (lin >> 3);
    const int qtr = swz & 7;
    const int qt  = causal ? (qtr ^ (((swz >> 5) & 1) ? 7 : 0)) : qtr;
    const int bh = swz >> 3;
    const int h = bh & 15, b = bh >> 4;
    const int q0 = qt * 128;

    const USHORT* gq  = Q  + (size_t)(b * SEQ + q0) * D_MODEL + h * DH;
    const USHORT* gk0 = K  + (size_t)b * SEQ * D_MODEL + h * DH;
    const USHORT* gv0 = Vt + (size_t)bh * DH * SEQ;

    auto stageK = [&](int buf, int kt) {           // 64x64, row&7 swizzle
        USHORT* dst = smem + buf * 4096;
        const size_t base = (size_t)kt * 64 * 1024;
#pragma unroll
        for (int p = 0; p < 2; ++p) {
            const int q = p * 256 + tid;
            const int row = q >> 3, cu = q & 7;
            GLDS(gk0 + base + (size_t)row * 1024 + ((cu ^ (row & 7)) << 3),
                 dst + (p * 256 + w * 64) * 8);
        }
    };
    auto stageV = [&](int buf, int kt) {           // 64 d x 64 j, row&7 swizzle
        USHORT* dst = smem + 8192 + buf * 4096;
        const int j0 = kt * 64;
#pragma unroll
        for (int p = 0; p < 2; ++p) {
            const int q = p * 256 + tid;
            const int row = q >> 3, cu = q & 7;
            GLDS(gv0 + (size_t)row * 1024 + j0 + ((cu ^ (row & 7)) << 3),
                 dst + (p * 256 + w * 64) * 8);
        }
    };

    // stage Q (128x64, row&7 swizzle) + first K/V tile
#pragma unroll
    for (int p = 0; p < 4; ++p) {
        const int q = p * 256 + tid;
        const int row = q >> 3, cu = q & 7;
        GLDS(gq + (size_t)row * 1024 + ((cu ^ (row & 7)) << 3),
             smem + 16384 + (p * 256 + w * 64) * 8);
    }
    stageK(0, 0);
    stageV(0, 0);

    f32x4 oacc[2][4];
    float m_[2], l_[2];            // per-lane state for q = w*32 + s*16 + lr
#pragma unroll
    for (int s = 0; s < 2; ++s) {
        m_[s] = -1e30f; l_[s] = 0.f;
#pragma unroll
        for (int d = 0; d < 4; ++d) oacc[s][d] = (f32x4){0.f, 0.f, 0.f, 0.f};
    }

    // P write offsets: row = s*16+lr, j = jb*16 + lg*4 .. +3 (one b64 each)
    int paddr[2][4];
#pragma unroll
    for (int s = 0; s < 2; ++s) {
        const int row = s * 16 + lr;
#pragma unroll
        for (int jb = 0; jb < 4; ++jb) {
            const int cu = jb * 2 + (lg >> 1);
            paddr[s][jb] = row * 64 + ((cu ^ (row & 7)) << 3) + (lg & 1) * 4;
        }
    }

    __syncthreads();                               // Q + tile 0 staged
    short8v qa[2][2];
#pragma unroll
    for (int s = 0; s < 2; ++s) {
        qa[s][0] = ld_frag(smem + 16384, w * 32 + s * 16 + lr, lg);
        qa[s][1] = ld_frag(smem + 16384, w * 32 + s * 16 + lr, 4 + lg);
    }
    __syncthreads();                               // Q consumed -> P may reuse
    USHORT* PsW = smem + 16384 + w * 2048;         // per-wave P [32 q][64 j]

    const int ntile = causal ? (qt * 2 + 2) : (SEQ / 64);
    for (int kt = 0; kt < ntile; ++kt) {
        const int cur = kt & 1;
        if (kt + 1 < ntile) {                      // prefetch next K/V tile
            stageK(cur ^ 1, kt + 1);
            stageV(cur ^ 1, kt + 1);
        }
        const int j0 = kt * 64;
        const USHORT* KsC = smem + cur * 4096;
        const USHORT* VsC = smem + 8192 + cur * 4096;

        // S^T = mfma(K, Q); K frags shared across both q-subtiles
        f32x4 sa[2][4];
        __builtin_amdgcn_s_setprio(1);
#pragma unroll
        for (int jb = 0; jb < 4; ++jb) {
            short8v kf0 = ld_frag(KsC, jb * 16 + lr, lg);
            short8v kf1 = ld_frag(KsC, jb * 16 + lr, 4 + lg);
#pragma unroll
            for (int s = 0; s < 2; ++s) {
                sa[s][jb] = (f32x4){0.f, 0.f, 0.f, 0.f};
                sa[s][jb] = __builtin_amdgcn_mfma_f32_16x16x32_bf16(
                    kf0, qa[s][0], sa[s][jb], 0, 0, 0);
                sa[s][jb] = __builtin_amdgcn_mfma_f32_16x16x32_bf16(
                    kf1, qa[s][1], sa[s][jb], 0, 0, 0);
            }
        }
        __builtin_amdgcn_s_setprio(0);

        // causal mask: only the last two tiles can cross the diagonal
        if (causal && kt >= ntile - 2) {
#pragma unroll
            for (int s = 0; s < 2; ++s) {
                const int qrow = q0 + w * 32 + s * 16 + lr;
#pragma unroll
                for (int jb = 0; jb < 4; ++jb)
#pragma unroll
                    for (int r = 0; r < 4; ++r)
                        if ((j0 + jb * 16 + lg * 4 + r) > qrow)
                            sa[s][jb][r] = -1e30f;
            }
        }

        // per-lane tile max over 16 values per qsub + 2 shfl each
        float tm[2];
#pragma unroll
        for (int s = 0; s < 2; ++s) {
            float t1 = max3f(sa[s][0][0], sa[s][0][1], sa[s][0][2]);
            float t2 = max3f(sa[s][0][3], sa[s][1][0], sa[s][1][1]);
            float t3 = max3f(sa[s][1][2], sa[s][1][3], sa[s][2][0]);
            float t4 = max3f(sa[s][2][1], sa[s][2][2], sa[s][2][3]);
            float t5 = max3f(sa[s][3][0], sa[s][3][1], sa[s][3][2]);
            float tv = fmaxf(max3f(max3f(t1, t2, t3), t4, t5), sa[s][3][3]);
            tv = fmaxf(tv, __shfl_xor(tv, 16));
            tv = fmaxf(tv, __shfl_xor(tv, 32));
            tm[s] = tv;
        }

        // defer-max rescale (wave-gated; broadcast sc from owner lanes)
        const bool anyf = (tm[0] > m_[0] + 8.f) | (tm[1] > m_[1] + 8.f);
        if (__ballot(anyf)) {
            float sc[2];
#pragma unroll
            for (int s = 0; s < 2; ++s) {
                const float mn = (tm[s] > m_[s] + 8.f) ? tm[s] : m_[s];
                sc[s] = exp2f(m_[s] - mn);
                l_[s] *= sc[s];
                m_[s] = mn;
            }
#pragma unroll
            for (int s = 0; s < 2; ++s)
#pragma unroll
                for (int r = 0; r < 4; ++r) {
                    const float scr = __shfl(sc[s], (l & 48) | (lg * 4 + r));
#pragma unroll
                    for (int d = 0; d < 4; ++d) oacc[s][d][r] *= scr;
                }
        }

        // exp (log2 domain) + lane-partial sum + HW pack + b64 P-writes
#pragma unroll
        for (int s = 0; s < 2; ++s)
#pragma unroll
            for (int jb = 0; jb < 4; ++jb) {
                const float p0 = exp2f(sa[s][jb][0] - m_[s]);
                const float p1 = exp2f(sa[s][jb][1] - m_[s]);
                const float p2 = exp2f(sa[s][jb][2] - m_[s]);
                const float p3 = exp2f(sa[s][jb][3] - m_[s]);
                l_[s] += (p0 + p1) + (p2 + p3);
                *reinterpret_cast<uint2*>(&PsW[paddr[s][jb]]) =
                    make_uint2(pk2bf(p0, p1), pk2bf(p2, p3));
            }

        // PV: V frags shared across both q-subtiles
        __builtin_amdgcn_s_setprio(1);
#pragma unroll
        for (int ks = 0; ks < 2; ++ks) {
            short8v pa[2];
#pragma unroll
            for (int s = 0; s < 2; ++s)
                pa[s] = ld_frag(PsW, s * 16 + lr, ks * 4 + lg);
#pragma unroll
            for (int d = 0; d < 4; ++d) {
                short8v vf = ld_frag(VsC, d * 16 + lr, ks * 4 + lg);
#pragma unroll
                for (int s = 0; s < 2; ++s)
                    oacc[s][d] = __builtin_amdgcn_mfma_f32_16x16x32_bf16(
                        pa[s], vf, oacc[s][d], 0, 0, 0);
            }
        }
        __builtin_amdgcn_s_setprio(0);
        __syncthreads();   // drains prefetch + guards K/V/P buffer reuse
    }

    // epilogue: cross-lg l sum per qsub, inv via owner-lane shfl
    USHORT* go = O + (size_t)(b * SEQ + q0 + w * 32) * D_MODEL + h * DH;
#pragma unroll
    for (int s = 0; s < 2; ++s) {
        float lv = l_[s];
        lv += __shfl_xor(lv, 16);
        lv += __shfl_xor(lv, 32);
        const float inv_own = 1.f / lv;
#pragma unroll
        for (int r = 0; r < 4; ++r) {
            const float inv = __shfl(inv_own, (l & 48) | (lg * 4 + r));
            const int qrow = s * 16 + lg * 4 + r;
#pragma unroll
            for (int d = 0; d < 4; ++d)
                go[(size_t)qrow * D_MODEL + d * 16 + lr] =
                    f2bf_fast(oacc[s][d][r] * inv);
        }
    }
}

// ---------------------------------------------------------------------------
// out = res + LayerNorm(x)*g + b, where x = xb (+ xb2) (+ biasx). (unchanged)
// ---------------------------------------------------------------------------
__global__ __launch_bounds__(256) void ln_res_kernel(
    const USHORT* __restrict__ xb, const USHORT* __restrict__ xb2,
    const float* __restrict__ biasx,
    const float* __restrict__ resf, const USHORT* __restrict__ resb,
    const float* __restrict__ g, const float* __restrict__ bta,
    float* __restrict__ outf, USHORT* __restrict__ outb)
{
    __shared__ float red[256];
    __shared__ float s_mu, s_rstd;

    const int row = blockIdx.x;
    const int tid = threadIdx.x;
    ushort4 xv = reinterpret_cast<const ushort4*>(xb + (size_t)row * D_MODEL)[tid];
    float vx = bf2f(xv.x), vy = bf2f(xv.y), vz = bf2f(xv.z), vw = bf2f(xv.w);
    if (xb2) {
        ushort4 x2 = reinterpret_cast<const ushort4*>(
            xb2 + (size_t)row * D_MODEL)[tid];
        vx += bf2f(x2.x); vy += bf2f(x2.y); vz += bf2f(x2.z); vw += bf2f(x2.w);
    }
    if (biasx) {
        float4 bx = reinterpret_cast<const float4*>(biasx)[tid];
        vx += bx.x; vy += bx.y; vz += bx.z; vw += bx.w;
    }

    red[tid] = vx + vy + vz + vw;
    __syncthreads();
    for (int s = 128; s > 0; s >>= 1) {
        if (tid < s) red[tid] += red[tid + s];
        __syncthreads();
    }
    if (tid == 0) s_mu = red[0] * (1.f / D_MODEL);
    __syncthreads();
    const float mu = s_mu;

    float dx = vx - mu, dy = vy - mu, dz = vz - mu, dw = vw - mu;
    red[tid] = dx * dx + dy * dy + dz * dz + dw * dw;
    __syncthreads();
    for (int s = 128; s > 0; s >>= 1) {
        if (tid < s) red[tid] += red[tid + s];
        __syncthreads();
    }
    if (tid == 0) s_rstd = rsqrtf(red[0] * (1.f / D_MODEL) + EPS);
    __syncthreads();
    const float rstd = s_rstd;

    float4 rv;
    if (resf) {
        rv = reinterpret_cast<const float4*>(resf + (size_t)row * D_MODEL)[tid];
    } else if (resb) {
        ushort4 rb = reinterpret_cast<const ushort4*>(
            resb + (size_t)row * D_MODEL)[tid];
        rv = make_float4(bf2f(rb.x), bf2f(rb.y), bf2f(rb.z), bf2f(rb.w));
    } else {
        rv = make_float4(vx, vy, vz, vw);          // res = x (norm_attn2 wiring)
    }
    float4 gv = reinterpret_cast<const float4*>(g)[tid];
    float4 bv = reinterpret_cast<const float4*>(bta)[tid];

    float4 o;
    o.x = rv.x + dx * rstd * gv.x + bv.x;
    o.y = rv.y + dy * rstd * gv.y + bv.y;
    o.z = rv.z + dz * rstd * gv.z + bv.z;
    o.w = rv.w + dw * rstd * gv.w + bv.w;
    reinterpret_cast<float4*>(outf + (size_t)row * D_MODEL)[tid] = o;
    if (outb)
        reinterpret_cast<ushort4*>(outb + (size_t)row * D_MODEL)[tid] =
            make_ushort4(f2bf(o.x), f2bf(o.y), f2bf(o.z), f2bf(o.w));
}

// ---------------------------------------------------------------------------
extern "C" void kernel_launch(void* const* d_in, const int* in_sizes, int n_in,
                              void* d_out, int out_size, void* d_ws, size_t ws_size,
                              hipStream_t stream)
{
    const float* X    = (const float*)d_in[0];
    const float* Wq1  = (const float*)d_in[1];
    const float* Wk1  = (const float*)d_in[2];
    const float* Wv1  = (const float*)d_in[3];
    const float* Wo1  = (const float*)d_in[4];
    const float* Wq2  = (const float*)d_in[5];
    const float* Wk2  = (const float*)d_in[6];
    const float* Wv2  = (const float*)d_in[7];
    const float* Wo2  = (const float*)d_in[8];
    const float* ln_g = (const float*)d_in[9];
    const float* ln_b = (const float*)d_in[10];
    const float* W1   = (const float*)d_in[11];
    const float* b1   = (const float*)d_in[12];
    const float* W2   = (const float*)d_in[13];
    const float* b2   = (const float*)d_in[14];

    const size_t MI = 1024 * 1024;
    USHORT* ws16 = (USHORT*)d_ws;
    USHORT* Wqkv1t = ws16;                 // [0,3Mi); also scr0 after MHA1
    USHORT* scr0   = ws16;
    USHORT* Wo1t   = ws16 + 3 * MI;
    USHORT* Wqkv2t = ws16 + 4 * MI;
    USHORT* Wo2t   = ws16 + 7 * MI;
    USHORT* W2t    = ws16 + 8 * MI;
    USHORT* Xb     = ws16 + 12 * MI;
    USHORT* W1t    = Xb;
    USHORT* qb     = ws16 + 16 * MI;
    USHORT* kb     = ws16 + 20 * MI;
    USHORT* Vtb    = ws16 + 24 * MI;
    USHORT* t0b    = ws16 + 28 * MI;
    USHORT* hb     = qb;
    USHORT* t2b    = ws16 + 32 * MI;
    USHORT* t1b    = ws16 + 36 * MI;
    float*  t2     = (float*)(ws16 + 40 * MI);

    auto gemmBig = [&](const USHORT* A, const USHORT* Bt, float* Cf, USHORT* Cb,
                       int M, int N, int K, const float* bias, int relu) {
        gemm_k128n256_kernel<<<dim3(N / 256, M / 128), 512, 0, stream>>>(
            A, Bt, Cf, Cb, nullptr, nullptr, M, N, K, bias, relu, 0);
    };
    auto gemm_qkv = [&](const USHORT* A, const USHORT* Bt) {
        gemm_k128n256_kernel<<<dim3(3072 / 256, TOK / 128), 512, 0, stream>>>(
            A, Bt, nullptr, qb, kb, Vtb, TOK, 3072, D_MODEL, nullptr, 0, 1);
    };
    auto gemm128c = [&](const USHORT* A, const USHORT* Bt, USHORT* Pa, USHORT* Pb,
                        int M, int N, int K) {
        gemm_k128c_kernel<<<dim3(N / 128, (M / 128) * 2), 512, 0, stream>>>(
            A, Bt, Pa, Pb, M, N, K);
    };

    dim3 agrid(SEQ / 128, BATCH * N_HEADS);

    // ---- prologue: all square weights + W2 + X -> bf16 ----
    {
        TcvtB4 p1{Wq1, Wk1, Wv1, Wo1,
                  Wqkv1t, Wqkv1t + 1 * MI, Wqkv1t + 2 * MI, Wo1t};
        tcvt4_kernel<<<dim3(16, 16, 4), 256, 0, stream>>>(p1, D_MODEL, D_MODEL);
        TcvtB4 p2{Wq2, Wk2, Wv2, Wo2,
                  Wqkv2t, Wqkv2t + 1 * MI, Wqkv2t + 2 * MI, Wo2t};
        tcvt4_kernel<<<dim3(16, 16, 4), 256, 0, stream>>>(p2, D_MODEL, D_MODEL);
    }
    tcvt_kernel<<<dim3(D_MODEL / 64, D_FF / 64), 256, 0, stream>>>(
        W2, W2t, D_FF, D_MODEL);
    f2b_kernel<<<dim3(4096), 256, 0, stream>>>(X, Xb, TOK * D_MODEL / 4);

    // ---- MHA 1 (causal) ----
    gemm_qkv(Xb, Wqkv1t);
    attn_mfma_kernel<<<agrid, 256, 0, stream>>>(qb, kb, Vtb, t0b, 1);
    gemm128c(t0b, Wo1t, t2b, t1b, TOK, D_MODEL, D_MODEL);     // masked = t2b+t1b
    ln_res_kernel<<<dim3(TOK), 256, 0, stream>>>(t2b, t1b, nullptr, X, nullptr,
                                                 ln_g, ln_b, t2, t2b);
    tcvt_kernel<<<dim3(D_FF / 64, D_MODEL / 64), 256, 0, stream>>>(
        W1, W1t, D_MODEL, D_FF);

    // ---- MHA 2 (full) ----
    gemm_qkv(t2b, Wqkv2t);
    attn_mfma_kernel<<<agrid, 256, 0, stream>>>(qb, kb, Vtb, t0b, 0);
    gemm128c(t0b, Wo2t, scr0, t1b, TOK, D_MODEL, D_MODEL);    // attn2 = scr0+t1b
    ln_res_kernel<<<dim3(TOK), 256, 0, stream>>>(scr0, t1b, nullptr,
                                                 nullptr, nullptr,   // res = x
                                                 ln_g, ln_b, t2, t2b);

    // ---- FFN ----
    gemmBig(t2b, W1t, nullptr, hb, TOK, D_FF, D_MODEL, b1, 1);
    gemm128c(hb, W2t, t2b, t1b, TOK, D_MODEL, D_FF);          // ff = t2b+t1b+b2
    ln_res_kernel<<<dim3(TOK), 256, 0, stream>>>(t2b, t1b, b2, t2, nullptr,
                                                 ln_g, ln_b, (float*)d_out, nullptr);
}

// Round 22
// 311.318 us; speedup vs baseline: 1.0868x; 1.0313x over previous
//
#include <hip/hip_runtime.h>
#include <hip/hip_bf16.h>

#define D_MODEL 1024
#define N_HEADS 16
#define DH 64
#define D_FF   4096
#define SEQ    1024
#define BATCH  4
#define TOK    (BATCH*SEQ)
#define EPS    1e-5f
#define SCALE  0.125f           // 1/sqrt(64)
#define QSCL   0.18033688f      // SCALE * log2(e): QK^T lands in log2 domain

typedef unsigned short USHORT;
typedef __attribute__((ext_vector_type(8))) short short8v;
typedef __attribute__((ext_vector_type(4))) float f32x4;

__device__ __forceinline__ USHORT f2bf(float f) {
    unsigned int u; __builtin_memcpy(&u, &f, 4);
    u += 0x7fffu + ((u >> 16) & 1u);          // RNE
    return (USHORT)(u >> 16);
}
// 2-op round-half-up pack (P in (0,256] and O: error == RNE magnitude)
__device__ __forceinline__ USHORT f2bf_fast(float f) {
    unsigned int u; __builtin_memcpy(&u, &f, 4);
    return (USHORT)((u + 0x8000u) >> 16);
}
// HW pack: 2 floats -> u32 of 2 bf16 (RNE, v_cvt_pk path); lo -> bits [15:0]
__device__ __forceinline__ unsigned pk2bf(float lo, float hi) {
    __hip_bfloat162 h = __float22bfloat162_rn(make_float2(lo, hi));
    unsigned u; __builtin_memcpy(&u, &h, 4);
    return u;
}
__device__ __forceinline__ float bf2f(USHORT s) {
    unsigned int u = ((unsigned int)s) << 16;
    float f; __builtin_memcpy(&f, &u, 4);
    return f;
}
__device__ __forceinline__ float max3f(float a, float b, float c) {
    return fmaxf(fmaxf(a, b), c);             // fuses to v_max3_f32
}

// row-stride-64 swizzled read: unit ^= row&7
__device__ __forceinline__ short8v ld_frag(const USHORT* lds, int row, int c8) {
    return *reinterpret_cast<const short8v*>(
        &lds[row * 64 + (((c8) ^ (row & 7)) << 3)]);
}

#define GLDS(gsrc, ldst) \
    __builtin_amdgcn_global_load_lds( \
        (const __attribute__((address_space(1))) void*)(gsrc), \
        (__attribute__((address_space(3))) void*)(ldst), 16, 0, 0)

#define WAITVM(n) asm volatile("s_waitcnt vmcnt(" #n ")" ::: "memory")

// ---------------------------------------------------------------------------
// bf16 MFMA GEMM, 256x256 tile, 8-PHASE pipeline (m201-template port).
// 512 threads = 8 waves (2M x 4N; wave = 128x64, acc[8][4]).
// Per 64-K tile = 4 phases, each:
//   barrier -> ds_read 4 A-frags (+8 B-frags at phase 0, reg-cached for the
//   whole tile) -> issue 1 half-tile GLDS (2 loads) -> setprio + 16 MFMA.
// Staging order per tile kt: ph0/ph1 stage A(kt+1) h0/h1 (target = other
// dbuf, freed when kt-1 finished); ph2/ph3 stage B(kt+2) h0/h1 (target =
// CURRENT dbuf's B, fully reg-read at ph0; ph2's leading barrier guarantees
// all waves passed ph1 => all ph0 B-reads done).
// vmcnt discipline (per-wave): at ph0 of kt, outstanding <= 12 loads
// {B(kt) leftovers < A(kt) < B(kt+1)}; WAITVM(4) forces all but B(kt+1)
// landed -> A(kt),B(kt) ready; B(kt+1) stays in flight (never drain mid-
// loop). Last tile: WAITVM(0). Prologue stages A(0),B(0),B(1) (12 loads).
// LDS: A[d][h]=128x64 @ d*16384+h*8192; B same @ +32768. Total 128 KB.
// Epilogues: normal (Cf/Cb,+bias/relu) or fused-QKV routing (verbatim R18).
// ---------------------------------------------------------------------------
__global__ __launch_bounds__(512) void gemm_k256p8_kernel(
    const USHORT* __restrict__ A, const USHORT* __restrict__ Bt,
    float* __restrict__ Cf, USHORT* __restrict__ Cb, USHORT* __restrict__ Ck,
    USHORT* __restrict__ VtOut,
    int M, int N, int K, const float* __restrict__ bias, int relu, int qkv)
{
    __shared__ USHORT smem[65536];         // 128 KB

    const int tid = threadIdx.x;
    const int l   = tid & 63;
    const int w   = tid >> 6;              // 0..7
    const int wr  = w >> 2, wc = w & 3;    // 2M x 4N wave grid
    const int lr  = l & 15, lg = l >> 4;

    const int gx  = gridDim.x;             // N/256
    const int nwg = gx * gridDim.y;
    const int lin = blockIdx.y * gx + blockIdx.x;
    const int swz = (lin & 7) * (nwg >> 3) + (lin >> 3);
    const int m0  = (swz / gx) * 256, n0 = (swz % gx) * 256;

    // staging source bases: unit q = p*512 + tid; row = q>>3 (p=1: +64),
    // col-unit = (q&7) ^ (row&7)  [same for p=0/1 since rows differ by 64]
    const int srow = tid >> 3;
    const int scol = ((tid & 7) ^ (srow & 7)) << 3;
    const USHORT* aS0 = A  + (size_t)(m0 + srow) * K + scol;
    const USHORT* bS0 = Bt + (size_t)(n0 + srow) * K + scol;
    const int dof0 = (w * 64) * 8;         // wave-uniform LDS dest (p=0)
    const int dof1 = (512 + w * 64) * 8;   // p=1

    auto stageH = [&](int mat, int d, int h, int koff) {  // one half-tile
        const USHORT* src = (mat ? bS0 : aS0) + (size_t)(h * 128) * K + koff;
        USHORT* dst = smem + mat * 32768 + d * 16384 + h * 8192;
        GLDS(src, dst + dof0);
        GLDS(src + (size_t)64 * K, dst + dof1);
    };

    f32x4 acc[8][4];
#pragma unroll
    for (int i = 0; i < 8; ++i)
#pragma unroll
        for (int j = 0; j < 4; ++j) acc[i][j] = (f32x4){0.f, 0.f, 0.f, 0.f};

    const int nk = K >> 6;                 // 64-K tiles

    // prologue: A(0)->buf0, B(0)->buf0, B(1)->buf1 (issue order matters)
    stageH(0, 0, 0, 0);  stageH(0, 0, 1, 0);
    stageH(1, 0, 0, 0);  stageH(1, 0, 1, 0);
    stageH(1, 1, 0, 64); stageH(1, 1, 1, 64);

    for (int kt = 0; kt < nk; ++kt) {
        const int d = kt & 1;
        const USHORT* Ah = smem + d * 16384 + wr * 8192;              // A half = wr
        const USHORT* Bh = smem + 32768 + d * 16384 + (wc >> 1) * 8192;
        const int brow = (wc & 1) * 64;
        short8v bfr[4][2];

#pragma unroll
        for (int g = 0; g < 4; ++g) {
            if (g == 0) {
                if (kt + 1 < nk) { WAITVM(4); } else { WAITVM(0); }
            }
            __builtin_amdgcn_s_barrier();

            if (g == 0) {
#pragma unroll
                for (int ni = 0; ni < 4; ++ni) {
                    bfr[ni][0] = ld_frag(Bh, brow + ni * 16 + lr, lg);
                    bfr[ni][1] = ld_frag(Bh, brow + ni * 16 + lr, 4 + lg);
                }
            }
            short8v a0k0 = ld_frag(Ah, (g * 2) * 16 + lr, lg);
            short8v a0k1 = ld_frag(Ah, (g * 2) * 16 + lr, 4 + lg);
            short8v a1k0 = ld_frag(Ah, (g * 2 + 1) * 16 + lr, lg);
            short8v a1k1 = ld_frag(Ah, (g * 2 + 1) * 16 + lr, 4 + lg);

            if (g == 0 && kt + 1 < nk) stageH(0, (kt + 1) & 1, 0, (kt + 1) * 64);
            if (g == 1 && kt + 1 < nk) stageH(0, (kt + 1) & 1, 1, (kt + 1) * 64);
            if (g == 2 && kt + 2 < nk) stageH(1, kt & 1, 0, (kt + 2) * 64);
            if (g == 3 && kt + 2 < nk) stageH(1, kt & 1, 1, (kt + 2) * 64);

            __builtin_amdgcn_s_setprio(1);
#pragma unroll
            for (int ni = 0; ni < 4; ++ni) {
                acc[g * 2][ni] = __builtin_amdgcn_mfma_f32_16x16x32_bf16(
                    a0k0, bfr[ni][0], acc[g * 2][ni], 0, 0, 0);
                acc[g * 2][ni] = __builtin_amdgcn_mfma_f32_16x16x32_bf16(
                    a0k1, bfr[ni][1], acc[g * 2][ni], 0, 0, 0);
                acc[g * 2 + 1][ni] = __builtin_amdgcn_mfma_f32_16x16x32_bf16(
                    a1k0, bfr[ni][0], acc[g * 2 + 1][ni], 0, 0, 0);
                acc[g * 2 + 1][ni] = __builtin_amdgcn_mfma_f32_16x16x32_bf16(
                    a1k1, bfr[ni][1], acc[g * 2 + 1][ni], 0, 0, 0);
            }
            __builtin_amdgcn_s_setprio(0);
        }
    }

    // epilogue: C/D layout col = lane&15, row = (lane>>4)*4 + reg
    if (qkv) {
#pragma unroll
        for (int mi = 0; mi < 8; ++mi) {
            const int row = m0 + wr * 128 + mi * 16 + (l >> 4) * 4;
#pragma unroll
            for (int ni = 0; ni < 4; ++ni) {
                const int col = n0 + wc * 64 + ni * 16 + lr;
                if (col < 2048) {
                    USHORT* dst = (col < 1024) ? Cb : Ck;
                    const float scl = (col < 1024) ? QSCL : 1.f;  // log2-e domain
                    const int c = col & 1023;
#pragma unroll
                    for (int j = 0; j < 4; ++j)
                        dst[(size_t)(row + j) * D_MODEL + c] =
                            f2bf(acc[mi][ni][j] * scl);
                } else {
                    const int c = col - 2048;
                    const int bb = row >> 10, jr = row & 1023;
                    const int hh = c >> 6, dd = c & 63;
                    uint2 pk = make_uint2(
                        pk2bf(acc[mi][ni][0], acc[mi][ni][1]),
                        pk2bf(acc[mi][ni][2], acc[mi][ni][3]));
                    *reinterpret_cast<uint2*>(
                        &VtOut[((size_t)(bb * 16 + hh) * 64 + dd) * 1024 + jr]) = pk;
                }
            }
        }
    } else {
#pragma unroll
        for (int mi = 0; mi < 8; ++mi) {
            const int row = m0 + wr * 128 + mi * 16 + (l >> 4) * 4;
#pragma unroll
            for (int ni = 0; ni < 4; ++ni) {
                const int col = n0 + wc * 64 + ni * 16 + lr;
                const float bv = bias ? bias[col] : 0.f;
#pragma unroll
                for (int j = 0; j < 4; ++j) {
                    float v = acc[mi][ni][j] + bv;
                    if (relu) v = fmaxf(v, 0.f);
                    const size_t idx = (size_t)(row + j) * N + col;
                    if (Cf) Cf[idx] = v;
                    if (Cb) Cb[idx] = f2bf(v);
                }
            }
        }
    }
}

// ---------------------------------------------------------------------------
// Split-K bf16 GEMM for the N=1024 shapes: 128x128 tile, BK=64, 2-buffer
// counted-vmcnt, 8 waves. Split-K=2, bf16 partials. (unchanged from R15)
// ---------------------------------------------------------------------------
__global__ __launch_bounds__(512) void gemm_k128c_kernel(
    const USHORT* __restrict__ A, const USHORT* __restrict__ Bt,
    USHORT* __restrict__ Pa, USHORT* __restrict__ Pb,
    int M, int N, int K)
{
    __shared__ USHORT As[2][128 * 64];
    __shared__ USHORT Bs[2][128 * 64];

    const int tid = threadIdx.x;
    const int l   = tid & 63;
    const int w   = tid >> 6;
    const int wr  = w >> 2, wc = w & 3;
    const int lr  = l & 15, lg = l >> 4;

    const int gx  = gridDim.x;
    const int nwg = gx * gridDim.y;
    const int lin = blockIdx.y * gx + blockIdx.x;
    const int swz = (lin & 7) * (nwg >> 3) + (lin >> 3);
    const int my  = swz / gx;
    const int mt  = M >> 7;
    const int part = my / mt;
    const int m0  = (my % mt) << 7;
    const int n0  = (swz % gx) * 128;
    const int koff = part * (K >> 1);
    USHORT* dst = part ? Pb : Pa;

    const USHORT* aS[2]; const USHORT* bS[2]; int dOf[2];
#pragma unroll
    for (int p = 0; p < 2; ++p) {
        const int q = p * 512 + tid;
        const int row = q >> 3, cu = q & 7;
        const int cs = ((cu ^ (row & 7)) << 3);
        aS[p] = A  + (size_t)(m0 + row) * K + cs;
        bS[p] = Bt + (size_t)(n0 + row) * K + cs;
        dOf[p] = (p * 512 + w * 64) * 8;
    }

    auto stage = [&](int buf, int k0) {
#pragma unroll
        for (int p = 0; p < 2; ++p) {
            GLDS(aS[p] + k0, &As[buf][dOf[p]]);
            GLDS(bS[p] + k0, &Bs[buf][dOf[p]]);
        }
    };

    f32x4 acc[4][2];
#pragma unroll
    for (int i = 0; i < 4; ++i)
#pragma unroll
        for (int j = 0; j < 2; ++j) acc[i][j] = (f32x4){0.f, 0.f, 0.f, 0.f};

    const int nk = K >> 7;
    stage(0, koff);

    for (int t = 0; t < nk; ++t) {
        const int cur = t & 1;
        if (t + 1 < nk) {
            stage(cur ^ 1, koff + ((t + 1) << 6));
            WAITVM(4);
        } else {
            WAITVM(0);
        }
        __builtin_amdgcn_s_barrier();

#pragma unroll
        for (int ks = 0; ks < 2; ++ks) {
            short8v bfr[2];
#pragma unroll
            for (int ni = 0; ni < 2; ++ni)
                bfr[ni] = ld_frag(Bs[cur], wc * 32 + ni * 16 + lr, ks * 4 + lg);
            __builtin_amdgcn_s_setprio(1);
#pragma unroll
            for (int mi = 0; mi < 4; ++mi) {
                short8v af = ld_frag(As[cur], wr * 64 + mi * 16 + lr, ks * 4 + lg);
#pragma unroll
                for (int ni = 0; ni < 2; ++ni)
                    acc[mi][ni] = __builtin_amdgcn_mfma_f32_16x16x32_bf16(
                        af, bfr[ni], acc[mi][ni], 0, 0, 0);
            }
            __builtin_amdgcn_s_setprio(0);
        }
        __builtin_amdgcn_s_barrier();
    }

#pragma unroll
    for (int mi = 0; mi < 4; ++mi) {
        const int row = m0 + wr * 64 + mi * 16 + (l >> 4) * 4;
#pragma unroll
        for (int ni = 0; ni < 2; ++ni) {
            const int col = n0 + wc * 32 + ni * 16 + lr;
#pragma unroll
            for (int j = 0; j < 4; ++j)
                dst[(size_t)(row + j) * N + col] = f2bf(acc[mi][ni][j]);
        }
    }
}

// ---------------------------------------------------------------------------
// Weight convert+transpose kernels (unchanged).
// ---------------------------------------------------------------------------
struct TcvtB4 {
    const float* s0; const float* s1; const float* s2; const float* s3;
    USHORT* d0; USHORT* d1; USHORT* d2; USHORT* d3;
};

__device__ __forceinline__ void tcvt_body(
    const float* __restrict__ W, USHORT* __restrict__ Wt, int K, int N)
{
    __shared__ USHORT L[64][65];
    const int tid = threadIdx.x;
    const int tx = tid & 15, ty = tid >> 4;
    const int n0 = blockIdx.x * 64, k0 = blockIdx.y * 64;
#pragma unroll
    for (int r = 0; r < 4; ++r) {
        int kr = ty + 16 * r;
        float4 v = *reinterpret_cast<const float4*>(
            &W[(size_t)(k0 + kr) * N + n0 + tx * 4]);
        L[tx * 4 + 0][kr] = f2bf(v.x);
        L[tx * 4 + 1][kr] = f2bf(v.y);
        L[tx * 4 + 2][kr] = f2bf(v.z);
        L[tx * 4 + 3][kr] = f2bf(v.w);
    }
    __syncthreads();
#pragma unroll
    for (int r = 0; r < 4; ++r) {
        int nr = ty + 16 * r;
        ushort4 o = make_ushort4(L[nr][tx * 4 + 0], L[nr][tx * 4 + 1],
                                 L[nr][tx * 4 + 2], L[nr][tx * 4 + 3]);
        *reinterpret_cast<ushort4*>(&Wt[(size_t)(n0 + nr) * K + k0 + tx * 4]) = o;
    }
}

__global__ __launch_bounds__(256) void tcvt_kernel(
    const float* __restrict__ W, USHORT* __restrict__ Wt, int K, int N)
{
    tcvt_body(W, Wt, K, N);
}

__global__ __launch_bounds__(256) void tcvt4_kernel(TcvtB4 p, int K, int N)
{
    const int z = blockIdx.z;
    const float* W = (z == 0) ? p.s0 : (z == 1) ? p.s1 : (z == 2) ? p.s2 : p.s3;
    USHORT*    Wt = (z == 0) ? p.d0 : (z == 1) ? p.d1 : (z == 2) ? p.d2 : p.d3;
    tcvt_body(W, Wt, K, N);
}

__global__ __launch_bounds__(256) void f2b_kernel(
    const float* __restrict__ in, USHORT* __restrict__ out, int n4)
{
    int i = blockIdx.x * 256 + threadIdx.x;
    if (i < n4) {
        float4 v = reinterpret_cast<const float4*>(in)[i];
        reinterpret_cast<ushort4*>(out)[i] =
            make_ushort4(f2bf(v.x), f2bf(v.y), f2bf(v.z), f2bf(v.w));
    }
}

// ---------------------------------------------------------------------------
// MFMA flash attention (unchanged from R21): QBLK=128, KVBLK=64, 4 waves,
// wave owns two 16-row q-subtiles sharing K/V frags, 48 KB LDS, swapped QK^T,
// per-lane softmax state, log2 domain, defer-max, cvt_pk P pack, causal
// qt anti-pairing for load balance.
// ---------------------------------------------------------------------------
__global__ __launch_bounds__(256) void attn_mfma_kernel(
    const USHORT* __restrict__ Q, const USHORT* __restrict__ K,
    const USHORT* __restrict__ Vt, USHORT* __restrict__ O, int causal)
{
    __shared__ USHORT smem[24576];                 // 48 KB

    const int tid = threadIdx.x;
    const int l  = tid & 63;
    const int w  = tid >> 6;
    const int lr = l & 15;
    const int lg = l >> 4;

    const int lin = blockIdx.y * 8 + blockIdx.x;    // nwg = 512
    const int swz = (lin & 7) * 64 + (lin >> 3);
    const int qtr = swz & 7;
    const int qt  = causal ? (qtr ^ (((swz >> 5) & 1) ? 7 : 0)) : qtr;
    const int bh = swz >> 3;
    const int h = bh & 15, b = bh >> 4;
    const int q0 = qt * 128;

    const USHORT* gq  = Q  + (size_t)(b * SEQ + q0) * D_MODEL + h * DH;
    const USHORT* gk0 = K  + (size_t)b * SEQ * D_MODEL + h * DH;
    const USHORT* gv0 = Vt + (size_t)bh * DH * SEQ;

    auto stageK = [&](int buf, int kt) {           // 64x64, row&7 swizzle
        USHORT* dst = smem + buf * 4096;
        const size_t base = (size_t)kt * 64 * 1024;
#pragma unroll
        for (int p = 0; p < 2; ++p) {
            const int q = p * 256 + tid;
            const int row = q >> 3, cu = q & 7;
            GLDS(gk0 + base + (size_t)row * 1024 + ((cu ^ (row & 7)) << 3),
                 dst + (p * 256 + w * 64) * 8);
        }
    };
    auto stageV = [&](int buf, int kt) {           // 64 d x 64 j, row&7 swizzle
        USHORT* dst = smem + 8192 + buf * 4096;
        const int j0 = kt * 64;
#pragma unroll
        for (int p = 0; p < 2; ++p) {
            const int q = p * 256 + tid;
            const int row = q >> 3, cu = q & 7;
            GLDS(gv0 + (size_t)row * 1024 + j0 + ((cu ^ (row & 7)) << 3),
                 dst + (p * 256 + w * 64) * 8);
        }
    };

    // stage Q (128x64, row&7 swizzle) + first K/V tile
#pragma unroll
    for (int p = 0; p < 4; ++p) {
        const int q = p * 256 + tid;
        const int row = q >> 3, cu = q & 7;
        GLDS(gq + (size_t)row * 1024 + ((cu ^ (row & 7)) << 3),
             smem + 16384 + (p * 256 + w * 64) * 8);
    }
    stageK(0, 0);
    stageV(0, 0);

    f32x4 oacc[2][4];
    float m_[2], l_[2];            // per-lane state for q = w*32 + s*16 + lr
#pragma unroll
    for (int s = 0; s < 2; ++s) {
        m_[s] = -1e30f; l_[s] = 0.f;
#pragma unroll
        for (int d = 0; d < 4; ++d) oacc[s][d] = (f32x4){0.f, 0.f, 0.f, 0.f};
    }

    // P write offsets: row = s*16+lr, j = jb*16 + lg*4 .. +3 (one b64 each)
    int paddr[2][4];
#pragma unroll
    for (int s = 0; s < 2; ++s) {
        const int row = s * 16 + lr;
#pragma unroll
        for (int jb = 0; jb < 4; ++jb) {
            const int cu = jb * 2 + (lg >> 1);
            paddr[s][jb] = row * 64 + ((cu ^ (row & 7)) << 3) + (lg & 1) * 4;
        }
    }

    __syncthreads();                               // Q + tile 0 staged
    short8v qa[2][2];
#pragma unroll
    for (int s = 0; s < 2; ++s) {
        qa[s][0] = ld_frag(smem + 16384, w * 32 + s * 16 + lr, lg);
        qa[s][1] = ld_frag(smem + 16384, w * 32 + s * 16 + lr, 4 + lg);
    }
    __syncthreads();                               // Q consumed -> P may reuse
    USHORT* PsW = smem + 16384 + w * 2048;         // per-wave P [32 q][64 j]

    const int ntile = causal ? (qt * 2 + 2) : (SEQ / 64);
    for (int kt = 0; kt < ntile; ++kt) {
        const int cur = kt & 1;
        if (kt + 1 < ntile) {                      // prefetch next K/V tile
            stageK(cur ^ 1, kt + 1);
            stageV(cur ^ 1, kt + 1);
        }
        const int j0 = kt * 64;
        const USHORT* KsC = smem + cur * 4096;
        const USHORT* VsC = smem + 8192 + cur * 4096;

        // S^T = mfma(K, Q); K frags shared across both q-subtiles
        f32x4 sa[2][4];
        __builtin_amdgcn_s_setprio(1);
#pragma unroll
        for (int jb = 0; jb < 4; ++jb) {
            short8v kf0 = ld_frag(KsC, jb * 16 + lr, lg);
            short8v kf1 = ld_frag(KsC, jb * 16 + lr, 4 + lg);
#pragma unroll
            for (int s = 0; s < 2; ++s) {
                sa[s][jb] = (f32x4){0.f, 0.f, 0.f, 0.f};
                sa[s][jb] = __builtin_amdgcn_mfma_f32_16x16x32_bf16(
                    kf0, qa[s][0], sa[s][jb], 0, 0, 0);
                sa[s][jb] = __builtin_amdgcn_mfma_f32_16x16x32_bf16(
                    kf1, qa[s][1], sa[s][jb], 0, 0, 0);
            }
        }
        __builtin_amdgcn_s_setprio(0);

        // causal mask: only the last two tiles can cross the diagonal
        if (causal && kt >= ntile - 2) {
#pragma unroll
            for (int s = 0; s < 2; ++s) {
                const int qrow = q0 + w * 32 + s * 16 + lr;
#pragma unroll
                for (int jb = 0; jb < 4; ++jb)
#pragma unroll
                    for (int r = 0; r < 4; ++r)
                        if ((j0 + jb * 16 + lg * 4 + r) > qrow)
                            sa[s][jb][r] = -1e30f;
            }
        }

        // per-lane tile max over 16 values per qsub + 2 shfl each
        float tm[2];
#pragma unroll
        for (int s = 0; s < 2; ++s) {
            float t1 = max3f(sa[s][0][0], sa[s][0][1], sa[s][0][2]);
            float t2 = max3f(sa[s][0][3], sa[s][1][0], sa[s][1][1]);
            float t3 = max3f(sa[s][1][2], sa[s][1][3], sa[s][2][0]);
            float t4 = max3f(sa[s][2][1], sa[s][2][2], sa[s][2][3]);
            float t5 = max3f(sa[s][3][0], sa[s][3][1], sa[s][3][2]);
            float tv = fmaxf(max3f(max3f(t1, t2, t3), t4, t5), sa[s][3][3]);
            tv = fmaxf(tv, __shfl_xor(tv, 16));
            tv = fmaxf(tv, __shfl_xor(tv, 32));
            tm[s] = tv;
        }

        // defer-max rescale (wave-gated; broadcast sc from owner lanes)
        const bool anyf = (tm[0] > m_[0] + 8.f) | (tm[1] > m_[1] + 8.f);
        if (__ballot(anyf)) {
            float sc[2];
#pragma unroll
            for (int s = 0; s < 2; ++s) {
                const float mn = (tm[s] > m_[s] + 8.f) ? tm[s] : m_[s];
                sc[s] = exp2f(m_[s] - mn);
                l_[s] *= sc[s];
                m_[s] = mn;
            }
#pragma unroll
            for (int s = 0; s < 2; ++s)
#pragma unroll
                for (int r = 0; r < 4; ++r) {
                    const float scr = __shfl(sc[s], (l & 48) | (lg * 4 + r));
#pragma unroll
                    for (int d = 0; d < 4; ++d) oacc[s][d][r] *= scr;
                }
        }

        // exp (log2 domain) + lane-partial sum + HW pack + b64 P-writes
#pragma unroll
        for (int s = 0; s < 2; ++s)
#pragma unroll
            for (int jb = 0; jb < 4; ++jb) {
                const float p0 = exp2f(sa[s][jb][0] - m_[s]);
                const float p1 = exp2f(sa[s][jb][1] - m_[s]);
                const float p2 = exp2f(sa[s][jb][2] - m_[s]);
                const float p3 = exp2f(sa[s][jb][3] - m_[s]);
                l_[s] += (p0 + p1) + (p2 + p3);
                *reinterpret_cast<uint2*>(&PsW[paddr[s][jb]]) =
                    make_uint2(pk2bf(p0, p1), pk2bf(p2, p3));
            }

        // PV: V frags shared across both q-subtiles
        __builtin_amdgcn_s_setprio(1);
#pragma unroll
        for (int ks = 0; ks < 2; ++ks) {
            short8v pa[2];
#pragma unroll
            for (int s = 0; s < 2; ++s)
                pa[s] = ld_frag(PsW, s * 16 + lr, ks * 4 + lg);
#pragma unroll
            for (int d = 0; d < 4; ++d) {
                short8v vf = ld_frag(VsC, d * 16 + lr, ks * 4 + lg);
#pragma unroll
                for (int s = 0; s < 2; ++s)
                    oacc[s][d] = __builtin_amdgcn_mfma_f32_16x16x32_bf16(
                        pa[s], vf, oacc[s][d], 0, 0, 0);
            }
        }
        __builtin_amdgcn_s_setprio(0);
        __syncthreads();   // drains prefetch + guards K/V/P buffer reuse
    }

    // epilogue: cross-lg l sum per qsub, inv via owner-lane shfl
    USHORT* go = O + (size_t)(b * SEQ + q0 + w * 32) * D_MODEL + h * DH;
#pragma unroll
    for (int s = 0; s < 2; ++s) {
        float lv = l_[s];
        lv += __shfl_xor(lv, 16);
        lv += __shfl_xor(lv, 32);
        const float inv_own = 1.f / lv;
#pragma unroll
        for (int r = 0; r < 4; ++r) {
            const float inv = __shfl(inv_own, (l & 48) | (lg * 4 + r));
            const int qrow = s * 16 + lg * 4 + r;
#pragma unroll
            for (int d = 0; d < 4; ++d)
                go[(size_t)qrow * D_MODEL + d * 16 + lr] =
                    f2bf_fast(oacc[s][d][r] * inv);
        }
    }
}

// ---------------------------------------------------------------------------
// out = res + LayerNorm(x)*g + b, where x = xb (+ xb2) (+ biasx). (unchanged)
// ---------------------------------------------------------------------------
__global__ __launch_bounds__(256) void ln_res_kernel(
    const USHORT* __restrict__ xb, const USHORT* __restrict__ xb2,
    const float* __restrict__ biasx,
    const float* __restrict__ resf, const USHORT* __restrict__ resb,
    const float* __restrict__ g, const float* __restrict__ bta,
    float* __restrict__ outf, USHORT* __restrict__ outb)
{
    __shared__ float red[256];
    __shared__ float s_mu, s_rstd;

    const int row = blockIdx.x;
    const int tid = threadIdx.x;
    ushort4 xv = reinterpret_cast<const ushort4*>(xb + (size_t)row * D_MODEL)[tid];
    float vx = bf2f(xv.x), vy = bf2f(xv.y), vz = bf2f(xv.z), vw = bf2f(xv.w);
    if (xb2) {
        ushort4 x2 = reinterpret_cast<const ushort4*>(
            xb2 + (size_t)row * D_MODEL)[tid];
        vx += bf2f(x2.x); vy += bf2f(x2.y); vz += bf2f(x2.z); vw += bf2f(x2.w);
    }
    if (biasx) {
        float4 bx = reinterpret_cast<const float4*>(biasx)[tid];
        vx += bx.x; vy += bx.y; vz += bx.z; vw += bx.w;
    }

    red[tid] = vx + vy + vz + vw;
    __syncthreads();
    for (int s = 128; s > 0; s >>= 1) {
        if (tid < s) red[tid] += red[tid + s];
        __syncthreads();
    }
    if (tid == 0) s_mu = red[0] * (1.f / D_MODEL);
    __syncthreads();
    const float mu = s_mu;

    float dx = vx - mu, dy = vy - mu, dz = vz - mu, dw = vw - mu;
    red[tid] = dx * dx + dy * dy + dz * dz + dw * dw;
    __syncthreads();
    for (int s = 128; s > 0; s >>= 1) {
        if (tid < s) red[tid] += red[tid + s];
        __syncthreads();
    }
    if (tid == 0) s_rstd = rsqrtf(red[0] * (1.f / D_MODEL) + EPS);
    __syncthreads();
    const float rstd = s_rstd;

    float4 rv;
    if (resf) {
        rv = reinterpret_cast<const float4*>(resf + (size_t)row * D_MODEL)[tid];
    } else if (resb) {
        ushort4 rb = reinterpret_cast<const ushort4*>(
            resb + (size_t)row * D_MODEL)[tid];
        rv = make_float4(bf2f(rb.x), bf2f(rb.y), bf2f(rb.z), bf2f(rb.w));
    } else {
        rv = make_float4(vx, vy, vz, vw);          // res = x (norm_attn2 wiring)
    }
    float4 gv = reinterpret_cast<const float4*>(g)[tid];
    float4 bv = reinterpret_cast<const float4*>(bta)[tid];

    float4 o;
    o.x = rv.x + dx * rstd * gv.x + bv.x;
    o.y = rv.y + dy * rstd * gv.y + bv.y;
    o.z = rv.z + dz * rstd * gv.z + bv.z;
    o.w = rv.w + dw * rstd * gv.w + bv.w;
    reinterpret_cast<float4*>(outf + (size_t)row * D_MODEL)[tid] = o;
    if (outb)
        reinterpret_cast<ushort4*>(outb + (size_t)row * D_MODEL)[tid] =
            make_ushort4(f2bf(o.x), f2bf(o.y), f2bf(o.z), f2bf(o.w));
}

// ---------------------------------------------------------------------------
extern "C" void kernel_launch(void* const* d_in, const int* in_sizes, int n_in,
                              void* d_out, int out_size, void* d_ws, size_t ws_size,
                              hipStream_t stream)
{
    const float* X    = (const float*)d_in[0];
    const float* Wq1  = (const float*)d_in[1];
    const float* Wk1  = (const float*)d_in[2];
    const float* Wv1  = (const float*)d_in[3];
    const float* Wo1  = (const float*)d_in[4];
    const float* Wq2  = (const float*)d_in[5];
    const float* Wk2  = (const float*)d_in[6];
    const float* Wv2  = (const float*)d_in[7];
    const float* Wo2  = (const float*)d_in[8];
    const float* ln_g = (const float*)d_in[9];
    const float* ln_b = (const float*)d_in[10];
    const float* W1   = (const float*)d_in[11];
    const float* b1   = (const float*)d_in[12];
    const float* W2   = (const float*)d_in[13];
    const float* b2   = (const float*)d_in[14];

    const size_t MI = 1024 * 1024;
    USHORT* ws16 = (USHORT*)d_ws;
    USHORT* Wqkv1t = ws16;                 // [0,3Mi); also scr0 after MHA1
    USHORT* scr0   = ws16;
    USHORT* Wo1t   = ws16 + 3 * MI;
    USHORT* Wqkv2t = ws16 + 4 * MI;
    USHORT* Wo2t   = ws16 + 7 * MI;
    USHORT* W2t    = ws16 + 8 * MI;
    USHORT* Xb     = ws16 + 12 * MI;
    USHORT* W1t    = Xb;
    USHORT* qb     = ws16 + 16 * MI;
    USHORT* kb     = ws16 + 20 * MI;
    USHORT* Vtb    = ws16 + 24 * MI;
    USHORT* t0b    = ws16 + 28 * MI;
    USHORT* hb     = qb;
    USHORT* t2b    = ws16 + 32 * MI;
    USHORT* t1b    = ws16 + 36 * MI;
    float*  t2     = (float*)(ws16 + 40 * MI);

    auto gemmBig = [&](const USHORT* A, const USHORT* Bt, float* Cf, USHORT* Cb,
                       int M, int N, int K, const float* bias, int relu) {
        gemm_k256p8_kernel<<<dim3(N / 256, M / 256), 512, 0, stream>>>(
            A, Bt, Cf, Cb, nullptr, nullptr, M, N, K, bias, relu, 0);
    };
    auto gemm_qkv = [&](const USHORT* A, const USHORT* Bt) {
        gemm_k256p8_kernel<<<dim3(3072 / 256, TOK / 256), 512, 0, stream>>>(
            A, Bt, nullptr, qb, kb, Vtb, TOK, 3072, D_MODEL, nullptr, 0, 1);
    };
    auto gemm128c = [&](const USHORT* A, const USHORT* Bt, USHORT* Pa, USHORT* Pb,
                        int M, int N, int K) {
        gemm_k128c_kernel<<<dim3(N / 128, (M / 128) * 2), 512, 0, stream>>>(
            A, Bt, Pa, Pb, M, N, K);
    };

    dim3 agrid(SEQ / 128, BATCH * N_HEADS);

    // ---- prologue: all square weights + W2 + X -> bf16 ----
    {
        TcvtB4 p1{Wq1, Wk1, Wv1, Wo1,
                  Wqkv1t, Wqkv1t + 1 * MI, Wqkv1t + 2 * MI, Wo1t};
        tcvt4_kernel<<<dim3(16, 16, 4), 256, 0, stream>>>(p1, D_MODEL, D_MODEL);
        TcvtB4 p2{Wq2, Wk2, Wv2, Wo2,
                  Wqkv2t, Wqkv2t + 1 * MI, Wqkv2t + 2 * MI, Wo2t};
        tcvt4_kernel<<<dim3(16, 16, 4), 256, 0, stream>>>(p2, D_MODEL, D_MODEL);
    }
    tcvt_kernel<<<dim3(D_MODEL / 64, D_FF / 64), 256, 0, stream>>>(
        W2, W2t, D_FF, D_MODEL);
    f2b_kernel<<<dim3(4096), 256, 0, stream>>>(X, Xb, TOK * D_MODEL / 4);

    // ---- MHA 1 (causal) ----
    gemm_qkv(Xb, Wqkv1t);
    attn_mfma_kernel<<<agrid, 256, 0, stream>>>(qb, kb, Vtb, t0b, 1);
    gemm128c(t0b, Wo1t, t2b, t1b, TOK, D_MODEL, D_MODEL);     // masked = t2b+t1b
    ln_res_kernel<<<dim3(TOK), 256, 0, stream>>>(t2b, t1b, nullptr, X, nullptr,
                                                 ln_g, ln_b, t2, t2b);
    tcvt_kernel<<<dim3(D_FF / 64, D_MODEL / 64), 256, 0, stream>>>(
        W1, W1t, D_MODEL, D_FF);

    // ---- MHA 2 (full) ----
    gemm_qkv(t2b, Wqkv2t);
    attn_mfma_kernel<<<agrid, 256, 0, stream>>>(qb, kb, Vtb, t0b, 0);
    gemm128c(t0b, Wo2t, scr0, t1b, TOK, D_MODEL, D_MODEL);    // attn2 = scr0+t1b
    ln_res_kernel<<<dim3(TOK), 256, 0, stream>>>(scr0, t1b, nullptr,
                                                 nullptr, nullptr,   // res = x
                                                 ln_g, ln_b, t2, t2b);

    // ---- FFN ----
    gemmBig(t2b, W1t, nullptr, hb, TOK, D_FF, D_MODEL, b1, 1);
    gemm128c(hb, W2t, t2b, t1b, TOK, D_MODEL, D_FF);          // ff = t2b+t1b+b2
    ln_res_kernel<<<dim3(TOK), 256, 0, stream>>>(t2b, t1b, b2, t2, nullptr,
                                                 ln_g, ln_b, (float*)d_out, nullptr);
}

// Round 24
// 306.781 us; speedup vs baseline: 1.1029x; 1.0148x over previous
//
#include <hip/hip_runtime.h>
#include <hip/hip_bf16.h>

#define D_MODEL 1024
#define N_HEADS 16
#define DH 64
#define D_FF   4096
#define SEQ    1024
#define BATCH  4
#define TOK    (BATCH*SEQ)
#define EPS    1e-5f
#define SCALE  0.125f           // 1/sqrt(64)
#define QSCL   0.18033688f      // SCALE * log2(e): QK^T lands in log2 domain

typedef unsigned short USHORT;
typedef __attribute__((ext_vector_type(8))) short short8v;
typedef __attribute__((ext_vector_type(4))) float f32x4;

__device__ __forceinline__ USHORT f2bf(float f) {
    unsigned int u; __builtin_memcpy(&u, &f, 4);
    u += 0x7fffu + ((u >> 16) & 1u);          // RNE
    return (USHORT)(u >> 16);
}
// 2-op round-half-up pack (P in (0,256] and O: error == RNE magnitude)
__device__ __forceinline__ USHORT f2bf_fast(float f) {
    unsigned int u; __builtin_memcpy(&u, &f, 4);
    return (USHORT)((u + 0x8000u) >> 16);
}
// HW pack: 2 floats -> u32 of 2 bf16 (RNE, v_cvt_pk path); lo -> bits [15:0]
__device__ __forceinline__ unsigned pk2bf(float lo, float hi) {
    __hip_bfloat162 h = __float22bfloat162_rn(make_float2(lo, hi));
    unsigned u; __builtin_memcpy(&u, &h, 4);
    return u;
}
__device__ __forceinline__ float bf2f(USHORT s) {
    unsigned int u = ((unsigned int)s) << 16;
    float f; __builtin_memcpy(&f, &u, 4);
    return f;
}
__device__ __forceinline__ float max3f(float a, float b, float c) {
    return fmaxf(fmaxf(a, b), c);             // fuses to v_max3_f32
}
// fast exp2: straight v_exp_f32 (args are <= 0 here; HW underflow->0 is
// exactly right for masked entries). OCML wrapper's clamp path skipped.
__device__ __forceinline__ float fexp2(float x) {
#if __has_builtin(__builtin_amdgcn_exp2f)
    return __builtin_amdgcn_exp2f(x);
#else
    return exp2f(x);
#endif
}

// row-stride-64 swizzled read: unit ^= row&7
__device__ __forceinline__ short8v ld_frag(const USHORT* lds, int row, int c8) {
    return *reinterpret_cast<const short8v*>(
        &lds[row * 64 + (((c8) ^ (row & 7)) << 3)]);
}

#define GLDS(gsrc, ldst) \
    __builtin_amdgcn_global_load_lds( \
        (const __attribute__((address_space(1))) void*)(gsrc), \
        (__attribute__((address_space(3))) void*)(ldst), 16, 0, 0)

#define WAITVM(n) asm volatile("s_waitcnt vmcnt(" #n ")" ::: "memory")

// ---------------------------------------------------------------------------
// bf16 MFMA GEMM, 256x256 tile, 8-PHASE pipeline (unchanged from R22).
// ---------------------------------------------------------------------------
__global__ __launch_bounds__(512) void gemm_k256p8_kernel(
    const USHORT* __restrict__ A, const USHORT* __restrict__ Bt,
    float* __restrict__ Cf, USHORT* __restrict__ Cb, USHORT* __restrict__ Ck,
    USHORT* __restrict__ VtOut,
    int M, int N, int K, const float* __restrict__ bias, int relu, int qkv)
{
    __shared__ USHORT smem[65536];         // 128 KB

    const int tid = threadIdx.x;
    const int l   = tid & 63;
    const int w   = tid >> 6;              // 0..7
    const int wr  = w >> 2, wc = w & 3;    // 2M x 4N wave grid
    const int lr  = l & 15, lg = l >> 4;

    const int gx  = gridDim.x;             // N/256
    const int nwg = gx * gridDim.y;
    const int lin = blockIdx.y * gx + blockIdx.x;
    const int swz = (lin & 7) * (nwg >> 3) + (lin >> 3);
    const int m0  = (swz / gx) * 256, n0 = (swz % gx) * 256;

    const int srow = tid >> 3;
    const int scol = ((tid & 7) ^ (srow & 7)) << 3;
    const USHORT* aS0 = A  + (size_t)(m0 + srow) * K + scol;
    const USHORT* bS0 = Bt + (size_t)(n0 + srow) * K + scol;
    const int dof0 = (w * 64) * 8;
    const int dof1 = (512 + w * 64) * 8;

    auto stageH = [&](int mat, int d, int h, int koff) {  // one half-tile
        const USHORT* src = (mat ? bS0 : aS0) + (size_t)(h * 128) * K + koff;
        USHORT* dst = smem + mat * 32768 + d * 16384 + h * 8192;
        GLDS(src, dst + dof0);
        GLDS(src + (size_t)64 * K, dst + dof1);
    };

    f32x4 acc[8][4];
#pragma unroll
    for (int i = 0; i < 8; ++i)
#pragma unroll
        for (int j = 0; j < 4; ++j) acc[i][j] = (f32x4){0.f, 0.f, 0.f, 0.f};

    const int nk = K >> 6;

    stageH(0, 0, 0, 0);  stageH(0, 0, 1, 0);
    stageH(1, 0, 0, 0);  stageH(1, 0, 1, 0);
    stageH(1, 1, 0, 64); stageH(1, 1, 1, 64);

    for (int kt = 0; kt < nk; ++kt) {
        const int d = kt & 1;
        const USHORT* Ah = smem + d * 16384 + wr * 8192;
        const USHORT* Bh = smem + 32768 + d * 16384 + (wc >> 1) * 8192;
        const int brow = (wc & 1) * 64;
        short8v bfr[4][2];

#pragma unroll
        for (int g = 0; g < 4; ++g) {
            if (g == 0) {
                if (kt + 1 < nk) { WAITVM(4); } else { WAITVM(0); }
            }
            __builtin_amdgcn_s_barrier();

            if (g == 0) {
#pragma unroll
                for (int ni = 0; ni < 4; ++ni) {
                    bfr[ni][0] = ld_frag(Bh, brow + ni * 16 + lr, lg);
                    bfr[ni][1] = ld_frag(Bh, brow + ni * 16 + lr, 4 + lg);
                }
            }
            short8v a0k0 = ld_frag(Ah, (g * 2) * 16 + lr, lg);
            short8v a0k1 = ld_frag(Ah, (g * 2) * 16 + lr, 4 + lg);
            short8v a1k0 = ld_frag(Ah, (g * 2 + 1) * 16 + lr, lg);
            short8v a1k1 = ld_frag(Ah, (g * 2 + 1) * 16 + lr, 4 + lg);

            if (g == 0 && kt + 1 < nk) stageH(0, (kt + 1) & 1, 0, (kt + 1) * 64);
            if (g == 1 && kt + 1 < nk) stageH(0, (kt + 1) & 1, 1, (kt + 1) * 64);
            if (g == 2 && kt + 2 < nk) stageH(1, kt & 1, 0, (kt + 2) * 64);
            if (g == 3 && kt + 2 < nk) stageH(1, kt & 1, 1, (kt + 2) * 64);

            __builtin_amdgcn_s_setprio(1);
#pragma unroll
            for (int ni = 0; ni < 4; ++ni) {
                acc[g * 2][ni] = __builtin_amdgcn_mfma_f32_16x16x32_bf16(
                    a0k0, bfr[ni][0], acc[g * 2][ni], 0, 0, 0);
                acc[g * 2][ni] = __builtin_amdgcn_mfma_f32_16x16x32_bf16(
                    a0k1, bfr[ni][1], acc[g * 2][ni], 0, 0, 0);
                acc[g * 2 + 1][ni] = __builtin_amdgcn_mfma_f32_16x16x32_bf16(
                    a1k0, bfr[ni][0], acc[g * 2 + 1][ni], 0, 0, 0);
                acc[g * 2 + 1][ni] = __builtin_amdgcn_mfma_f32_16x16x32_bf16(
                    a1k1, bfr[ni][1], acc[g * 2 + 1][ni], 0, 0, 0);
            }
            __builtin_amdgcn_s_setprio(0);
        }
    }

    // epilogue: C/D layout col = lane&15, row = (lane>>4)*4 + reg
    if (qkv) {
#pragma unroll
        for (int mi = 0; mi < 8; ++mi) {
            const int row = m0 + wr * 128 + mi * 16 + (l >> 4) * 4;
#pragma unroll
            for (int ni = 0; ni < 4; ++ni) {
                const int col = n0 + wc * 64 + ni * 16 + lr;
                if (col < 2048) {
                    USHORT* dst = (col < 1024) ? Cb : Ck;
                    const float scl = (col < 1024) ? QSCL : 1.f;  // log2-e domain
                    const int c = col & 1023;
#pragma unroll
                    for (int j = 0; j < 4; ++j)
                        dst[(size_t)(row + j) * D_MODEL + c] =
                            f2bf(acc[mi][ni][j] * scl);
                } else {
                    const int c = col - 2048;
                    const int bb = row >> 10, jr = row & 1023;
                    const int hh = c >> 6, dd = c & 63;
                    uint2 pk = make_uint2(
                        pk2bf(acc[mi][ni][0], acc[mi][ni][1]),
                        pk2bf(acc[mi][ni][2], acc[mi][ni][3]));
                    *reinterpret_cast<uint2*>(
                        &VtOut[((size_t)(bb * 16 + hh) * 64 + dd) * 1024 + jr]) = pk;
                }
            }
        }
    } else {
#pragma unroll
        for (int mi = 0; mi < 8; ++mi) {
            const int row = m0 + wr * 128 + mi * 16 + (l >> 4) * 4;
#pragma unroll
            for (int ni = 0; ni < 4; ++ni) {
                const int col = n0 + wc * 64 + ni * 16 + lr;
                const float bv = bias ? bias[col] : 0.f;
#pragma unroll
                for (int j = 0; j < 4; ++j) {
                    float v = acc[mi][ni][j] + bv;
                    if (relu) v = fmaxf(v, 0.f);
                    const size_t idx = (size_t)(row + j) * N + col;
                    if (Cf) Cf[idx] = v;
                    if (Cb) Cb[idx] = f2bf(v);
                }
            }
        }
    }
}

// ---------------------------------------------------------------------------
// Split-K=2 bf16 GEMM (Wo shapes, K=1024): 128x128 tile, BK=64, 2-buffer
// counted-vmcnt, 8 waves. (unchanged from R15)
// ---------------------------------------------------------------------------
__global__ __launch_bounds__(512) void gemm_k128c_kernel(
    const USHORT* __restrict__ A, const USHORT* __restrict__ Bt,
    USHORT* __restrict__ Pa, USHORT* __restrict__ Pb,
    int M, int N, int K)
{
    __shared__ USHORT As[2][128 * 64];
    __shared__ USHORT Bs[2][128 * 64];

    const int tid = threadIdx.x;
    const int l   = tid & 63;
    const int w   = tid >> 6;
    const int wr  = w >> 2, wc = w & 3;
    const int lr  = l & 15, lg = l >> 4;

    const int gx  = gridDim.x;
    const int nwg = gx * gridDim.y;
    const int lin = blockIdx.y * gx + blockIdx.x;
    const int swz = (lin & 7) * (nwg >> 3) + (lin >> 3);
    const int my  = swz / gx;
    const int mt  = M >> 7;
    const int part = my / mt;
    const int m0  = (my % mt) << 7;
    const int n0  = (swz % gx) * 128;
    const int koff = part * (K >> 1);
    USHORT* dst = part ? Pb : Pa;

    const USHORT* aS[2]; const USHORT* bS[2]; int dOf[2];
#pragma unroll
    for (int p = 0; p < 2; ++p) {
        const int q = p * 512 + tid;
        const int row = q >> 3, cu = q & 7;
        const int cs = ((cu ^ (row & 7)) << 3);
        aS[p] = A  + (size_t)(m0 + row) * K + cs;
        bS[p] = Bt + (size_t)(n0 + row) * K + cs;
        dOf[p] = (p * 512 + w * 64) * 8;
    }

    auto stage = [&](int buf, int k0) {
#pragma unroll
        for (int p = 0; p < 2; ++p) {
            GLDS(aS[p] + k0, &As[buf][dOf[p]]);
            GLDS(bS[p] + k0, &Bs[buf][dOf[p]]);
        }
    };

    f32x4 acc[4][2];
#pragma unroll
    for (int i = 0; i < 4; ++i)
#pragma unroll
        for (int j = 0; j < 2; ++j) acc[i][j] = (f32x4){0.f, 0.f, 0.f, 0.f};

    const int nk = K >> 7;
    stage(0, koff);

    for (int t = 0; t < nk; ++t) {
        const int cur = t & 1;
        if (t + 1 < nk) {
            stage(cur ^ 1, koff + ((t + 1) << 6));
            WAITVM(4);
        } else {
            WAITVM(0);
        }
        __builtin_amdgcn_s_barrier();

#pragma unroll
        for (int ks = 0; ks < 2; ++ks) {
            short8v bfr[2];
#pragma unroll
            for (int ni = 0; ni < 2; ++ni)
                bfr[ni] = ld_frag(Bs[cur], wc * 32 + ni * 16 + lr, ks * 4 + lg);
            __builtin_amdgcn_s_setprio(1);
#pragma unroll
            for (int mi = 0; mi < 4; ++mi) {
                short8v af = ld_frag(As[cur], wr * 64 + mi * 16 + lr, ks * 4 + lg);
#pragma unroll
                for (int ni = 0; ni < 2; ++ni)
                    acc[mi][ni] = __builtin_amdgcn_mfma_f32_16x16x32_bf16(
                        af, bfr[ni], acc[mi][ni], 0, 0, 0);
            }
            __builtin_amdgcn_s_setprio(0);
        }
        __builtin_amdgcn_s_barrier();
    }

#pragma unroll
    for (int mi = 0; mi < 4; ++mi) {
        const int row = m0 + wr * 64 + mi * 16 + (l >> 4) * 4;
#pragma unroll
        for (int ni = 0; ni < 2; ++ni) {
            const int col = n0 + wc * 32 + ni * 16 + lr;
#pragma unroll
            for (int j = 0; j < 4; ++j)
                dst[(size_t)(row + j) * N + col] = f2bf(acc[mi][ni][j]);
        }
    }
}

// ---------------------------------------------------------------------------
// Split-K=4 bf16 GEMM (FFN2, K=4096): same structure; grid = 1024 blocks
// -> 4 blocks/CU of TLP; nk = 16 iters. Partials 0..3 -> Pa..Pd.
// ---------------------------------------------------------------------------
__global__ __launch_bounds__(512) void gemm_k128c4_kernel(
    const USHORT* __restrict__ A, const USHORT* __restrict__ Bt,
    USHORT* __restrict__ Pa, USHORT* __restrict__ Pb,
    USHORT* __restrict__ Pc, USHORT* __restrict__ Pd,
    int M, int N, int K)
{
    __shared__ USHORT As[2][128 * 64];
    __shared__ USHORT Bs[2][128 * 64];

    const int tid = threadIdx.x;
    const int l   = tid & 63;
    const int w   = tid >> 6;
    const int wr  = w >> 2, wc = w & 3;
    const int lr  = l & 15, lg = l >> 4;

    const int gx  = gridDim.x;
    const int nwg = gx * gridDim.y;
    const int lin = blockIdx.y * gx + blockIdx.x;
    const int swz = (lin & 7) * (nwg >> 3) + (lin >> 3);
    const int my  = swz / gx;
    const int mt  = M >> 7;
    const int part = my / mt;              // 0..3
    const int m0  = (my % mt) << 7;
    const int n0  = (swz % gx) * 128;
    const int koff = part * (K >> 2);
    USHORT* dst = (part == 0) ? Pa : (part == 1) ? Pb : (part == 2) ? Pc : Pd;

    const USHORT* aS[2]; const USHORT* bS[2]; int dOf[2];
#pragma unroll
    for (int p = 0; p < 2; ++p) {
        const int q = p * 512 + tid;
        const int row = q >> 3, cu = q & 7;
        const int cs = ((cu ^ (row & 7)) << 3);
        aS[p] = A  + (size_t)(m0 + row) * K + cs;
        bS[p] = Bt + (size_t)(n0 + row) * K + cs;
        dOf[p] = (p * 512 + w * 64) * 8;
    }

    auto stage = [&](int buf, int k0) {
#pragma unroll
        for (int p = 0; p < 2; ++p) {
            GLDS(aS[p] + k0, &As[buf][dOf[p]]);
            GLDS(bS[p] + k0, &Bs[buf][dOf[p]]);
        }
    };

    f32x4 acc[4][2];
#pragma unroll
    for (int i = 0; i < 4; ++i)
#pragma unroll
        for (int j = 0; j < 2; ++j) acc[i][j] = (f32x4){0.f, 0.f, 0.f, 0.f};

    const int nk = K >> 8;                 // (K/4)/64
    stage(0, koff);

    for (int t = 0; t < nk; ++t) {
        const int cur = t & 1;
        if (t + 1 < nk) {
            stage(cur ^ 1, koff + ((t + 1) << 6));
            WAITVM(4);
        } else {
            WAITVM(0);
        }
        __builtin_amdgcn_s_barrier();

#pragma unroll
        for (int ks = 0; ks < 2; ++ks) {
            short8v bfr[2];
#pragma unroll
            for (int ni = 0; ni < 2; ++ni)
                bfr[ni] = ld_frag(Bs[cur], wc * 32 + ni * 16 + lr, ks * 4 + lg);
            __builtin_amdgcn_s_setprio(1);
#pragma unroll
            for (int mi = 0; mi < 4; ++mi) {
                short8v af = ld_frag(As[cur], wr * 64 + mi * 16 + lr, ks * 4 + lg);
#pragma unroll
                for (int ni = 0; ni < 2; ++ni)
                    acc[mi][ni] = __builtin_amdgcn_mfma_f32_16x16x32_bf16(
                        af, bfr[ni], acc[mi][ni], 0, 0, 0);
            }
            __builtin_amdgcn_s_setprio(0);
        }
        __builtin_amdgcn_s_barrier();
    }

#pragma unroll
    for (int mi = 0; mi < 4; ++mi) {
        const int row = m0 + wr * 64 + mi * 16 + (l >> 4) * 4;
#pragma unroll
        for (int ni = 0; ni < 2; ++ni) {
            const int col = n0 + wc * 32 + ni * 16 + lr;
#pragma unroll
            for (int j = 0; j < 4; ++j)
                dst[(size_t)(row + j) * N + col] = f2bf(acc[mi][ni][j]);
        }
    }
}

// ---------------------------------------------------------------------------
// Weight convert+transpose kernels (unchanged).
// ---------------------------------------------------------------------------
struct TcvtB4 {
    const float* s0; const float* s1; const float* s2; const float* s3;
    USHORT* d0; USHORT* d1; USHORT* d2; USHORT* d3;
};

__device__ __forceinline__ void tcvt_body(
    const float* __restrict__ W, USHORT* __restrict__ Wt, int K, int N)
{
    __shared__ USHORT L[64][65];
    const int tid = threadIdx.x;
    const int tx = tid & 15, ty = tid >> 4;
    const int n0 = blockIdx.x * 64, k0 = blockIdx.y * 64;
#pragma unroll
    for (int r = 0; r < 4; ++r) {
        int kr = ty + 16 * r;
        float4 v = *reinterpret_cast<const float4*>(
            &W[(size_t)(k0 + kr) * N + n0 + tx * 4]);
        L[tx * 4 + 0][kr] = f2bf(v.x);
        L[tx * 4 + 1][kr] = f2bf(v.y);
        L[tx * 4 + 2][kr] = f2bf(v.z);
        L[tx * 4 + 3][kr] = f2bf(v.w);
    }
    __syncthreads();
#pragma unroll
    for (int r = 0; r < 4; ++r) {
        int nr = ty + 16 * r;
        ushort4 o = make_ushort4(L[nr][tx * 4 + 0], L[nr][tx * 4 + 1],
                                 L[nr][tx * 4 + 2], L[nr][tx * 4 + 3]);
        *reinterpret_cast<ushort4*>(&Wt[(size_t)(n0 + nr) * K + k0 + tx * 4]) = o;
    }
}

__global__ __launch_bounds__(256) void tcvt_kernel(
    const float* __restrict__ W, USHORT* __restrict__ Wt, int K, int N)
{
    tcvt_body(W, Wt, K, N);
}

__global__ __launch_bounds__(256) void tcvt4_kernel(TcvtB4 p, int K, int N)
{
    const int z = blockIdx.z;
    const float* W = (z == 0) ? p.s0 : (z == 1) ? p.s1 : (z == 2) ? p.s2 : p.s3;
    USHORT*    Wt = (z == 0) ? p.d0 : (z == 1) ? p.d1 : (z == 2) ? p.d2 : p.d3;
    tcvt_body(W, Wt, K, N);
}

__global__ __launch_bounds__(256) void f2b_kernel(
    const float* __restrict__ in, USHORT* __restrict__ out, int n4)
{
    int i = blockIdx.x * 256 + threadIdx.x;
    if (i < n4) {
        float4 v = reinterpret_cast<const float4*>(in)[i];
        reinterpret_cast<ushort4*>(out)[i] =
            make_ushort4(f2bf(v.x), f2bf(v.y), f2bf(v.z), f2bf(v.w));
    }
}

// ---------------------------------------------------------------------------
// MFMA flash attention (R21 structure; fexp2 = raw v_exp_f32).
// ---------------------------------------------------------------------------
__global__ __launch_bounds__(256) void attn_mfma_kernel(
    const USHORT* __restrict__ Q, const USHORT* __restrict__ K,
    const USHORT* __restrict__ Vt, USHORT* __restrict__ O, int causal)
{
    __shared__ USHORT smem[24576];                 // 48 KB

    const int tid = threadIdx.x;
    const int l  = tid & 63;
    const int w  = tid >> 6;
    const int lr = l & 15;
    const int lg = l >> 4;

    const int lin = blockIdx.y * 8 + blockIdx.x;    // nwg = 512
    const int swz = (lin & 7) * 64 + (lin >> 3);
    const int qtr = swz & 7;
    const int qt  = causal ? (qtr ^ (((swz >> 5) & 1) ? 7 : 0)) : qtr;
    const int bh = swz >> 3;
    const int h = bh & 15, b = bh >> 4;
    const int q0 = qt * 128;

    const USHORT* gq  = Q  + (size_t)(b * SEQ + q0) * D_MODEL + h * DH;
    const USHORT* gk0 = K  + (size_t)b * SEQ * D_MODEL + h * DH;
    const USHORT* gv0 = Vt + (size_t)bh * DH * SEQ;

    auto stageK = [&](int buf, int kt) {           // 64x64, row&7 swizzle
        USHORT* dst = smem + buf * 4096;
        const size_t base = (size_t)kt * 64 * 1024;
#pragma unroll
        for (int p = 0; p < 2; ++p) {
            const int q = p * 256 + tid;
            const int row = q >> 3, cu = q & 7;
            GLDS(gk0 + base + (size_t)row * 1024 + ((cu ^ (row & 7)) << 3),
                 dst + (p * 256 + w * 64) * 8);
        }
    };
    auto stageV = [&](int buf, int kt) {           // 64 d x 64 j, row&7 swizzle
        USHORT* dst = smem + 8192 + buf * 4096;
        const int j0 = kt * 64;
#pragma unroll
        for (int p = 0; p < 2; ++p) {
            const int q = p * 256 + tid;
            const int row = q >> 3, cu = q & 7;
            GLDS(gv0 + (size_t)row * 1024 + j0 + ((cu ^ (row & 7)) << 3),
                 dst + (p * 256 + w * 64) * 8);
        }
    };

    // stage Q (128x64, row&7 swizzle) + first K/V tile
#pragma unroll
    for (int p = 0; p < 4; ++p) {
        const int q = p * 256 + tid;
        const int row = q >> 3, cu = q & 7;
        GLDS(gq + (size_t)row * 1024 + ((cu ^ (row & 7)) << 3),
             smem + 16384 + (p * 256 + w * 64) * 8);
    }
    stageK(0, 0);
    stageV(0, 0);

    f32x4 oacc[2][4];
    float m_[2], l_[2];            // per-lane state for q = w*32 + s*16 + lr
#pragma unroll
    for (int s = 0; s < 2; ++s) {
        m_[s] = -1e30f; l_[s] = 0.f;
#pragma unroll
        for (int d = 0; d < 4; ++d) oacc[s][d] = (f32x4){0.f, 0.f, 0.f, 0.f};
    }

    // P write offsets: row = s*16+lr, j = jb*16 + lg*4 .. +3 (one b64 each)
    int paddr[2][4];
#pragma unroll
    for (int s = 0; s < 2; ++s) {
        const int row = s * 16 + lr;
#pragma unroll
        for (int jb = 0; jb < 4; ++jb) {
            const int cu = jb * 2 + (lg >> 1);
            paddr[s][jb] = row * 64 + ((cu ^ (row & 7)) << 3) + (lg & 1) * 4;
        }
    }

    __syncthreads();                               // Q + tile 0 staged
    short8v qa[2][2];
#pragma unroll
    for (int s = 0; s < 2; ++s) {
        qa[s][0] = ld_frag(smem + 16384, w * 32 + s * 16 + lr, lg);
        qa[s][1] = ld_frag(smem + 16384, w * 32 + s * 16 + lr, 4 + lg);
    }
    __syncthreads();                               // Q consumed -> P may reuse
    USHORT* PsW = smem + 16384 + w * 2048;         // per-wave P [32 q][64 j]

    const int ntile = causal ? (qt * 2 + 2) : (SEQ / 64);
    for (int kt = 0; kt < ntile; ++kt) {
        const int cur = kt & 1;
        if (kt + 1 < ntile) {                      // prefetch next K/V tile
            stageK(cur ^ 1, kt + 1);
            stageV(cur ^ 1, kt + 1);
        }
        const int j0 = kt * 64;
        const USHORT* KsC = smem + cur * 4096;
        const USHORT* VsC = smem + 8192 + cur * 4096;

        // S^T = mfma(K, Q); K frags shared across both q-subtiles
        f32x4 sa[2][4];
        __builtin_amdgcn_s_setprio(1);
#pragma unroll
        for (int jb = 0; jb < 4; ++jb) {
            short8v kf0 = ld_frag(KsC, jb * 16 + lr, lg);
            short8v kf1 = ld_frag(KsC, jb * 16 + lr, 4 + lg);
#pragma unroll
            for (int s = 0; s < 2; ++s) {
                sa[s][jb] = (f32x4){0.f, 0.f, 0.f, 0.f};
                sa[s][jb] = __builtin_amdgcn_mfma_f32_16x16x32_bf16(
                    kf0, qa[s][0], sa[s][jb], 0, 0, 0);
                sa[s][jb] = __builtin_amdgcn_mfma_f32_16x16x32_bf16(
                    kf1, qa[s][1], sa[s][jb], 0, 0, 0);
            }
        }
        __builtin_amdgcn_s_setprio(0);

        // causal mask: only the last two tiles can cross the diagonal
        if (causal && kt >= ntile - 2) {
#pragma unroll
            for (int s = 0; s < 2; ++s) {
                const int qrow = q0 + w * 32 + s * 16 + lr;
#pragma unroll
                for (int jb = 0; jb < 4; ++jb)
#pragma unroll
                    for (int r = 0; r < 4; ++r)
                        if ((j0 + jb * 16 + lg * 4 + r) > qrow)
                            sa[s][jb][r] = -1e30f;
            }
        }

        // per-lane tile max over 16 values per qsub + 2 shfl each
        float tm[2];
#pragma unroll
        for (int s = 0; s < 2; ++s) {
            float t1 = max3f(sa[s][0][0], sa[s][0][1], sa[s][0][2]);
            float t2 = max3f(sa[s][0][3], sa[s][1][0], sa[s][1][1]);
            float t3 = max3f(sa[s][1][2], sa[s][1][3], sa[s][2][0]);
            float t4 = max3f(sa[s][2][1], sa[s][2][2], sa[s][2][3]);
            float t5 = max3f(sa[s][3][0], sa[s][3][1], sa[s][3][2]);
            float tv = fmaxf(max3f(max3f(t1, t2, t3), t4, t5), sa[s][3][3]);
            tv = fmaxf(tv, __shfl_xor(tv, 16));
            tv = fmaxf(tv, __shfl_xor(tv, 32));
            tm[s] = tv;
        }

        // defer-max rescale (wave-gated; broadcast sc from owner lanes)
        const bool anyf = (tm[0] > m_[0] + 8.f) | (tm[1] > m_[1] + 8.f);
        if (__ballot(anyf)) {
            float sc[2];
#pragma unroll
            for (int s = 0; s < 2; ++s) {
                const float mn = (tm[s] > m_[s] + 8.f) ? tm[s] : m_[s];
                sc[s] = fexp2(m_[s] - mn);
                l_[s] *= sc[s];
                m_[s] = mn;
            }
#pragma unroll
            for (int s = 0; s < 2; ++s)
#pragma unroll
                for (int r = 0; r < 4; ++r) {
                    const float scr = __shfl(sc[s], (l & 48) | (lg * 4 + r));
#pragma unroll
                    for (int d = 0; d < 4; ++d) oacc[s][d][r] *= scr;
                }
        }

        // exp (log2 domain, raw v_exp) + lane-partial sum + pack + b64 writes
#pragma unroll
        for (int s = 0; s < 2; ++s)
#pragma unroll
            for (int jb = 0; jb < 4; ++jb) {
                const float p0 = fexp2(sa[s][jb][0] - m_[s]);
                const float p1 = fexp2(sa[s][jb][1] - m_[s]);
                const float p2 = fexp2(sa[s][jb][2] - m_[s]);
                const float p3 = fexp2(sa[s][jb][3] - m_[s]);
                l_[s] += (p0 + p1) + (p2 + p3);
                *reinterpret_cast<uint2*>(&PsW[paddr[s][jb]]) =
                    make_uint2(pk2bf(p0, p1), pk2bf(p2, p3));
            }

        // PV: V frags shared across both q-subtiles
        __builtin_amdgcn_s_setprio(1);
#pragma unroll
        for (int ks = 0; ks < 2; ++ks) {
            short8v pa[2];
#pragma unroll
            for (int s = 0; s < 2; ++s)
                pa[s] = ld_frag(PsW, s * 16 + lr, ks * 4 + lg);
#pragma unroll
            for (int d = 0; d < 4; ++d) {
                short8v vf = ld_frag(VsC, d * 16 + lr, ks * 4 + lg);
#pragma unroll
                for (int s = 0; s < 2; ++s)
                    oacc[s][d] = __builtin_amdgcn_mfma_f32_16x16x32_bf16(
                        pa[s], vf, oacc[s][d], 0, 0, 0);
            }
        }
        __builtin_amdgcn_s_setprio(0);
        __syncthreads();   // drains prefetch + guards K/V/P buffer reuse
    }

    // epilogue: cross-lg l sum per qsub, inv via owner-lane shfl
    USHORT* go = O + (size_t)(b * SEQ + q0 + w * 32) * D_MODEL + h * DH;
#pragma unroll
    for (int s = 0; s < 2; ++s) {
        float lv = l_[s];
        lv += __shfl_xor(lv, 16);
        lv += __shfl_xor(lv, 32);
        const float inv_own = 1.f / lv;
#pragma unroll
        for (int r = 0; r < 4; ++r) {
            const float inv = __shfl(inv_own, (l & 48) | (lg * 4 + r));
            const int qrow = s * 16 + lg * 4 + r;
#pragma unroll
            for (int d = 0; d < 4; ++d)
                go[(size_t)qrow * D_MODEL + d * 16 + lr] =
                    f2bf_fast(oacc[s][d][r] * inv);
        }
    }
}

// ---------------------------------------------------------------------------
// out = res + LayerNorm(x)*g + b, x = xb (+xb2) (+xb3) (+xb4) (+biasx).
// res: fp32 (resf) / bf16 (resb) / x itself (both null).
// ---------------------------------------------------------------------------
__global__ __launch_bounds__(256) void ln_res_kernel(
    const USHORT* __restrict__ xb, const USHORT* __restrict__ xb2,
    const USHORT* __restrict__ xb3, const USHORT* __restrict__ xb4,
    const float* __restrict__ biasx,
    const float* __restrict__ resf, const USHORT* __restrict__ resb,
    const float* __restrict__ g, const float* __restrict__ bta,
    float* __restrict__ outf, USHORT* __restrict__ outb)
{
    __shared__ float red[256];
    __shared__ float s_mu, s_rstd;

    const int row = blockIdx.x;
    const int tid = threadIdx.x;
    ushort4 xv = reinterpret_cast<const ushort4*>(xb + (size_t)row * D_MODEL)[tid];
    float vx = bf2f(xv.x), vy = bf2f(xv.y), vz = bf2f(xv.z), vw = bf2f(xv.w);
    if (xb2) {
        ushort4 x2 = reinterpret_cast<const ushort4*>(
            xb2 + (size_t)row * D_MODEL)[tid];
        vx += bf2f(x2.x); vy += bf2f(x2.y); vz += bf2f(x2.z); vw += bf2f(x2.w);
    }
    if (xb3) {
        ushort4 x3 = reinterpret_cast<const ushort4*>(
            xb3 + (size_t)row * D_MODEL)[tid];
        vx += bf2f(x3.x); vy += bf2f(x3.y); vz += bf2f(x3.z); vw += bf2f(x3.w);
    }
    if (xb4) {
        ushort4 x4 = reinterpret_cast<const ushort4*>(
            xb4 + (size_t)row * D_MODEL)[tid];
        vx += bf2f(x4.x); vy += bf2f(x4.y); vz += bf2f(x4.z); vw += bf2f(x4.w);
    }
    if (biasx) {
        float4 bx = reinterpret_cast<const float4*>(biasx)[tid];
        vx += bx.x; vy += bx.y; vz += bx.z; vw += bx.w;
    }

    red[tid] = vx + vy + vz + vw;
    __syncthreads();
    for (int s = 128; s > 0; s >>= 1) {
        if (tid < s) red[tid] += red[tid + s];
        __syncthreads();
    }
    if (tid == 0) s_mu = red[0] * (1.f / D_MODEL);
    __syncthreads();
    const float mu = s_mu;

    float dx = vx - mu, dy = vy - mu, dz = vz - mu, dw = vw - mu;
    red[tid] = dx * dx + dy * dy + dz * dz + dw * dw;
    __syncthreads();
    for (int s = 128; s > 0; s >>= 1) {
        if (tid < s) red[tid] += red[tid + s];
        __syncthreads();
    }
    if (tid == 0) s_rstd = rsqrtf(red[0] * (1.f / D_MODEL) + EPS);
    __syncthreads();
    const float rstd = s_rstd;

    float4 rv;
    if (resf) {
        rv = reinterpret_cast<const float4*>(resf + (size_t)row * D_MODEL)[tid];
    } else if (resb) {
        ushort4 rb = reinterpret_cast<const ushort4*>(
            resb + (size_t)row * D_MODEL)[tid];
        rv = make_float4(bf2f(rb.x), bf2f(rb.y), bf2f(rb.z), bf2f(rb.w));
    } else {
        rv = make_float4(vx, vy, vz, vw);          // res = x (norm_attn2 wiring)
    }
    float4 gv = reinterpret_cast<const float4*>(g)[tid];
    float4 bv = reinterpret_cast<const float4*>(bta)[tid];

    float4 o;
    o.x = rv.x + dx * rstd * gv.x + bv.x;
    o.y = rv.y + dy * rstd * gv.y + bv.y;
    o.z = rv.z + dz * rstd * gv.z + bv.z;
    o.w = rv.w + dw * rstd * gv.w + bv.w;
    reinterpret_cast<float4*>(outf + (size_t)row * D_MODEL)[tid] = o;
    if (outb)
        reinterpret_cast<ushort4*>(outb + (size_t)row * D_MODEL)[tid] =
            make_ushort4(f2bf(o.x), f2bf(o.y), f2bf(o.z), f2bf(o.w));
}

// ---------------------------------------------------------------------------
extern "C" void kernel_launch(void* const* d_in, const int* in_sizes, int n_in,
                              void* d_out, int out_size, void* d_ws, size_t ws_size,
                              hipStream_t stream)
{
    const float* X    = (const float*)d_in[0];
    const float* Wq1  = (const float*)d_in[1];
    const float* Wk1  = (const float*)d_in[2];
    const float* Wv1  = (const float*)d_in[3];
    const float* Wo1  = (const float*)d_in[4];
    const float* Wq2  = (const float*)d_in[5];
    const float* Wk2  = (const float*)d_in[6];
    const float* Wv2  = (const float*)d_in[7];
    const float* Wo2  = (const float*)d_in[8];
    const float* ln_g = (const float*)d_in[9];
    const float* ln_b = (const float*)d_in[10];
    const float* W1   = (const float*)d_in[11];
    const float* b1   = (const float*)d_in[12];
    const float* W2   = (const float*)d_in[13];
    const float* b2   = (const float*)d_in[14];

    // ws layout (ushort units). CRITICAL: FFN hidden hb = qb spans
    // [16Mi, 32Mi) -- FFN2 partials MUST stay outside that range.
    const size_t MI = 1024 * 1024;
    USHORT* ws16 = (USHORT*)d_ws;
    USHORT* Wqkv1t = ws16;                 // [0,3Mi); scr0 reuses [0,4Mi)
    USHORT* scr0   = ws16;                 //   dead after MHA2 ln_res
    USHORT* Wo1t   = ws16 + 3 * MI;
    USHORT* Wqkv2t = ws16 + 4 * MI;
    USHORT* Wo2t   = ws16 + 7 * MI;
    USHORT* W2t    = ws16 + 8 * MI;
    USHORT* Xb     = ws16 + 12 * MI;
    USHORT* W1t    = Xb;                   // [12,16Mi): dead after FFN1
    USHORT* qb     = ws16 + 16 * MI;
    USHORT* kb     = ws16 + 20 * MI;
    USHORT* Vtb    = ws16 + 24 * MI;
    USHORT* t0b    = ws16 + 28 * MI;       // INSIDE hb -- never an FFN2 partial
    USHORT* hb     = qb;                   // [16,32Mi)
    USHORT* t2b    = ws16 + 32 * MI;
    USHORT* t1b    = ws16 + 36 * MI;
    float*  t2     = (float*)(ws16 + 40 * MI);

    auto gemmBig = [&](const USHORT* A, const USHORT* Bt, float* Cf, USHORT* Cb,
                       int M, int N, int K, const float* bias, int relu) {
        gemm_k256p8_kernel<<<dim3(N / 256, M / 256), 512, 0, stream>>>(
            A, Bt, Cf, Cb, nullptr, nullptr, M, N, K, bias, relu, 0);
    };
    auto gemm_qkv = [&](const USHORT* A, const USHORT* Bt) {
        gemm_k256p8_kernel<<<dim3(3072 / 256, TOK / 256), 512, 0, stream>>>(
            A, Bt, nullptr, qb, kb, Vtb, TOK, 3072, D_MODEL, nullptr, 0, 1);
    };
    auto gemm128c = [&](const USHORT* A, const USHORT* Bt, USHORT* Pa, USHORT* Pb,
                        int M, int N, int K) {
        gemm_k128c_kernel<<<dim3(N / 128, (M / 128) * 2), 512, 0, stream>>>(
            A, Bt, Pa, Pb, M, N, K);
    };
    auto gemm128c4 = [&](const USHORT* A, const USHORT* Bt,
                         USHORT* Pa, USHORT* Pb, USHORT* Pc, USHORT* Pd,
                         int M, int N, int K) {
        gemm_k128c4_kernel<<<dim3(N / 128, (M / 128) * 4), 512, 0, stream>>>(
            A, Bt, Pa, Pb, Pc, Pd, M, N, K);
    };

    dim3 agrid(SEQ / 128, BATCH * N_HEADS);

    // ---- prologue: all square weights + W2 + X -> bf16 ----
    {
        TcvtB4 p1{Wq1, Wk1, Wv1, Wo1,
                  Wqkv1t, Wqkv1t + 1 * MI, Wqkv1t + 2 * MI, Wo1t};
        tcvt4_kernel<<<dim3(16, 16, 4), 256, 0, stream>>>(p1, D_MODEL, D_MODEL);
        TcvtB4 p2{Wq2, Wk2, Wv2, Wo2,
                  Wqkv2t, Wqkv2t + 1 * MI, Wqkv2t + 2 * MI, Wo2t};
        tcvt4_kernel<<<dim3(16, 16, 4), 256, 0, stream>>>(p2, D_MODEL, D_MODEL);
    }
    tcvt_kernel<<<dim3(D_MODEL / 64, D_FF / 64), 256, 0, stream>>>(
        W2, W2t, D_FF, D_MODEL);
    f2b_kernel<<<dim3(4096), 256, 0, stream>>>(X, Xb, TOK * D_MODEL / 4);

    // ---- MHA 1 (causal) ----
    gemm_qkv(Xb, Wqkv1t);
    attn_mfma_kernel<<<agrid, 256, 0, stream>>>(qb, kb, Vtb, t0b, 1);
    gemm128c(t0b, Wo1t, t2b, t1b, TOK, D_MODEL, D_MODEL);     // masked = t2b+t1b
    ln_res_kernel<<<dim3(TOK), 256, 0, stream>>>(t2b, t1b, nullptr, nullptr,
                                                 nullptr, X, nullptr,
                                                 ln_g, ln_b, t2, t2b);
    tcvt_kernel<<<dim3(D_FF / 64, D_MODEL / 64), 256, 0, stream>>>(
        W1, W1t, D_MODEL, D_FF);

    // ---- MHA 2 (full) ----
    gemm_qkv(t2b, Wqkv2t);
    attn_mfma_kernel<<<agrid, 256, 0, stream>>>(qb, kb, Vtb, t0b, 0);
    gemm128c(t0b, Wo2t, scr0, t1b, TOK, D_MODEL, D_MODEL);    // attn2 = scr0+t1b
    ln_res_kernel<<<dim3(TOK), 256, 0, stream>>>(scr0, t1b, nullptr, nullptr,
                                                 nullptr, nullptr, nullptr,
                                                 ln_g, ln_b, t2, t2b);   // res = x

    // ---- FFN ----
    gemmBig(t2b, W1t, nullptr, hb, TOK, D_FF, D_MODEL, b1, 1);
    // FFN2 split-K=4: partials in scr0 [0,4Mi), W1t [12,16Mi), t2b, t1b --
    // all dead here and all OUTSIDE hb [16,32Mi).
    gemm128c4(hb, W2t, scr0, W1t, t2b, t1b, TOK, D_MODEL, D_FF);
    ln_res_kernel<<<dim3(TOK), 256, 0, stream>>>(scr0, W1t, t2b, t1b, b2,
                                                 t2, nullptr,
                                                 ln_g, ln_b, (float*)d_out, nullptr);
}

// Round 25
// 298.572 us; speedup vs baseline: 1.1332x; 1.0275x over previous
//
#include <hip/hip_runtime.h>
#include <hip/hip_bf16.h>

#define D_MODEL 1024
#define N_HEADS 16
#define DH 64
#define D_FF   4096
#define SEQ    1024
#define BATCH  4
#define TOK    (BATCH*SEQ)
#define EPS    1e-5f
#define SCALE  0.125f           // 1/sqrt(64)
#define QSCL   0.18033688f      // SCALE * log2(e): QK^T lands in log2 domain

typedef unsigned short USHORT;
typedef __attribute__((ext_vector_type(8))) short short8v;
typedef __attribute__((ext_vector_type(4))) float f32x4;

__device__ __forceinline__ USHORT f2bf(float f) {
    unsigned int u; __builtin_memcpy(&u, &f, 4);
    u += 0x7fffu + ((u >> 16) & 1u);          // RNE
    return (USHORT)(u >> 16);
}
// 2-op round-half-up pack (P in (0,256] and O: error == RNE magnitude)
__device__ __forceinline__ USHORT f2bf_fast(float f) {
    unsigned int u; __builtin_memcpy(&u, &f, 4);
    return (USHORT)((u + 0x8000u) >> 16);
}
// HW pack: 2 floats -> u32 of 2 bf16 (RNE, v_cvt_pk path); lo -> bits [15:0]
__device__ __forceinline__ unsigned pk2bf(float lo, float hi) {
    __hip_bfloat162 h = __float22bfloat162_rn(make_float2(lo, hi));
    unsigned u; __builtin_memcpy(&u, &h, 4);
    return u;
}
__device__ __forceinline__ float bf2f(USHORT s) {
    unsigned int u = ((unsigned int)s) << 16;
    float f; __builtin_memcpy(&f, &u, 4);
    return f;
}
__device__ __forceinline__ float max3f(float a, float b, float c) {
    return fmaxf(fmaxf(a, b), c);             // fuses to v_max3_f32
}
// fast exp2: straight v_exp_f32 (args <= 0; HW underflow->0 is correct).
__device__ __forceinline__ float fexp2(float x) {
#if __has_builtin(__builtin_amdgcn_exp2f)
    return __builtin_amdgcn_exp2f(x);
#else
    return exp2f(x);
#endif
}

// row-stride-64 swizzled read: unit ^= row&7
__device__ __forceinline__ short8v ld_frag(const USHORT* lds, int row, int c8) {
    return *reinterpret_cast<const short8v*>(
        &lds[row * 64 + (((c8) ^ (row & 7)) << 3)]);
}

#define GLDS(gsrc, ldst) \
    __builtin_amdgcn_global_load_lds( \
        (const __attribute__((address_space(1))) void*)(gsrc), \
        (__attribute__((address_space(3))) void*)(ldst), 16, 0, 0)

#define WAITVM(n) asm volatile("s_waitcnt vmcnt(" #n ")" ::: "memory")

// ---------------------------------------------------------------------------
// bf16 MFMA GEMM, 256x256 tile, 8-PHASE pipeline (unchanged from R22).
// ---------------------------------------------------------------------------
__global__ __launch_bounds__(512) void gemm_k256p8_kernel(
    const USHORT* __restrict__ A, const USHORT* __restrict__ Bt,
    float* __restrict__ Cf, USHORT* __restrict__ Cb, USHORT* __restrict__ Ck,
    USHORT* __restrict__ VtOut,
    int M, int N, int K, const float* __restrict__ bias, int relu, int qkv)
{
    __shared__ USHORT smem[65536];         // 128 KB

    const int tid = threadIdx.x;
    const int l   = tid & 63;
    const int w   = tid >> 6;              // 0..7
    const int wr  = w >> 2, wc = w & 3;    // 2M x 4N wave grid
    const int lr  = l & 15, lg = l >> 4;

    const int gx  = gridDim.x;             // N/256
    const int nwg = gx * gridDim.y;
    const int lin = blockIdx.y * gx + blockIdx.x;
    const int swz = (lin & 7) * (nwg >> 3) + (lin >> 3);
    const int m0  = (swz / gx) * 256, n0 = (swz % gx) * 256;

    const int srow = tid >> 3;
    const int scol = ((tid & 7) ^ (srow & 7)) << 3;
    const USHORT* aS0 = A  + (size_t)(m0 + srow) * K + scol;
    const USHORT* bS0 = Bt + (size_t)(n0 + srow) * K + scol;
    const int dof0 = (w * 64) * 8;
    const int dof1 = (512 + w * 64) * 8;

    auto stageH = [&](int mat, int d, int h, int koff) {  // one half-tile
        const USHORT* src = (mat ? bS0 : aS0) + (size_t)(h * 128) * K + koff;
        USHORT* dst = smem + mat * 32768 + d * 16384 + h * 8192;
        GLDS(src, dst + dof0);
        GLDS(src + (size_t)64 * K, dst + dof1);
    };

    f32x4 acc[8][4];
#pragma unroll
    for (int i = 0; i < 8; ++i)
#pragma unroll
        for (int j = 0; j < 4; ++j) acc[i][j] = (f32x4){0.f, 0.f, 0.f, 0.f};

    const int nk = K >> 6;

    stageH(0, 0, 0, 0);  stageH(0, 0, 1, 0);
    stageH(1, 0, 0, 0);  stageH(1, 0, 1, 0);
    stageH(1, 1, 0, 64); stageH(1, 1, 1, 64);

    for (int kt = 0; kt < nk; ++kt) {
        const int d = kt & 1;
        const USHORT* Ah = smem + d * 16384 + wr * 8192;
        const USHORT* Bh = smem + 32768 + d * 16384 + (wc >> 1) * 8192;
        const int brow = (wc & 1) * 64;
        short8v bfr[4][2];

#pragma unroll
        for (int g = 0; g < 4; ++g) {
            if (g == 0) {
                if (kt + 1 < nk) { WAITVM(4); } else { WAITVM(0); }
            }
            __builtin_amdgcn_s_barrier();

            if (g == 0) {
#pragma unroll
                for (int ni = 0; ni < 4; ++ni) {
                    bfr[ni][0] = ld_frag(Bh, brow + ni * 16 + lr, lg);
                    bfr[ni][1] = ld_frag(Bh, brow + ni * 16 + lr, 4 + lg);
                }
            }
            short8v a0k0 = ld_frag(Ah, (g * 2) * 16 + lr, lg);
            short8v a0k1 = ld_frag(Ah, (g * 2) * 16 + lr, 4 + lg);
            short8v a1k0 = ld_frag(Ah, (g * 2 + 1) * 16 + lr, lg);
            short8v a1k1 = ld_frag(Ah, (g * 2 + 1) * 16 + lr, 4 + lg);

            if (g == 0 && kt + 1 < nk) stageH(0, (kt + 1) & 1, 0, (kt + 1) * 64);
            if (g == 1 && kt + 1 < nk) stageH(0, (kt + 1) & 1, 1, (kt + 1) * 64);
            if (g == 2 && kt + 2 < nk) stageH(1, kt & 1, 0, (kt + 2) * 64);
            if (g == 3 && kt + 2 < nk) stageH(1, kt & 1, 1, (kt + 2) * 64);

            __builtin_amdgcn_s_setprio(1);
#pragma unroll
            for (int ni = 0; ni < 4; ++ni) {
                acc[g * 2][ni] = __builtin_amdgcn_mfma_f32_16x16x32_bf16(
                    a0k0, bfr[ni][0], acc[g * 2][ni], 0, 0, 0);
                acc[g * 2][ni] = __builtin_amdgcn_mfma_f32_16x16x32_bf16(
                    a0k1, bfr[ni][1], acc[g * 2][ni], 0, 0, 0);
                acc[g * 2 + 1][ni] = __builtin_amdgcn_mfma_f32_16x16x32_bf16(
                    a1k0, bfr[ni][0], acc[g * 2 + 1][ni], 0, 0, 0);
                acc[g * 2 + 1][ni] = __builtin_amdgcn_mfma_f32_16x16x32_bf16(
                    a1k1, bfr[ni][1], acc[g * 2 + 1][ni], 0, 0, 0);
            }
            __builtin_amdgcn_s_setprio(0);
        }
    }

    // epilogue: C/D layout col = lane&15, row = (lane>>4)*4 + reg
    if (qkv) {
#pragma unroll
        for (int mi = 0; mi < 8; ++mi) {
            const int row = m0 + wr * 128 + mi * 16 + (l >> 4) * 4;
#pragma unroll
            for (int ni = 0; ni < 4; ++ni) {
                const int col = n0 + wc * 64 + ni * 16 + lr;
                if (col < 2048) {
                    USHORT* dst = (col < 1024) ? Cb : Ck;
                    const float scl = (col < 1024) ? QSCL : 1.f;  // log2-e domain
                    const int c = col & 1023;
#pragma unroll
                    for (int j = 0; j < 4; ++j)
                        dst[(size_t)(row + j) * D_MODEL + c] =
                            f2bf(acc[mi][ni][j] * scl);
                } else {
                    const int c = col - 2048;
                    const int bb = row >> 10, jr = row & 1023;
                    const int hh = c >> 6, dd = c & 63;
                    uint2 pk = make_uint2(
                        pk2bf(acc[mi][ni][0], acc[mi][ni][1]),
                        pk2bf(acc[mi][ni][2], acc[mi][ni][3]));
                    *reinterpret_cast<uint2*>(
                        &VtOut[((size_t)(bb * 16 + hh) * 64 + dd) * 1024 + jr]) = pk;
                }
            }
        }
    } else {
#pragma unroll
        for (int mi = 0; mi < 8; ++mi) {
            const int row = m0 + wr * 128 + mi * 16 + (l >> 4) * 4;
#pragma unroll
            for (int ni = 0; ni < 4; ++ni) {
                const int col = n0 + wc * 64 + ni * 16 + lr;
                const float bv = bias ? bias[col] : 0.f;
#pragma unroll
                for (int j = 0; j < 4; ++j) {
                    float v = acc[mi][ni][j] + bv;
                    if (relu) v = fmaxf(v, 0.f);
                    const size_t idx = (size_t)(row + j) * N + col;
                    if (Cf) Cf[idx] = v;
                    if (Cb) Cb[idx] = f2bf(v);
                }
            }
        }
    }
}

// ---------------------------------------------------------------------------
// bf16 MFMA GEMM, 256x256 tile, 8-PHASE pipeline, SPLIT-K=4 (FFN2).
// Identical schedule to gemm_k256p8 (per-wave vmcnt counts unchanged; all
// staging offsets shifted by koff = part*(K/4)). Grid = (N/256) x
// (M/256 * 4) = 256 blocks = 1/CU (the 8-phase design point). Writes bf16
// PARTIALS (no bias): part 0..3 -> Pa..Pd; consumer ln_res sums them.
// Staged L2 traffic for FFN2: 256 blocks x 1 MB = 256 MB (vs 512 MB at the
// 128^2 tile -> was the 44 us L2-BW floor).
// ---------------------------------------------------------------------------
__global__ __launch_bounds__(512) void gemm_k256p8s4_kernel(
    const USHORT* __restrict__ A, const USHORT* __restrict__ Bt,
    USHORT* __restrict__ Pa, USHORT* __restrict__ Pb,
    USHORT* __restrict__ Pc, USHORT* __restrict__ Pd,
    int M, int N, int K)
{
    __shared__ USHORT smem[65536];         // 128 KB

    const int tid = threadIdx.x;
    const int l   = tid & 63;
    const int w   = tid >> 6;
    const int wr  = w >> 2, wc = w & 3;
    const int lr  = l & 15, lg = l >> 4;

    const int gx  = gridDim.x;             // N/256
    const int nwg = gx * gridDim.y;
    const int lin = blockIdx.y * gx + blockIdx.x;
    const int swz = (lin & 7) * (nwg >> 3) + (lin >> 3);
    const int my  = swz / gx;              // 0 .. 4*(M/256)-1
    const int mt  = M >> 8;
    const int part = my / mt;              // 0..3
    const int m0  = (my % mt) << 8;
    const int n0  = (swz % gx) * 256;
    const int koff = part * (K >> 2);
    USHORT* dst = (part == 0) ? Pa : (part == 1) ? Pb : (part == 2) ? Pc : Pd;

    const int srow = tid >> 3;
    const int scol = ((tid & 7) ^ (srow & 7)) << 3;
    const USHORT* aS0 = A  + (size_t)(m0 + srow) * K + scol;
    const USHORT* bS0 = Bt + (size_t)(n0 + srow) * K + scol;
    const int dof0 = (w * 64) * 8;
    const int dof1 = (512 + w * 64) * 8;

    auto stageH = [&](int mat, int d, int h, int ko) {    // one half-tile
        const USHORT* src = (mat ? bS0 : aS0) + (size_t)(h * 128) * K + ko;
        USHORT* dst2 = smem + mat * 32768 + d * 16384 + h * 8192;
        GLDS(src, dst2 + dof0);
        GLDS(src + (size_t)64 * K, dst2 + dof1);
    };

    f32x4 acc[8][4];
#pragma unroll
    for (int i = 0; i < 8; ++i)
#pragma unroll
        for (int j = 0; j < 4; ++j) acc[i][j] = (f32x4){0.f, 0.f, 0.f, 0.f};

    const int nk = K >> 8;                 // (K/4) / 64 tiles

    stageH(0, 0, 0, koff);      stageH(0, 0, 1, koff);
    stageH(1, 0, 0, koff);      stageH(1, 0, 1, koff);
    stageH(1, 1, 0, koff + 64); stageH(1, 1, 1, koff + 64);

    for (int kt = 0; kt < nk; ++kt) {
        const int d = kt & 1;
        const USHORT* Ah = smem + d * 16384 + wr * 8192;
        const USHORT* Bh = smem + 32768 + d * 16384 + (wc >> 1) * 8192;
        const int brow = (wc & 1) * 64;
        short8v bfr[4][2];

#pragma unroll
        for (int g = 0; g < 4; ++g) {
            if (g == 0) {
                if (kt + 1 < nk) { WAITVM(4); } else { WAITVM(0); }
            }
            __builtin_amdgcn_s_barrier();

            if (g == 0) {
#pragma unroll
                for (int ni = 0; ni < 4; ++ni) {
                    bfr[ni][0] = ld_frag(Bh, brow + ni * 16 + lr, lg);
                    bfr[ni][1] = ld_frag(Bh, brow + ni * 16 + lr, 4 + lg);
                }
            }
            short8v a0k0 = ld_frag(Ah, (g * 2) * 16 + lr, lg);
            short8v a0k1 = ld_frag(Ah, (g * 2) * 16 + lr, 4 + lg);
            short8v a1k0 = ld_frag(Ah, (g * 2 + 1) * 16 + lr, lg);
            short8v a1k1 = ld_frag(Ah, (g * 2 + 1) * 16 + lr, 4 + lg);

            if (g == 0 && kt + 1 < nk) stageH(0, (kt + 1) & 1, 0, koff + (kt + 1) * 64);
            if (g == 1 && kt + 1 < nk) stageH(0, (kt + 1) & 1, 1, koff + (kt + 1) * 64);
            if (g == 2 && kt + 2 < nk) stageH(1, kt & 1, 0, koff + (kt + 2) * 64);
            if (g == 3 && kt + 2 < nk) stageH(1, kt & 1, 1, koff + (kt + 2) * 64);

            __builtin_amdgcn_s_setprio(1);
#pragma unroll
            for (int ni = 0; ni < 4; ++ni) {
                acc[g * 2][ni] = __builtin_amdgcn_mfma_f32_16x16x32_bf16(
                    a0k0, bfr[ni][0], acc[g * 2][ni], 0, 0, 0);
                acc[g * 2][ni] = __builtin_amdgcn_mfma_f32_16x16x32_bf16(
                    a0k1, bfr[ni][1], acc[g * 2][ni], 0, 0, 0);
                acc[g * 2 + 1][ni] = __builtin_amdgcn_mfma_f32_16x16x32_bf16(
                    a1k0, bfr[ni][0], acc[g * 2 + 1][ni], 0, 0, 0);
                acc[g * 2 + 1][ni] = __builtin_amdgcn_mfma_f32_16x16x32_bf16(
                    a1k1, bfr[ni][1], acc[g * 2 + 1][ni], 0, 0, 0);
            }
            __builtin_amdgcn_s_setprio(0);
        }
    }

    // epilogue: bf16 partials (no bias)
#pragma unroll
    for (int mi = 0; mi < 8; ++mi) {
        const int row = m0 + wr * 128 + mi * 16 + (l >> 4) * 4;
#pragma unroll
        for (int ni = 0; ni < 4; ++ni) {
            const int col = n0 + wc * 64 + ni * 16 + lr;
#pragma unroll
            for (int j = 0; j < 4; ++j)
                dst[(size_t)(row + j) * N + col] = f2bf(acc[mi][ni][j]);
        }
    }
}

// ---------------------------------------------------------------------------
// Split-K=2 bf16 GEMM (Wo shapes, K=1024): 128x128 tile, BK=64, 2-buffer
// counted-vmcnt, 8 waves. (unchanged from R15)
// ---------------------------------------------------------------------------
__global__ __launch_bounds__(512) void gemm_k128c_kernel(
    const USHORT* __restrict__ A, const USHORT* __restrict__ Bt,
    USHORT* __restrict__ Pa, USHORT* __restrict__ Pb,
    int M, int N, int K)
{
    __shared__ USHORT As[2][128 * 64];
    __shared__ USHORT Bs[2][128 * 64];

    const int tid = threadIdx.x;
    const int l   = tid & 63;
    const int w   = tid >> 6;
    const int wr  = w >> 2, wc = w & 3;
    const int lr  = l & 15, lg = l >> 4;

    const int gx  = gridDim.x;
    const int nwg = gx * gridDim.y;
    const int lin = blockIdx.y * gx + blockIdx.x;
    const int swz = (lin & 7) * (nwg >> 3) + (lin >> 3);
    const int my  = swz / gx;
    const int mt  = M >> 7;
    const int part = my / mt;
    const int m0  = (my % mt) << 7;
    const int n0  = (swz % gx) * 128;
    const int koff = part * (K >> 1);
    USHORT* dst = part ? Pb : Pa;

    const USHORT* aS[2]; const USHORT* bS[2]; int dOf[2];
#pragma unroll
    for (int p = 0; p < 2; ++p) {
        const int q = p * 512 + tid;
        const int row = q >> 3, cu = q & 7;
        const int cs = ((cu ^ (row & 7)) << 3);
        aS[p] = A  + (size_t)(m0 + row) * K + cs;
        bS[p] = Bt + (size_t)(n0 + row) * K + cs;
        dOf[p] = (p * 512 + w * 64) * 8;
    }

    auto stage = [&](int buf, int k0) {
#pragma unroll
        for (int p = 0; p < 2; ++p) {
            GLDS(aS[p] + k0, &As[buf][dOf[p]]);
            GLDS(bS[p] + k0, &Bs[buf][dOf[p]]);
        }
    };

    f32x4 acc[4][2];
#pragma unroll
    for (int i = 0; i < 4; ++i)
#pragma unroll
        for (int j = 0; j < 2; ++j) acc[i][j] = (f32x4){0.f, 0.f, 0.f, 0.f};

    const int nk = K >> 7;
    stage(0, koff);

    for (int t = 0; t < nk; ++t) {
        const int cur = t & 1;
        if (t + 1 < nk) {
            stage(cur ^ 1, koff + ((t + 1) << 6));
            WAITVM(4);
        } else {
            WAITVM(0);
        }
        __builtin_amdgcn_s_barrier();

#pragma unroll
        for (int ks = 0; ks < 2; ++ks) {
            short8v bfr[2];
#pragma unroll
            for (int ni = 0; ni < 2; ++ni)
                bfr[ni] = ld_frag(Bs[cur], wc * 32 + ni * 16 + lr, ks * 4 + lg);
            __builtin_amdgcn_s_setprio(1);
#pragma unroll
            for (int mi = 0; mi < 4; ++mi) {
                short8v af = ld_frag(As[cur], wr * 64 + mi * 16 + lr, ks * 4 + lg);
#pragma unroll
                for (int ni = 0; ni < 2; ++ni)
                    acc[mi][ni] = __builtin_amdgcn_mfma_f32_16x16x32_bf16(
                        af, bfr[ni], acc[mi][ni], 0, 0, 0);
            }
            __builtin_amdgcn_s_setprio(0);
        }
        __builtin_amdgcn_s_barrier();
    }

#pragma unroll
    for (int mi = 0; mi < 4; ++mi) {
        const int row = m0 + wr * 64 + mi * 16 + (l >> 4) * 4;
#pragma unroll
        for (int ni = 0; ni < 2; ++ni) {
            const int col = n0 + wc * 32 + ni * 16 + lr;
#pragma unroll
            for (int j = 0; j < 4; ++j)
                dst[(size_t)(row + j) * N + col] = f2bf(acc[mi][ni][j]);
        }
    }
}

// ---------------------------------------------------------------------------
// Weight convert+transpose kernels (unchanged).
// ---------------------------------------------------------------------------
struct TcvtB4 {
    const float* s0; const float* s1; const float* s2; const float* s3;
    USHORT* d0; USHORT* d1; USHORT* d2; USHORT* d3;
};

__device__ __forceinline__ void tcvt_body(
    const float* __restrict__ W, USHORT* __restrict__ Wt, int K, int N)
{
    __shared__ USHORT L[64][65];
    const int tid = threadIdx.x;
    const int tx = tid & 15, ty = tid >> 4;
    const int n0 = blockIdx.x * 64, k0 = blockIdx.y * 64;
#pragma unroll
    for (int r = 0; r < 4; ++r) {
        int kr = ty + 16 * r;
        float4 v = *reinterpret_cast<const float4*>(
            &W[(size_t)(k0 + kr) * N + n0 + tx * 4]);
        L[tx * 4 + 0][kr] = f2bf(v.x);
        L[tx * 4 + 1][kr] = f2bf(v.y);
        L[tx * 4 + 2][kr] = f2bf(v.z);
        L[tx * 4 + 3][kr] = f2bf(v.w);
    }
    __syncthreads();
#pragma unroll
    for (int r = 0; r < 4; ++r) {
        int nr = ty + 16 * r;
        ushort4 o = make_ushort4(L[nr][tx * 4 + 0], L[nr][tx * 4 + 1],
                                 L[nr][tx * 4 + 2], L[nr][tx * 4 + 3]);
        *reinterpret_cast<ushort4*>(&Wt[(size_t)(n0 + nr) * K + k0 + tx * 4]) = o;
    }
}

__global__ __launch_bounds__(256) void tcvt_kernel(
    const float* __restrict__ W, USHORT* __restrict__ Wt, int K, int N)
{
    tcvt_body(W, Wt, K, N);
}

__global__ __launch_bounds__(256) void tcvt4_kernel(TcvtB4 p, int K, int N)
{
    const int z = blockIdx.z;
    const float* W = (z == 0) ? p.s0 : (z == 1) ? p.s1 : (z == 2) ? p.s2 : p.s3;
    USHORT*    Wt = (z == 0) ? p.d0 : (z == 1) ? p.d1 : (z == 2) ? p.d2 : p.d3;
    tcvt_body(W, Wt, K, N);
}

__global__ __launch_bounds__(256) void f2b_kernel(
    const float* __restrict__ in, USHORT* __restrict__ out, int n4)
{
    int i = blockIdx.x * 256 + threadIdx.x;
    if (i < n4) {
        float4 v = reinterpret_cast<const float4*>(in)[i];
        reinterpret_cast<ushort4*>(out)[i] =
            make_ushort4(f2bf(v.x), f2bf(v.y), f2bf(v.z), f2bf(v.w));
    }
}

// ---------------------------------------------------------------------------
// MFMA flash attention (unchanged from R24).
// ---------------------------------------------------------------------------
__global__ __launch_bounds__(256) void attn_mfma_kernel(
    const USHORT* __restrict__ Q, const USHORT* __restrict__ K,
    const USHORT* __restrict__ Vt, USHORT* __restrict__ O, int causal)
{
    __shared__ USHORT smem[24576];                 // 48 KB

    const int tid = threadIdx.x;
    const int l  = tid & 63;
    const int w  = tid >> 6;
    const int lr = l & 15;
    const int lg = l >> 4;

    const int lin = blockIdx.y * 8 + blockIdx.x;    // nwg = 512
    const int swz = (lin & 7) * 64 + (lin >> 3);
    const int qtr = swz & 7;
    const int qt  = causal ? (qtr ^ (((swz >> 5) & 1) ? 7 : 0)) : qtr;
    const int bh = swz >> 3;
    const int h = bh & 15, b = bh >> 4;
    const int q0 = qt * 128;

    const USHORT* gq  = Q  + (size_t)(b * SEQ + q0) * D_MODEL + h * DH;
    const USHORT* gk0 = K  + (size_t)b * SEQ * D_MODEL + h * DH;
    const USHORT* gv0 = Vt + (size_t)bh * DH * SEQ;

    auto stageK = [&](int buf, int kt) {           // 64x64, row&7 swizzle
        USHORT* dst = smem + buf * 4096;
        const size_t base = (size_t)kt * 64 * 1024;
#pragma unroll
        for (int p = 0; p < 2; ++p) {
            const int q = p * 256 + tid;
            const int row = q >> 3, cu = q & 7;
            GLDS(gk0 + base + (size_t)row * 1024 + ((cu ^ (row & 7)) << 3),
                 dst + (p * 256 + w * 64) * 8);
        }
    };
    auto stageV = [&](int buf, int kt) {           // 64 d x 64 j, row&7 swizzle
        USHORT* dst = smem + 8192 + buf * 4096;
        const int j0 = kt * 64;
#pragma unroll
        for (int p = 0; p < 2; ++p) {
            const int q = p * 256 + tid;
            const int row = q >> 3, cu = q & 7;
            GLDS(gv0 + (size_t)row * 1024 + j0 + ((cu ^ (row & 7)) << 3),
                 dst + (p * 256 + w * 64) * 8);
        }
    };

    // stage Q (128x64, row&7 swizzle) + first K/V tile
#pragma unroll
    for (int p = 0; p < 4; ++p) {
        const int q = p * 256 + tid;
        const int row = q >> 3, cu = q & 7;
        GLDS(gq + (size_t)row * 1024 + ((cu ^ (row & 7)) << 3),
             smem + 16384 + (p * 256 + w * 64) * 8);
    }
    stageK(0, 0);
    stageV(0, 0);

    f32x4 oacc[2][4];
    float m_[2], l_[2];            // per-lane state for q = w*32 + s*16 + lr
#pragma unroll
    for (int s = 0; s < 2; ++s) {
        m_[s] = -1e30f; l_[s] = 0.f;
#pragma unroll
        for (int d = 0; d < 4; ++d) oacc[s][d] = (f32x4){0.f, 0.f, 0.f, 0.f};
    }

    // P write offsets: row = s*16+lr, j = jb*16 + lg*4 .. +3 (one b64 each)
    int paddr[2][4];
#pragma unroll
    for (int s = 0; s < 2; ++s) {
        const int row = s * 16 + lr;
#pragma unroll
        for (int jb = 0; jb < 4; ++jb) {
            const int cu = jb * 2 + (lg >> 1);
            paddr[s][jb] = row * 64 + ((cu ^ (row & 7)) << 3) + (lg & 1) * 4;
        }
    }

    __syncthreads();                               // Q + tile 0 staged
    short8v qa[2][2];
#pragma unroll
    for (int s = 0; s < 2; ++s) {
        qa[s][0] = ld_frag(smem + 16384, w * 32 + s * 16 + lr, lg);
        qa[s][1] = ld_frag(smem + 16384, w * 32 + s * 16 + lr, 4 + lg);
    }
    __syncthreads();                               // Q consumed -> P may reuse
    USHORT* PsW = smem + 16384 + w * 2048;         // per-wave P [32 q][64 j]

    const int ntile = causal ? (qt * 2 + 2) : (SEQ / 64);
    for (int kt = 0; kt < ntile; ++kt) {
        const int cur = kt & 1;
        if (kt + 1 < ntile) {                      // prefetch next K/V tile
            stageK(cur ^ 1, kt + 1);
            stageV(cur ^ 1, kt + 1);
        }
        const int j0 = kt * 64;
        const USHORT* KsC = smem + cur * 4096;
        const USHORT* VsC = smem + 8192 + cur * 4096;

        // S^T = mfma(K, Q); K frags shared across both q-subtiles
        f32x4 sa[2][4];
        __builtin_amdgcn_s_setprio(1);
#pragma unroll
        for (int jb = 0; jb < 4; ++jb) {
            short8v kf0 = ld_frag(KsC, jb * 16 + lr, lg);
            short8v kf1 = ld_frag(KsC, jb * 16 + lr, 4 + lg);
#pragma unroll
            for (int s = 0; s < 2; ++s) {
                sa[s][jb] = (f32x4){0.f, 0.f, 0.f, 0.f};
                sa[s][jb] = __builtin_amdgcn_mfma_f32_16x16x32_bf16(
                    kf0, qa[s][0], sa[s][jb], 0, 0, 0);
                sa[s][jb] = __builtin_amdgcn_mfma_f32_16x16x32_bf16(
                    kf1, qa[s][1], sa[s][jb], 0, 0, 0);
            }
        }
        __builtin_amdgcn_s_setprio(0);

        // causal mask: only the last two tiles can cross the diagonal
        if (causal && kt >= ntile - 2) {
#pragma unroll
            for (int s = 0; s < 2; ++s) {
                const int qrow = q0 + w * 32 + s * 16 + lr;
#pragma unroll
                for (int jb = 0; jb < 4; ++jb)
#pragma unroll
                    for (int r = 0; r < 4; ++r)
                        if ((j0 + jb * 16 + lg * 4 + r) > qrow)
                            sa[s][jb][r] = -1e30f;
            }
        }

        // per-lane tile max over 16 values per qsub + 2 shfl each
        float tm[2];
#pragma unroll
        for (int s = 0; s < 2; ++s) {
            float t1 = max3f(sa[s][0][0], sa[s][0][1], sa[s][0][2]);
            float t2 = max3f(sa[s][0][3], sa[s][1][0], sa[s][1][1]);
            float t3 = max3f(sa[s][1][2], sa[s][1][3], sa[s][2][0]);
            float t4 = max3f(sa[s][2][1], sa[s][2][2], sa[s][2][3]);
            float t5 = max3f(sa[s][3][0], sa[s][3][1], sa[s][3][2]);
            float tv = fmaxf(max3f(max3f(t1, t2, t3), t4, t5), sa[s][3][3]);
            tv = fmaxf(tv, __shfl_xor(tv, 16));
            tv = fmaxf(tv, __shfl_xor(tv, 32));
            tm[s] = tv;
        }

        // defer-max rescale (wave-gated; broadcast sc from owner lanes)
        const bool anyf = (tm[0] > m_[0] + 8.f) | (tm[1] > m_[1] + 8.f);
        if (__ballot(anyf)) {
            float sc[2];
#pragma unroll
            for (int s = 0; s < 2; ++s) {
                const float mn = (tm[s] > m_[s] + 8.f) ? tm[s] : m_[s];
                sc[s] = fexp2(m_[s] - mn);
                l_[s] *= sc[s];
                m_[s] = mn;
            }
#pragma unroll
            for (int s = 0; s < 2; ++s)
#pragma unroll
                for (int r = 0; r < 4; ++r) {
                    const float scr = __shfl(sc[s], (l & 48) | (lg * 4 + r));
#pragma unroll
                    for (int d = 0; d < 4; ++d) oacc[s][d][r] *= scr;
                }
        }

        // exp (log2 domain, raw v_exp) + lane-partial sum + pack + b64 writes
#pragma unroll
        for (int s = 0; s < 2; ++s)
#pragma unroll
            for (int jb = 0; jb < 4; ++jb) {
                const float p0 = fexp2(sa[s][jb][0] - m_[s]);
                const float p1 = fexp2(sa[s][jb][1] - m_[s]);
                const float p2 = fexp2(sa[s][jb][2] - m_[s]);
                const float p3 = fexp2(sa[s][jb][3] - m_[s]);
                l_[s] += (p0 + p1) + (p2 + p3);
                *reinterpret_cast<uint2*>(&PsW[paddr[s][jb]]) =
                    make_uint2(pk2bf(p0, p1), pk2bf(p2, p3));
            }

        // PV: V frags shared across both q-subtiles
        __builtin_amdgcn_s_setprio(1);
#pragma unroll
        for (int ks = 0; ks < 2; ++ks) {
            short8v pa[2];
#pragma unroll
            for (int s = 0; s < 2; ++s)
                pa[s] = ld_frag(PsW, s * 16 + lr, ks * 4 + lg);
#pragma unroll
            for (int d = 0; d < 4; ++d) {
                short8v vf = ld_frag(VsC, d * 16 + lr, ks * 4 + lg);
#pragma unroll
                for (int s = 0; s < 2; ++s)
                    oacc[s][d] = __builtin_amdgcn_mfma_f32_16x16x32_bf16(
                        pa[s], vf, oacc[s][d], 0, 0, 0);
            }
        }
        __builtin_amdgcn_s_setprio(0);
        __syncthreads();   // drains prefetch + guards K/V/P buffer reuse
    }

    // epilogue: cross-lg l sum per qsub, inv via owner-lane shfl
    USHORT* go = O + (size_t)(b * SEQ + q0 + w * 32) * D_MODEL + h * DH;
#pragma unroll
    for (int s = 0; s < 2; ++s) {
        float lv = l_[s];
        lv += __shfl_xor(lv, 16);
        lv += __shfl_xor(lv, 32);
        const float inv_own = 1.f / lv;
#pragma unroll
        for (int r = 0; r < 4; ++r) {
            const float inv = __shfl(inv_own, (l & 48) | (lg * 4 + r));
            const int qrow = s * 16 + lg * 4 + r;
#pragma unroll
            for (int d = 0; d < 4; ++d)
                go[(size_t)qrow * D_MODEL + d * 16 + lr] =
                    f2bf_fast(oacc[s][d][r] * inv);
        }
    }
}

// ---------------------------------------------------------------------------
// out = res + LayerNorm(x)*g + b, x = xb (+xb2) (+xb3) (+xb4) (+biasx).
// res: fp32 (resf) / bf16 (resb) / x itself (both null). (unchanged)
// ---------------------------------------------------------------------------
__global__ __launch_bounds__(256) void ln_res_kernel(
    const USHORT* __restrict__ xb, const USHORT* __restrict__ xb2,
    const USHORT* __restrict__ xb3, const USHORT* __restrict__ xb4,
    const float* __restrict__ biasx,
    const float* __restrict__ resf, const USHORT* __restrict__ resb,
    const float* __restrict__ g, const float* __restrict__ bta,
    float* __restrict__ outf, USHORT* __restrict__ outb)
{
    __shared__ float red[256];
    __shared__ float s_mu, s_rstd;

    const int row = blockIdx.x;
    const int tid = threadIdx.x;
    ushort4 xv = reinterpret_cast<const ushort4*>(xb + (size_t)row * D_MODEL)[tid];
    float vx = bf2f(xv.x), vy = bf2f(xv.y), vz = bf2f(xv.z), vw = bf2f(xv.w);
    if (xb2) {
        ushort4 x2 = reinterpret_cast<const ushort4*>(
            xb2 + (size_t)row * D_MODEL)[tid];
        vx += bf2f(x2.x); vy += bf2f(x2.y); vz += bf2f(x2.z); vw += bf2f(x2.w);
    }
    if (xb3) {
        ushort4 x3 = reinterpret_cast<const ushort4*>(
            xb3 + (size_t)row * D_MODEL)[tid];
        vx += bf2f(x3.x); vy += bf2f(x3.y); vz += bf2f(x3.z); vw += bf2f(x3.w);
    }
    if (xb4) {
        ushort4 x4 = reinterpret_cast<const ushort4*>(
            xb4 + (size_t)row * D_MODEL)[tid];
        vx += bf2f(x4.x); vy += bf2f(x4.y); vz += bf2f(x4.z); vw += bf2f(x4.w);
    }
    if (biasx) {
        float4 bx = reinterpret_cast<const float4*>(biasx)[tid];
        vx += bx.x; vy += bx.y; vz += bx.z; vw += bx.w;
    }

    red[tid] = vx + vy + vz + vw;
    __syncthreads();
    for (int s = 128; s > 0; s >>= 1) {
        if (tid < s) red[tid] += red[tid + s];
        __syncthreads();
    }
    if (tid == 0) s_mu = red[0] * (1.f / D_MODEL);
    __syncthreads();
    const float mu = s_mu;

    float dx = vx - mu, dy = vy - mu, dz = vz - mu, dw = vw - mu;
    red[tid] = dx * dx + dy * dy + dz * dz + dw * dw;
    __syncthreads();
    for (int s = 128; s > 0; s >>= 1) {
        if (tid < s) red[tid] += red[tid + s];
        __syncthreads();
    }
    if (tid == 0) s_rstd = rsqrtf(red[0] * (1.f / D_MODEL) + EPS);
    __syncthreads();
    const float rstd = s_rstd;

    float4 rv;
    if (resf) {
        rv = reinterpret_cast<const float4*>(resf + (size_t)row * D_MODEL)[tid];
    } else if (resb) {
        ushort4 rb = reinterpret_cast<const ushort4*>(
            resb + (size_t)row * D_MODEL)[tid];
        rv = make_float4(bf2f(rb.x), bf2f(rb.y), bf2f(rb.z), bf2f(rb.w));
    } else {
        rv = make_float4(vx, vy, vz, vw);          // res = x (norm_attn2 wiring)
    }
    float4 gv = reinterpret_cast<const float4*>(g)[tid];
    float4 bv = reinterpret_cast<const float4*>(bta)[tid];

    float4 o;
    o.x = rv.x + dx * rstd * gv.x + bv.x;
    o.y = rv.y + dy * rstd * gv.y + bv.y;
    o.z = rv.z + dz * rstd * gv.z + bv.z;
    o.w = rv.w + dw * rstd * gv.w + bv.w;
    reinterpret_cast<float4*>(outf + (size_t)row * D_MODEL)[tid] = o;
    if (outb)
        reinterpret_cast<ushort4*>(outb + (size_t)row * D_MODEL)[tid] =
            make_ushort4(f2bf(o.x), f2bf(o.y), f2bf(o.z), f2bf(o.w));
}

// ---------------------------------------------------------------------------
extern "C" void kernel_launch(void* const* d_in, const int* in_sizes, int n_in,
                              void* d_out, int out_size, void* d_ws, size_t ws_size,
                              hipStream_t stream)
{
    const float* X    = (const float*)d_in[0];
    const float* Wq1  = (const float*)d_in[1];
    const float* Wk1  = (const float*)d_in[2];
    const float* Wv1  = (const float*)d_in[3];
    const float* Wo1  = (const float*)d_in[4];
    const float* Wq2  = (const float*)d_in[5];
    const float* Wk2  = (const float*)d_in[6];
    const float* Wv2  = (const float*)d_in[7];
    const float* Wo2  = (const float*)d_in[8];
    const float* ln_g = (const float*)d_in[9];
    const float* ln_b = (const float*)d_in[10];
    const float* W1   = (const float*)d_in[11];
    const float* b1   = (const float*)d_in[12];
    const float* W2   = (const float*)d_in[13];
    const float* b2   = (const float*)d_in[14];

    // ws layout (ushort units). CRITICAL: FFN hidden hb = qb spans
    // [16Mi, 32Mi) -- FFN2 partials MUST stay outside that range.
    const size_t MI = 1024 * 1024;
    USHORT* ws16 = (USHORT*)d_ws;
    USHORT* Wqkv1t = ws16;                 // [0,3Mi); scr0 reuses [0,4Mi)
    USHORT* scr0   = ws16;                 //   dead after MHA2 ln_res
    USHORT* Wo1t   = ws16 + 3 * MI;
    USHORT* Wqkv2t = ws16 + 4 * MI;
    USHORT* Wo2t   = ws16 + 7 * MI;
    USHORT* W2t    = ws16 + 8 * MI;
    USHORT* Xb     = ws16 + 12 * MI;
    USHORT* W1t    = Xb;                   // [12,16Mi): dead after FFN1
    USHORT* qb     = ws16 + 16 * MI;
    USHORT* kb     = ws16 + 20 * MI;
    USHORT* Vtb    = ws16 + 24 * MI;
    USHORT* t0b    = ws16 + 28 * MI;       // INSIDE hb -- never an FFN2 partial
    USHORT* hb     = qb;                   // [16,32Mi)
    USHORT* t2b    = ws16 + 32 * MI;
    USHORT* t1b    = ws16 + 36 * MI;
    float*  t2     = (float*)(ws16 + 40 * MI);

    auto gemmBig = [&](const USHORT* A, const USHORT* Bt, float* Cf, USHORT* Cb,
                       int M, int N, int K, const float* bias, int relu) {
        gemm_k256p8_kernel<<<dim3(N / 256, M / 256), 512, 0, stream>>>(
            A, Bt, Cf, Cb, nullptr, nullptr, M, N, K, bias, relu, 0);
    };
    auto gemm_qkv = [&](const USHORT* A, const USHORT* Bt) {
        gemm_k256p8_kernel<<<dim3(3072 / 256, TOK / 256), 512, 0, stream>>>(
            A, Bt, nullptr, qb, kb, Vtb, TOK, 3072, D_MODEL, nullptr, 0, 1);
    };
    auto gemm128c = [&](const USHORT* A, const USHORT* Bt, USHORT* Pa, USHORT* Pb,
                        int M, int N, int K) {
        gemm_k128c_kernel<<<dim3(N / 128, (M / 128) * 2), 512, 0, stream>>>(
            A, Bt, Pa, Pb, M, N, K);
    };
    auto gemm256s4 = [&](const USHORT* A, const USHORT* Bt,
                         USHORT* Pa, USHORT* Pb, USHORT* Pc, USHORT* Pd,
                         int M, int N, int K) {
        gemm_k256p8s4_kernel<<<dim3(N / 256, (M / 256) * 4), 512, 0, stream>>>(
            A, Bt, Pa, Pb, Pc, Pd, M, N, K);
    };

    dim3 agrid(SEQ / 128, BATCH * N_HEADS);

    // ---- prologue: all square weights + W2 + X -> bf16 ----
    {
        TcvtB4 p1{Wq1, Wk1, Wv1, Wo1,
                  Wqkv1t, Wqkv1t + 1 * MI, Wqkv1t + 2 * MI, Wo1t};
        tcvt4_kernel<<<dim3(16, 16, 4), 256, 0, stream>>>(p1, D_MODEL, D_MODEL);
        TcvtB4 p2{Wq2, Wk2, Wv2, Wo2,
                  Wqkv2t, Wqkv2t + 1 * MI, Wqkv2t + 2 * MI, Wo2t};
        tcvt4_kernel<<<dim3(16, 16, 4), 256, 0, stream>>>(p2, D_MODEL, D_MODEL);
    }
    tcvt_kernel<<<dim3(D_MODEL / 64, D_FF / 64), 256, 0, stream>>>(
        W2, W2t, D_FF, D_MODEL);
    f2b_kernel<<<dim3(4096), 256, 0, stream>>>(X, Xb, TOK * D_MODEL / 4);

    // ---- MHA 1 (causal) ----
    gemm_qkv(Xb, Wqkv1t);
    attn_mfma_kernel<<<agrid, 256, 0, stream>>>(qb, kb, Vtb, t0b, 1);
    gemm128c(t0b, Wo1t, t2b, t1b, TOK, D_MODEL, D_MODEL);     // masked = t2b+t1b
    ln_res_kernel<<<dim3(TOK), 256, 0, stream>>>(t2b, t1b, nullptr, nullptr,
                                                 nullptr, X, nullptr,
                                                 ln_g, ln_b, t2, t2b);
    tcvt_kernel<<<dim3(D_FF / 64, D_MODEL / 64), 256, 0, stream>>>(
        W1, W1t, D_MODEL, D_FF);

    // ---- MHA 2 (full) ----
    gemm_qkv(t2b, Wqkv2t);
    attn_mfma_kernel<<<agrid, 256, 0, stream>>>(qb, kb, Vtb, t0b, 0);
    gemm128c(t0b, Wo2t, scr0, t1b, TOK, D_MODEL, D_MODEL);    // attn2 = scr0+t1b
    ln_res_kernel<<<dim3(TOK), 256, 0, stream>>>(scr0, t1b, nullptr, nullptr,
                                                 nullptr, nullptr, nullptr,
                                                 ln_g, ln_b, t2, t2b);   // res = x

    // ---- FFN ----
    gemmBig(t2b, W1t, nullptr, hb, TOK, D_FF, D_MODEL, b1, 1);
    // FFN2: 256^2 8-phase split-K=4; partials in scr0 [0,4Mi), W1t [12,16Mi),
    // t2b, t1b -- all dead here and all OUTSIDE hb [16,32Mi).
    gemm256s4(hb, W2t, scr0, W1t, t2b, t1b, TOK, D_MODEL, D_FF);
    ln_res_kernel<<<dim3(TOK), 256, 0, stream>>>(scr0, W1t, t2b, t1b, b2,
                                                 t2, nullptr,
                                                 ln_g, ln_b, (float*)d_out, nullptr);
}